// Round 1
// baseline (904.118 us; speedup 1.0000x reference)
//
#include <hip/hip_runtime.h>

typedef _Float16 half_t;
typedef _Float16 half8  __attribute__((ext_vector_type(8)));
typedef _Float16 half4v __attribute__((ext_vector_type(4)));
typedef _Float16 half2v __attribute__((ext_vector_type(2)));
typedef float    f32x4  __attribute__((ext_vector_type(4)));

constexpr int N_NODES = 32768;
constexpr int NPG_    = 512;

// ---------------- CSR build ----------------
__global__ void k_deg_init(int* __restrict__ deg) {
  deg[blockIdx.x * 256 + threadIdx.x] = 1;   // self-loop counts as 1
}

__global__ void k_hist(const int* __restrict__ dst, int* __restrict__ deg, int E) {
  int i = blockIdx.x * 256 + threadIdx.x;
  if (i < E) atomicAdd(&deg[dst[i]], 1);
}

__global__ __launch_bounds__(1024) void k_scan(const int* __restrict__ deg,
                                               int* __restrict__ rowptr) {
  __shared__ int part[1024];
  int t = threadIdx.x;
  int base = t * 32;
  int s = 0;
  #pragma unroll
  for (int i = 0; i < 32; i++) s += deg[base + i];
  part[t] = s;
  __syncthreads();
  for (int off = 1; off < 1024; off <<= 1) {
    int add = (t >= off) ? part[t - off] : 0;
    __syncthreads();
    part[t] += add;
    __syncthreads();
  }
  int run = (t == 0) ? 0 : part[t - 1];
  for (int i = 0; i < 32; i++) { rowptr[base + i] = run; run += deg[base + i]; }
  if (t == 1023) rowptr[N_NODES] = run;
}

__global__ void k_selfloop(const int* __restrict__ rowptr, int* __restrict__ fill,
                           int* __restrict__ col) {
  int i = blockIdx.x * 256 + threadIdx.x;
  fill[i] = 1;
  col[rowptr[i]] = i;   // self-loop is slot 0 of every dst
}

__global__ void k_scatter(const int* __restrict__ src, const int* __restrict__ dst,
                          const int* __restrict__ rowptr, int* __restrict__ fill,
                          int* __restrict__ col, int E) {
  int i = blockIdx.x * 256 + threadIdx.x;
  if (i < E) {
    int d = dst[i];
    int pos = rowptr[d] + atomicAdd(&fill[d], 1);
    col[pos] = src[i];
  }
}

// ---------------- conversions ----------------
__global__ void k_f2h(const float* __restrict__ in, half_t* __restrict__ out, int n) {
  int i = blockIdx.x * 256 + threadIdx.x;
  if (i < n) out[i] = (half_t)in[i];
}

// out[o*K + k] = W[k*Nc + o]  (transpose-convert: W is [K,Nc], out is [Nc,K])
__global__ void k_f2h_T(const float* __restrict__ W, half_t* __restrict__ out,
                        int K, int Nc) {
  int i = blockIdx.x * 256 + threadIdx.x;
  if (i < K * Nc) {
    int o = i / K, k = i % K;
    out[i] = (half_t)W[(size_t)k * Nc + o];
  }
}

// ---------------- GEMM: C[M,Nc] = A[M,K] @ Bt[Nc,K]^T (+bias) ----------------
// A, Bt fp16 K-major. Block = 4 waves; wave w: rows m0=by*64+w*16, cols n0..n0+63.
__global__ __launch_bounds__(256) void k_gemm(
    const half_t* __restrict__ A, const half_t* __restrict__ Bt,
    const float* __restrict__ bias, int bias_per_row,
    half_t* __restrict__ outh, float* __restrict__ outf,
    int M, int Nc, int K)
{
  int w = threadIdx.x >> 6, lane = threadIdx.x & 63;
  int r = lane & 15, q = lane >> 4;
  int m0 = blockIdx.y * 64 + w * 16;
  int n0 = blockIdx.x * 64;
  f32x4 acc[4];
  #pragma unroll
  for (int t = 0; t < 4; t++) acc[t] = f32x4{0.f, 0.f, 0.f, 0.f};
  const half_t* Ap = A + (size_t)(m0 + r) * K;
  const half_t* Bp = Bt + (size_t)(n0 + r) * K;
  for (int k0 = 0; k0 < K; k0 += 32) {
    half8 a = *(const half8*)(Ap + k0 + q * 8);
    #pragma unroll
    for (int t = 0; t < 4; t++) {
      half8 b = *(const half8*)(Bp + (size_t)(16 * t) * K + k0 + q * 8);
      acc[t] = __builtin_amdgcn_mfma_f32_16x16x32_f16(a, b, acc[t], 0, 0, 0);
    }
  }
  #pragma unroll
  for (int t = 0; t < 4; t++) {
    int colc = n0 + 16 * t + r;
    #pragma unroll
    for (int i = 0; i < 4; i++) {
      int row = m0 + q * 4 + i;
      float bv = bias ? (bias_per_row ? bias[row] : bias[colc]) : 0.f;
      float v = acc[t][i] + bv;
      size_t idx = (size_t)row * Nc + colc;
      if (outf) outf[idx] = v;
      if (outh) outh[idx] = (half_t)v;
    }
  }
}

// ---------------- per-node attention scores es/ed ----------------
template<int HC, int H>
__global__ __launch_bounds__(256) void k_scored(
    const half_t* __restrict__ h, const float* __restrict__ aS,
    const float* __restrict__ aD, float* __restrict__ es, float* __restrict__ ed)
{
  constexpr int VPT = HC / 64;
  constexpr int LPH = 64 / H;     // lanes per head
  int lane = threadIdx.x & 63;
  int n = blockIdx.x * 4 + (threadIdx.x >> 6);
  const half_t* hp = h + (size_t)n * HC + lane * VPT;
  float ps = 0.f, pd = 0.f;
  #pragma unroll
  for (int i = 0; i < VPT; i++) {
    float v = (float)hp[i];
    ps += v * aS[lane * VPT + i];
    pd += v * aD[lane * VPT + i];
  }
  #pragma unroll
  for (int off = 1; off < LPH; off <<= 1) {
    ps += __shfl_xor(ps, off);
    pd += __shfl_xor(pd, off);
  }
  if ((lane & (LPH - 1)) == 0) {
    es[(size_t)n * H + lane / LPH] = ps;
    ed[(size_t)n * H + lane / LPH] = pd;
  }
}

// ---------------- edge-softmax aggregation (one wave per dst) ----------------
template<int HC, int H>
__global__ __launch_bounds__(256) void k_agg(
    const half_t* __restrict__ h, const float* __restrict__ es,
    const float* __restrict__ ed, const float* __restrict__ bias,
    const int* __restrict__ rowptr, const int* __restrict__ col, int elu,
    float* __restrict__ outf, half_t* __restrict__ outh)
{
  constexpr int VPT = HC / 64;
  constexpr int C = HC / H;
  int lane = threadIdx.x & 63;
  int n = blockIdx.x * 4 + (threadIdx.x >> 6);
  int hl = (lane * VPT) / C;
  float edn = ed[(size_t)n * H + hl];
  int j0 = rowptr[n], j1 = rowptr[n + 1];
  float m = -1e30f;
  for (int j = j0; j < j1; j++) {
    int s = col[j];
    float e = es[(size_t)s * H + hl] + edn;
    e = (e >= 0.f) ? e : 0.2f * e;          // LeakyReLU(0.2)
    m = fmaxf(m, e);
  }
  float sum = 0.f;
  float acc[VPT];
  #pragma unroll
  for (int i = 0; i < VPT; i++) acc[i] = 0.f;
  for (int j = j0; j < j1; j++) {
    int s = col[j];
    float e = es[(size_t)s * H + hl] + edn;
    e = (e >= 0.f) ? e : 0.2f * e;
    float p = __expf(e - m);
    sum += p;
    const half_t* hp = h + (size_t)s * HC + lane * VPT;
    if constexpr (VPT == 4) {
      half4v hv = *(const half4v*)hp;
      acc[0] += p * (float)hv[0]; acc[1] += p * (float)hv[1];
      acc[2] += p * (float)hv[2]; acc[3] += p * (float)hv[3];
    } else {
      half2v hv = *(const half2v*)hp;
      acc[0] += p * (float)hv[0]; acc[1] += p * (float)hv[1];
    }
  }
  float inv = 1.f / sum;
  #pragma unroll
  for (int i = 0; i < VPT; i++) {
    int c = lane * VPT + i;
    float v = acc[i] * inv + bias[c];
    if (elu) v = (v > 0.f) ? v : __expf(v) - 1.f;   // jax.nn.elu
    if (outf) outf[(size_t)n * HC + c] = v;
    if (outh) outh[(size_t)n * HC + c] = (half_t)v;
  }
}

// ---------------- MHA core: per (graph, head, 32 q-rows) ----------------
// qk: [N,512] fp16 (Q | K, bias applied). vt: [256,32768] fp16 = V^T per head.
__global__ __launch_bounds__(256) void k_attn(
    const half_t* __restrict__ qk, const half_t* __restrict__ vt,
    half_t* __restrict__ o)
{
  __shared__ half_t SP[32][520];   // scores then probabilities, stride-padded
  __shared__ float rowsum[32];
  int qt   = blockIdx.x;           // 0..15 (32 q-rows each)
  int pair = blockIdx.y;           // 0..255 = graph*4 + head
  int b = pair >> 2, hh = pair & 3;
  int w = threadIdx.x >> 6, lane = threadIdx.x & 63;
  int r = lane & 15, q = lane >> 4;
  int rt = w & 1, wc = w >> 1;

  // Phase 1: S = Q K^T * (1/8)
  {
    const half_t* Qp = qk + (size_t)(b * NPG_ + qt * 32 + rt * 16 + r) * 512 + hh * 64;
    for (int ct = wc; ct < 32; ct += 2) {
      const half_t* Kp = qk + (size_t)(b * NPG_ + ct * 16 + r) * 512 + 256 + hh * 64;
      f32x4 acc = f32x4{0.f, 0.f, 0.f, 0.f};
      #pragma unroll
      for (int kk = 0; kk < 2; kk++) {
        half8 a  = *(const half8*)(Qp + kk * 32 + q * 8);
        half8 bb = *(const half8*)(Kp + kk * 32 + q * 8);
        acc = __builtin_amdgcn_mfma_f32_16x16x32_f16(a, bb, acc, 0, 0, 0);
      }
      #pragma unroll
      for (int i = 0; i < 4; i++)
        SP[rt * 16 + q * 4 + i][ct * 16 + r] = (half_t)(acc[i] * 0.125f);
    }
  }
  __syncthreads();

  // Phase 2: row softmax (exact max), P left unnormalized; rowsum saved
  {
    int rr = threadIdx.x >> 3;
    int s0 = threadIdx.x & 7;
    float mx = -1e30f;
    for (int c = s0; c < 512; c += 8) mx = fmaxf(mx, (float)SP[rr][c]);
    #pragma unroll
    for (int off = 1; off < 8; off <<= 1) mx = fmaxf(mx, __shfl_xor(mx, off));
    float sm = 0.f;
    for (int c = s0; c < 512; c += 8) {
      float p = __expf((float)SP[rr][c] - mx);
      sm += p;
      SP[rr][c] = (half_t)p;
    }
    #pragma unroll
    for (int off = 1; off < 8; off <<= 1) sm += __shfl_xor(sm, off);
    if (s0 == 0) rowsum[rr] = sm;
  }
  __syncthreads();

  // Phase 3: O = P @ V, reading V^T directly (K-contiguous)
  f32x4 acc[2] = {f32x4{0.f,0.f,0.f,0.f}, f32x4{0.f,0.f,0.f,0.f}};
  for (int ks = 0; ks < 16; ks++) {
    half8 a = *(const half8*)(&SP[rt * 16 + r][ks * 32 + q * 8]);
    #pragma unroll
    for (int u = 0; u < 2; u++) {
      int dtile = wc + u * 2;
      const half_t* Vp = vt + (size_t)(hh * 64 + dtile * 16 + r) * 32768
                            + b * NPG_ + ks * 32 + q * 8;
      half8 bb = *(const half8*)Vp;
      acc[u] = __builtin_amdgcn_mfma_f32_16x16x32_f16(a, bb, acc[u], 0, 0, 0);
    }
  }
  #pragma unroll
  for (int u = 0; u < 2; u++) {
    int dtile = wc + u * 2;
    #pragma unroll
    for (int i = 0; i < 4; i++) {
      int rq = rt * 16 + q * 4 + i;
      float v = acc[u][i] / rowsum[rq];
      int node = b * NPG_ + qt * 32 + rq;
      o[(size_t)node * 256 + hh * 64 + dtile * 16 + r] = (half_t)v;
    }
  }
}

// ---------------- residual + LayerNorm -> fp16 ----------------
__global__ __launch_bounds__(256) void k_ln(
    const float* __restrict__ att, const float* __restrict__ x2,
    const float* __restrict__ gamma, const float* __restrict__ beta,
    half_t* __restrict__ outh)
{
  int lane = threadIdx.x & 63;
  int n = blockIdx.x * 4 + (threadIdx.x >> 6);
  size_t base = (size_t)n * 256 + lane * 4;
  float4 a  = *(const float4*)(att + base);
  float4 xx = *(const float4*)(x2 + base);
  float v[4] = {a.x + xx.x, a.y + xx.y, a.z + xx.z, a.w + xx.w};
  float s  = v[0] + v[1] + v[2] + v[3];
  float ss = v[0]*v[0] + v[1]*v[1] + v[2]*v[2] + v[3]*v[3];
  #pragma unroll
  for (int off = 1; off < 64; off <<= 1) {
    s  += __shfl_xor(s, off);
    ss += __shfl_xor(ss, off);
  }
  float mean = s * (1.f / 256.f);
  float var  = ss * (1.f / 256.f) - mean * mean;
  float rstd = rsqrtf(var + 1e-5f);
  #pragma unroll
  for (int i = 0; i < 4; i++) {
    int c = lane * 4 + i;
    outh[(size_t)n * 256 + c] = (half_t)((v[i] - mean) * rstd * gamma[c] + beta[c]);
  }
}

// ---------------- host ----------------
extern "C" void kernel_launch(void* const* d_in, const int* in_sizes, int n_in,
                              void* d_out, int out_size, void* d_ws, size_t ws_size,
                              hipStream_t stream)
{
  const float* x    = (const float*)d_in[0];
  const int*   ei   = (const int*)d_in[1];
  const float* W1   = (const float*)d_in[3];
  const float* aS1  = (const float*)d_in[4];
  const float* aD1  = (const float*)d_in[5];
  const float* b1   = (const float*)d_in[6];
  const float* W2   = (const float*)d_in[7];
  const float* aS2  = (const float*)d_in[8];
  const float* aD2  = (const float*)d_in[9];
  const float* b2   = (const float*)d_in[10];
  const float* W3   = (const float*)d_in[11];
  const float* aS3  = (const float*)d_in[12];
  const float* aD3  = (const float*)d_in[13];
  const float* b3   = (const float*)d_in[14];
  const float* Wi   = (const float*)d_in[15];
  const float* bi   = (const float*)d_in[16];
  const float* Wo   = (const float*)d_in[17];
  const float* bo   = (const float*)d_in[18];
  const float* gam  = (const float*)d_in[19];
  const float* bet  = (const float*)d_in[20];
  float* out = (float*)d_out;
  const int N = N_NODES;
  int E = in_sizes[1] / 2;

  char* ws = (char*)d_ws;
  size_t off = 0;
  auto alloc = [&](size_t bytes) -> void* {
    void* p = ws + off;
    off = (off + bytes + 255) & ~(size_t)255;
    return p;
  };
  half_t* x_h    = (half_t*)alloc((size_t)N * 128 * 2);
  half_t* h_h    = (half_t*)alloc((size_t)N * 256 * 2);   // h1/h2/h3
  half_t* x1_h   = (half_t*)alloc((size_t)N * 256 * 2);
  float*  x2_f   = (float*) alloc((size_t)N * 256 * 4);
  half_t* x2_h   = (half_t*)alloc((size_t)N * 256 * 2);
  half_t* qk_h   = (half_t*)alloc((size_t)N * 512 * 2);
  half_t* vt_h   = (half_t*)alloc((size_t)256 * N * 2);   // V^T: [256][32768]
  half_t* o_h    = (half_t*)alloc((size_t)N * 256 * 2);
  float*  att_f  = (float*) alloc((size_t)N * 256 * 4);
  half_t* x2a_h  = (half_t*)alloc((size_t)N * 256 * 2);
  half_t* W1t    = (half_t*)alloc(256 * 128 * 2);
  half_t* W2t    = (half_t*)alloc(256 * 256 * 2);
  half_t* W3t    = (half_t*)alloc(128 * 256 * 2);
  half_t* Wi_h   = (half_t*)alloc(768 * 256 * 2);
  half_t* Wo_h   = (half_t*)alloc(256 * 256 * 2);
  float*  es     = (float*) alloc((size_t)N * 4 * 4);
  float*  ed     = (float*) alloc((size_t)N * 4 * 4);
  int*    deg    = (int*)   alloc((size_t)N * 4);
  int*    fill   = (int*)   alloc((size_t)N * 4);
  int*    rowptr = (int*)   alloc(((size_t)N + 1) * 4);
  int*    col    = (int*)   alloc((size_t)(N + E) * 4);

  const int* srcE = ei;
  const int* dstE = ei + E;

  // CSR by destination (self-loop first in every row)
  k_deg_init<<<N / 256, 256, 0, stream>>>(deg);
  k_hist<<<(E + 255) / 256, 256, 0, stream>>>(dstE, deg, E);
  k_scan<<<1, 1024, 0, stream>>>(deg, rowptr);
  k_selfloop<<<N / 256, 256, 0, stream>>>(rowptr, fill, col);
  k_scatter<<<(E + 255) / 256, 256, 0, stream>>>(srcE, dstE, rowptr, fill, col, E);

  // fp16 conversions
  k_f2h<<<(N * 128 + 255) / 256, 256, 0, stream>>>(x, x_h, N * 128);
  k_f2h_T<<<(256 * 128 + 255) / 256, 256, 0, stream>>>(W1, W1t, 128, 256);
  k_f2h_T<<<(256 * 256 + 255) / 256, 256, 0, stream>>>(W2, W2t, 256, 256);
  k_f2h_T<<<(128 * 256 + 255) / 256, 256, 0, stream>>>(W3, W3t, 256, 128);
  k_f2h<<<(768 * 256 + 255) / 256, 256, 0, stream>>>(Wi, Wi_h, 768 * 256);
  k_f2h<<<(256 * 256 + 255) / 256, 256, 0, stream>>>(Wo, Wo_h, 256 * 256);

  // ---- GAT1: h1 = x @ W1 ; edge softmax ; ELU -> x1 ----
  k_gemm<<<dim3(4, N / 64), 256, 0, stream>>>(x_h, W1t, nullptr, 0, h_h, nullptr, N, 256, 128);
  k_scored<256, 4><<<N / 4, 256, 0, stream>>>(h_h, aS1, aD1, es, ed);
  k_agg<256, 4><<<N / 4, 256, 0, stream>>>(h_h, es, ed, b1, rowptr, col, 1, nullptr, x1_h);

  // ---- GAT2 -> x2 (fp32 for residual/LN + fp16 for QKV) ----
  k_gemm<<<dim3(4, N / 64), 256, 0, stream>>>(x1_h, W2t, nullptr, 0, h_h, nullptr, N, 256, 256);
  k_scored<256, 4><<<N / 4, 256, 0, stream>>>(h_h, aS2, aD2, es, ed);
  k_agg<256, 4><<<N / 4, 256, 0, stream>>>(h_h, es, ed, b2, rowptr, col, 1, x2_f, x2_h);

  // ---- MHA: QK projection [N,512]; V projected transposed [256,N] ----
  k_gemm<<<dim3(8, N / 64), 256, 0, stream>>>(x2_h, Wi_h, bi, 0, qk_h, nullptr, N, 512, 256);
  k_gemm<<<dim3(N / 64, 4), 256, 0, stream>>>(Wi_h + 512 * 256, x2_h, bi + 512, 1,
                                              vt_h, nullptr, 256, N, 256);
  k_attn<<<dim3(16, 256), 256, 0, stream>>>(qk_h, vt_h, o_h);
  k_gemm<<<dim3(4, N / 64), 256, 0, stream>>>(o_h, Wo_h, bo, 0, nullptr, att_f, N, 256, 256);

  // ---- residual + LayerNorm -> x2a (fp16) ----
  k_ln<<<N / 4, 256, 0, stream>>>(att_f, x2_f, gam, bet, x2a_h);

  // ---- GAT3: heads=1, C=128, no ELU, mean==identity -> d_out fp32 ----
  k_gemm<<<dim3(2, N / 64), 256, 0, stream>>>(x2a_h, W3t, nullptr, 0, h_h, nullptr, N, 128, 256);
  k_scored<128, 1><<<N / 4, 256, 0, stream>>>(h_h, aS3, aD3, es, ed);
  k_agg<128, 1><<<N / 4, 256, 0, stream>>>(h_h, es, ed, b3, rowptr, col, 0, out, nullptr);
}

// Round 2
// 721.099 us; speedup vs baseline: 1.2538x; 1.2538x over previous
//
#include <hip/hip_runtime.h>

typedef _Float16 half_t;
typedef _Float16 half8  __attribute__((ext_vector_type(8)));
typedef _Float16 half4v __attribute__((ext_vector_type(4)));
typedef _Float16 half2v __attribute__((ext_vector_type(2)));
typedef float    f32x4  __attribute__((ext_vector_type(4)));

constexpr int N_NODES = 32768;
constexpr int NPG_    = 512;

#define MFMA16(a, b, c) __builtin_amdgcn_mfma_f32_16x16x32_f16((a), (b), (c), 0, 0, 0)

__device__ __forceinline__ void gload_lds16(const half_t* g, half_t* l) {
  __builtin_amdgcn_global_load_lds(
      (const __attribute__((address_space(1))) void*)g,
      (__attribute__((address_space(3))) void*)l, 16, 0, 0);
}

// ---------------- CSR build ----------------
__global__ void k_deg_init(int* __restrict__ deg) {
  deg[blockIdx.x * 256 + threadIdx.x] = 1;   // self-loop counts as 1
}

__global__ void k_hist(const int* __restrict__ dst, int* __restrict__ deg, int E) {
  int i = blockIdx.x * 256 + threadIdx.x;
  if (i < E) atomicAdd(&deg[dst[i]], 1);
}

__global__ __launch_bounds__(1024) void k_scan(const int* __restrict__ deg,
                                               int* __restrict__ rowptr) {
  __shared__ int part[1024];
  int t = threadIdx.x;
  int base = t * 32;
  int s = 0;
  #pragma unroll
  for (int i = 0; i < 32; i++) s += deg[base + i];
  part[t] = s;
  __syncthreads();
  for (int off = 1; off < 1024; off <<= 1) {
    int add = (t >= off) ? part[t - off] : 0;
    __syncthreads();
    part[t] += add;
    __syncthreads();
  }
  int run = (t == 0) ? 0 : part[t - 1];
  for (int i = 0; i < 32; i++) { rowptr[base + i] = run; run += deg[base + i]; }
  if (t == 1023) rowptr[N_NODES] = run;
}

__global__ void k_selfloop(const int* __restrict__ rowptr, int* __restrict__ fill,
                           int* __restrict__ col) {
  int i = blockIdx.x * 256 + threadIdx.x;
  fill[i] = 1;
  col[rowptr[i]] = i;   // self-loop is slot 0 of every dst
}

__global__ void k_scatter(const int* __restrict__ src, const int* __restrict__ dst,
                          const int* __restrict__ rowptr, int* __restrict__ fill,
                          int* __restrict__ col, int E) {
  int i = blockIdx.x * 256 + threadIdx.x;
  if (i < E) {
    int d = dst[i];
    int pos = rowptr[d] + atomicAdd(&fill[d], 1);
    col[pos] = src[i];
  }
}

// ---------------- conversions ----------------
__global__ void k_f2h(const float* __restrict__ in, half_t* __restrict__ out, int n) {
  int i = blockIdx.x * 256 + threadIdx.x;
  if (i < n) out[i] = (half_t)in[i];
}

// out[o*K + k] = W[k*Nc + o]  (transpose-convert: W is [K,Nc], out is [Nc,K])
__global__ void k_f2h_T(const float* __restrict__ W, half_t* __restrict__ out,
                        int K, int Nc) {
  int i = blockIdx.x * 256 + threadIdx.x;
  if (i < K * Nc) {
    int o = i / K, k = i % K;
    out[i] = (half_t)W[(size_t)k * Nc + o];
  }
}

// ---------------- GEMM: C[M,Nc] = A[M,K] @ Bt[Nc,K]^T (+bias) ----------------
// m97-style: 128x128 tile, BK=32, LDS staging via global_load_lds width=16.
// A, Bt fp16 K-major. Wave w computes 64x64: m-half (w&1), n-half (w>>1).
__global__ __launch_bounds__(256) void k_gemm(
    const half_t* __restrict__ A, const half_t* __restrict__ Bt,
    const float* __restrict__ bias, int bias_per_row,
    half_t* __restrict__ outh, float* __restrict__ outf,
    int M, int Nc, int K)
{
  __shared__ __align__(16) half_t As[128 * 32];
  __shared__ __align__(16) half_t Bs[128 * 32];
  int w = threadIdx.x >> 6, lane = threadIdx.x & 63;
  int r = lane & 15, q = lane >> 4;
  int m0 = blockIdx.y * 128, n0 = blockIdx.x * 128;
  int mh = (w & 1) * 64, nh = (w >> 1) * 64;
  f32x4 acc[4][4];
  #pragma unroll
  for (int i = 0; i < 4; i++)
    #pragma unroll
    for (int j = 0; j < 4; j++) acc[i][j] = f32x4{0.f, 0.f, 0.f, 0.f};

  int srow = lane >> 2;          // 0..15 within a 16-row slab
  int sch  = (lane & 3) * 8;     // 16B chunk within a 64B row

  for (int k0 = 0; k0 < K; k0 += 32) {
    __syncthreads();
    #pragma unroll
    for (int i = 0; i < 2; i++) {
      int R0 = i * 64 + w * 16;
      int row = R0 + srow;
      gload_lds16(A  + (size_t)(m0 + row) * K + k0 + sch, &As[R0 * 32]);
      gload_lds16(Bt + (size_t)(n0 + row) * K + k0 + sch, &Bs[R0 * 32]);
    }
    __syncthreads();
    half8 af[4], bf[4];
    #pragma unroll
    for (int t = 0; t < 4; t++) af[t] = *(const half8*)&As[(mh + t * 16 + r) * 32 + q * 8];
    #pragma unroll
    for (int t = 0; t < 4; t++) bf[t] = *(const half8*)&Bs[(nh + t * 16 + r) * 32 + q * 8];
    #pragma unroll
    for (int ti = 0; ti < 4; ti++)
      #pragma unroll
      for (int tj = 0; tj < 4; tj++)
        acc[ti][tj] = MFMA16(af[ti], bf[tj], acc[ti][tj]);
  }

  #pragma unroll
  for (int tj = 0; tj < 4; tj++) {
    int colc = n0 + nh + tj * 16 + r;
    #pragma unroll
    for (int ti = 0; ti < 4; ti++) {
      #pragma unroll
      for (int i = 0; i < 4; i++) {
        int row = m0 + mh + ti * 16 + q * 4 + i;
        float bv = bias ? (bias_per_row ? bias[row] : bias[colc]) : 0.f;
        float v = acc[ti][tj][i] + bv;
        size_t idx = (size_t)row * Nc + colc;
        if (outf) outf[idx] = v;
        if (outh) outh[idx] = (half_t)v;
      }
    }
  }
}

// ---------------- per-node attention scores es/ed ----------------
template<int HC, int H>
__global__ __launch_bounds__(256) void k_scored(
    const half_t* __restrict__ h, const float* __restrict__ aS,
    const float* __restrict__ aD, float* __restrict__ es, float* __restrict__ ed)
{
  constexpr int VPT = HC / 64;
  constexpr int LPH = 64 / H;     // lanes per head
  int lane = threadIdx.x & 63;
  int n = blockIdx.x * 4 + (threadIdx.x >> 6);
  const half_t* hp = h + (size_t)n * HC + lane * VPT;
  float ps = 0.f, pd = 0.f;
  #pragma unroll
  for (int i = 0; i < VPT; i++) {
    float v = (float)hp[i];
    ps += v * aS[lane * VPT + i];
    pd += v * aD[lane * VPT + i];
  }
  #pragma unroll
  for (int off = 1; off < LPH; off <<= 1) {
    ps += __shfl_xor(ps, off);
    pd += __shfl_xor(pd, off);
  }
  if ((lane & (LPH - 1)) == 0) {
    es[(size_t)n * H + lane / LPH] = ps;
    ed[(size_t)n * H + lane / LPH] = pd;
  }
}

// ---------------- edge-softmax aggregation (one wave per dst) ----------------
template<int HC, int H>
__global__ __launch_bounds__(256) void k_agg(
    const half_t* __restrict__ h, const float* __restrict__ es,
    const float* __restrict__ ed, const float* __restrict__ bias,
    const int* __restrict__ rowptr, const int* __restrict__ col, int elu,
    float* __restrict__ outf, half_t* __restrict__ outh)
{
  constexpr int VPT = HC / 64;
  constexpr int C = HC / H;
  int lane = threadIdx.x & 63;
  int n = blockIdx.x * 4 + (threadIdx.x >> 6);
  int hl = (lane * VPT) / C;
  float edn = ed[(size_t)n * H + hl];
  int j0 = rowptr[n], j1 = rowptr[n + 1];
  float m = -1e30f;
  for (int j = j0; j < j1; j++) {
    int s = col[j];
    float e = es[(size_t)s * H + hl] + edn;
    e = (e >= 0.f) ? e : 0.2f * e;          // LeakyReLU(0.2)
    m = fmaxf(m, e);
  }
  float sum = 0.f;
  float acc[VPT];
  #pragma unroll
  for (int i = 0; i < VPT; i++) acc[i] = 0.f;
  for (int j = j0; j < j1; j++) {
    int s = col[j];
    float e = es[(size_t)s * H + hl] + edn;
    e = (e >= 0.f) ? e : 0.2f * e;
    float p = __expf(e - m);
    sum += p;
    const half_t* hp = h + (size_t)s * HC + lane * VPT;
    if constexpr (VPT == 4) {
      half4v hv = *(const half4v*)hp;
      acc[0] += p * (float)hv[0]; acc[1] += p * (float)hv[1];
      acc[2] += p * (float)hv[2]; acc[3] += p * (float)hv[3];
    } else {
      half2v hv = *(const half2v*)hp;
      acc[0] += p * (float)hv[0]; acc[1] += p * (float)hv[1];
    }
  }
  float inv = 1.f / sum;
  #pragma unroll
  for (int i = 0; i < VPT; i++) {
    int c = lane * VPT + i;
    float v = acc[i] * inv + bias[c];
    if (elu) v = (v > 0.f) ? v : __expf(v) - 1.f;   // jax.nn.elu
    if (outf) outf[(size_t)n * HC + c] = v;
    if (outh) outh[(size_t)n * HC + c] = (half_t)v;
  }
}

// ---------------- MHA core: block = (pair, 64 q-rows), LDS-resident ----------------
// qk: [N,512] fp16 (Q | K). vt: [256,32768] fp16 = V^T.
// K slab (512x64) staged into LDS (xor-swizzled 16B chunks, swizzle applied on the
// GLOBAL source address so the lane-linear global_load_lds dest stays legal);
// after S is computed the same region is overwritten with the V^T slab (64x512).
__global__ __launch_bounds__(256) void k_attn(
    const half_t* __restrict__ qk, const half_t* __restrict__ vt,
    half_t* __restrict__ o)
{
  __shared__ __align__(16) half_t KV[32768];     // 64 KB: K[512][64] then V[64][512]
  __shared__ __align__(16) half_t SP[64][520];   // scores -> probabilities
  __shared__ float rowmax[64];
  __shared__ float rowsum[64];

  int pair = blockIdx.x;            // 0..255 = graph*4 + head  (pins pair -> XCD)
  int b = pair >> 2, hh = pair & 3;
  int q0 = blockIdx.y * 64;         // q-chunk base within graph
  int w = threadIdx.x >> 6, lane = threadIdx.x & 63;
  int r = lane & 15, q = lane >> 4;

  // ---- stage K slab: row=key (512), 8 chunks of 16B ----
  {
    const half_t* kbase = qk + ((size_t)(b * NPG_) * 512 + 256 + hh * 64);
    int key_off = lane >> 3;         // 0..7
    int cl = lane & 7;
    #pragma unroll
    for (int i = 0; i < 16; i++) {
      int R0 = (i * 4 + w) * 8;
      int key = R0 + key_off;
      int cg = cl ^ (key & 7);
      gload_lds16(kbase + (size_t)key * 512 + cg * 8, &KV[R0 * 64]);
    }
  }
  __syncthreads();

  // ---- phase 1: S = Q K^T / 8, row max tracked in registers ----
  {
    const half_t* Qp = qk + ((size_t)(b * NPG_ + q0 + w * 16 + r) * 512 + hh * 64);
    half8 qa0 = *(const half8*)(Qp + q * 8);
    half8 qa1 = *(const half8*)(Qp + 32 + q * 8);
    int sw = r & 7;
    float mloc[4] = {-1e30f, -1e30f, -1e30f, -1e30f};
    for (int ct = 0; ct < 32; ct++) {
      int key = ct * 16 + r;
      half8 b0 = *(const half8*)&KV[key * 64 + ((q ^ sw) << 3)];
      half8 b1 = *(const half8*)&KV[key * 64 + (((4 + q) ^ sw) << 3)];
      f32x4 acc = f32x4{0.f, 0.f, 0.f, 0.f};
      acc = MFMA16(qa0, b0, acc);
      acc = MFMA16(qa1, b1, acc);
      #pragma unroll
      for (int i = 0; i < 4; i++) {
        float v = acc[i] * 0.125f;
        mloc[i] = fmaxf(mloc[i], v);
        SP[w * 16 + q * 4 + i][ct * 16 + r] = (half_t)v;
      }
    }
    #pragma unroll
    for (int off = 1; off < 16; off <<= 1)
      #pragma unroll
      for (int i = 0; i < 4; i++) mloc[i] = fmaxf(mloc[i], __shfl_xor(mloc[i], off));
    if (r == 0)
      #pragma unroll
      for (int i = 0; i < 4; i++) rowmax[w * 16 + q * 4 + i] = mloc[i];
  }
  __syncthreads();

  // ---- stage V slab over K region (async; overlaps softmax VALU) ----
  {
    const half_t* vbase = vt + ((size_t)(hh * 64) * 32768 + b * NPG_);
    #pragma unroll
    for (int i = 0; i < 16; i++) {
      int d = i * 4 + w;
      int cg = lane ^ (d & 7);
      gload_lds16(vbase + (size_t)d * 32768 + cg * 8, &KV[d * 512]);
    }
  }

  // ---- phase 2: softmax on own rows (exp + rowsum), P written back fp16 ----
  {
    int row = w * 16 + (lane >> 2);
    float mx = rowmax[row];
    float sm = 0.f;
    #pragma unroll
    for (int j = 0; j < 16; j++) {
      int ch = (lane & 3) + j * 4;
      half8* p = (half8*)&SP[row][ch * 8];
      half8 hv = *p;
      half8 ov;
      #pragma unroll
      for (int t = 0; t < 8; t++) {
        float pv = __expf((float)hv[t] - mx);
        sm += pv;
        ov[t] = (half_t)pv;
      }
      *p = ov;
    }
    sm += __shfl_xor(sm, 1);
    sm += __shfl_xor(sm, 2);
    if ((lane & 3) == 0) rowsum[row] = sm;
  }
  __syncthreads();   // drains V staging (vmcnt) + makes P/rowsum visible

  // ---- phase 3: O = P V from LDS ----
  {
    f32x4 oacc[4];
    #pragma unroll
    for (int t = 0; t < 4; t++) oacc[t] = f32x4{0.f, 0.f, 0.f, 0.f};
    int sw = r & 7;
    for (int ks = 0; ks < 16; ks++) {
      half8 a = *(const half8*)&SP[w * 16 + r][ks * 32 + q * 8];
      #pragma unroll
      for (int nt = 0; nt < 4; nt++) {
        int d = nt * 16 + r;
        half8 bb = *(const half8*)&KV[d * 512 + (((ks * 4 + q) ^ sw) << 3)];
        oacc[nt] = MFMA16(a, bb, oacc[nt]);
      }
    }
    #pragma unroll
    for (int nt = 0; nt < 4; nt++) {
      #pragma unroll
      for (int i = 0; i < 4; i++) {
        int row = w * 16 + q * 4 + i;
        float v = oacc[nt][i] / rowsum[row];
        int node = b * NPG_ + q0 + row;
        o[(size_t)node * 256 + hh * 64 + nt * 16 + r] = (half_t)v;
      }
    }
  }
}

// ---------------- residual + LayerNorm -> fp16 ----------------
__global__ __launch_bounds__(256) void k_ln(
    const float* __restrict__ att, const float* __restrict__ x2,
    const float* __restrict__ gamma, const float* __restrict__ beta,
    half_t* __restrict__ outh)
{
  int lane = threadIdx.x & 63;
  int n = blockIdx.x * 4 + (threadIdx.x >> 6);
  size_t base = (size_t)n * 256 + lane * 4;
  float4 a  = *(const float4*)(att + base);
  float4 xx = *(const float4*)(x2 + base);
  float v[4] = {a.x + xx.x, a.y + xx.y, a.z + xx.z, a.w + xx.w};
  float s  = v[0] + v[1] + v[2] + v[3];
  float ss = v[0]*v[0] + v[1]*v[1] + v[2]*v[2] + v[3]*v[3];
  #pragma unroll
  for (int off = 1; off < 64; off <<= 1) {
    s  += __shfl_xor(s, off);
    ss += __shfl_xor(ss, off);
  }
  float mean = s * (1.f / 256.f);
  float var  = ss * (1.f / 256.f) - mean * mean;
  float rstd = rsqrtf(var + 1e-5f);
  #pragma unroll
  for (int i = 0; i < 4; i++) {
    int c = lane * 4 + i;
    outh[(size_t)n * 256 + c] = (half_t)((v[i] - mean) * rstd * gamma[c] + beta[c]);
  }
}

// ---------------- host ----------------
extern "C" void kernel_launch(void* const* d_in, const int* in_sizes, int n_in,
                              void* d_out, int out_size, void* d_ws, size_t ws_size,
                              hipStream_t stream)
{
  const float* x    = (const float*)d_in[0];
  const int*   ei   = (const int*)d_in[1];
  const float* W1   = (const float*)d_in[3];
  const float* aS1  = (const float*)d_in[4];
  const float* aD1  = (const float*)d_in[5];
  const float* b1   = (const float*)d_in[6];
  const float* W2   = (const float*)d_in[7];
  const float* aS2  = (const float*)d_in[8];
  const float* aD2  = (const float*)d_in[9];
  const float* b2   = (const float*)d_in[10];
  const float* W3   = (const float*)d_in[11];
  const float* aS3  = (const float*)d_in[12];
  const float* aD3  = (const float*)d_in[13];
  const float* b3   = (const float*)d_in[14];
  const float* Wi   = (const float*)d_in[15];
  const float* bi   = (const float*)d_in[16];
  const float* Wo   = (const float*)d_in[17];
  const float* bo   = (const float*)d_in[18];
  const float* gam  = (const float*)d_in[19];
  const float* bet  = (const float*)d_in[20];
  float* out = (float*)d_out;
  const int N = N_NODES;
  int E = in_sizes[1] / 2;

  char* ws = (char*)d_ws;
  size_t off = 0;
  auto alloc = [&](size_t bytes) -> void* {
    void* p = ws + off;
    off = (off + bytes + 255) & ~(size_t)255;
    return p;
  };
  half_t* x_h    = (half_t*)alloc((size_t)N * 128 * 2);
  half_t* h_h    = (half_t*)alloc((size_t)N * 256 * 2);   // h1/h2/h3
  half_t* x1_h   = (half_t*)alloc((size_t)N * 256 * 2);
  float*  x2_f   = (float*) alloc((size_t)N * 256 * 4);
  half_t* x2_h   = (half_t*)alloc((size_t)N * 256 * 2);
  half_t* qk_h   = (half_t*)alloc((size_t)N * 512 * 2);
  half_t* vt_h   = (half_t*)alloc((size_t)256 * N * 2);   // V^T: [256][32768]
  half_t* o_h    = (half_t*)alloc((size_t)N * 256 * 2);
  float*  att_f  = (float*) alloc((size_t)N * 256 * 4);
  half_t* x2a_h  = (half_t*)alloc((size_t)N * 256 * 2);
  half_t* W1t    = (half_t*)alloc(256 * 128 * 2);
  half_t* W2t    = (half_t*)alloc(256 * 256 * 2);
  half_t* W3t    = (half_t*)alloc(128 * 256 * 2);
  half_t* Wi_h   = (half_t*)alloc(768 * 256 * 2);
  half_t* Wo_h   = (half_t*)alloc(256 * 256 * 2);
  float*  es     = (float*) alloc((size_t)N * 4 * 4);
  float*  ed     = (float*) alloc((size_t)N * 4 * 4);
  int*    deg    = (int*)   alloc((size_t)N * 4);
  int*    fill   = (int*)   alloc((size_t)N * 4);
  int*    rowptr = (int*)   alloc(((size_t)N + 1) * 4);
  int*    col    = (int*)   alloc((size_t)(N + E) * 4);

  const int* srcE = ei;
  const int* dstE = ei + E;

  // CSR by destination (self-loop first in every row)
  k_deg_init<<<N / 256, 256, 0, stream>>>(deg);
  k_hist<<<(E + 255) / 256, 256, 0, stream>>>(dstE, deg, E);
  k_scan<<<1, 1024, 0, stream>>>(deg, rowptr);
  k_selfloop<<<N / 256, 256, 0, stream>>>(rowptr, fill, col);
  k_scatter<<<(E + 255) / 256, 256, 0, stream>>>(srcE, dstE, rowptr, fill, col, E);

  // fp16 conversions
  k_f2h<<<(N * 128 + 255) / 256, 256, 0, stream>>>(x, x_h, N * 128);
  k_f2h_T<<<(256 * 128 + 255) / 256, 256, 0, stream>>>(W1, W1t, 128, 256);
  k_f2h_T<<<(256 * 256 + 255) / 256, 256, 0, stream>>>(W2, W2t, 256, 256);
  k_f2h_T<<<(128 * 256 + 255) / 256, 256, 0, stream>>>(W3, W3t, 256, 128);
  k_f2h<<<(768 * 256 + 255) / 256, 256, 0, stream>>>(Wi, Wi_h, 768 * 256);
  k_f2h<<<(256 * 256 + 255) / 256, 256, 0, stream>>>(Wo, Wo_h, 256 * 256);

  // ---- GAT1: h1 = x @ W1 ; edge softmax ; ELU -> x1 ----
  k_gemm<<<dim3(2, N / 128), 256, 0, stream>>>(x_h, W1t, nullptr, 0, h_h, nullptr, N, 256, 128);
  k_scored<256, 4><<<N / 4, 256, 0, stream>>>(h_h, aS1, aD1, es, ed);
  k_agg<256, 4><<<N / 4, 256, 0, stream>>>(h_h, es, ed, b1, rowptr, col, 1, nullptr, x1_h);

  // ---- GAT2 -> x2 (fp32 for residual/LN + fp16 for QKV) ----
  k_gemm<<<dim3(2, N / 128), 256, 0, stream>>>(x1_h, W2t, nullptr, 0, h_h, nullptr, N, 256, 256);
  k_scored<256, 4><<<N / 4, 256, 0, stream>>>(h_h, aS2, aD2, es, ed);
  k_agg<256, 4><<<N / 4, 256, 0, stream>>>(h_h, es, ed, b2, rowptr, col, 1, x2_f, x2_h);

  // ---- MHA: QK projection [N,512]; V projected transposed [256,N] ----
  k_gemm<<<dim3(4, N / 128), 256, 0, stream>>>(x2_h, Wi_h, bi, 0, qk_h, nullptr, N, 512, 256);
  k_gemm<<<dim3(N / 128, 2), 256, 0, stream>>>(Wi_h + 512 * 256, x2_h, bi + 512, 1,
                                               vt_h, nullptr, 256, N, 256);
  k_attn<<<dim3(256, 8), 256, 0, stream>>>(qk_h, vt_h, o_h);
  k_gemm<<<dim3(2, N / 128), 256, 0, stream>>>(o_h, Wo_h, bo, 0, nullptr, att_f, N, 256, 256);

  // ---- residual + LayerNorm -> x2a (fp16) ----
  k_ln<<<N / 4, 256, 0, stream>>>(att_f, x2_f, gam, bet, x2a_h);

  // ---- GAT3: heads=1, C=128, no ELU, mean==identity -> d_out fp32 ----
  k_gemm<<<dim3(1, N / 128), 256, 0, stream>>>(x2a_h, W3t, nullptr, 0, h_h, nullptr, N, 128, 256);
  k_scored<128, 1><<<N / 4, 256, 0, stream>>>(h_h, aS3, aD3, es, ed);
  k_agg<128, 1><<<N / 4, 256, 0, stream>>>(h_h, es, ed, b3, rowptr, col, 0, out, nullptr);
}

// Round 3
// 559.021 us; speedup vs baseline: 1.6173x; 1.2899x over previous
//
#include <hip/hip_runtime.h>

typedef _Float16 half_t;
typedef _Float16 half8  __attribute__((ext_vector_type(8)));
typedef _Float16 half4v __attribute__((ext_vector_type(4)));
typedef _Float16 half2v __attribute__((ext_vector_type(2)));
typedef float    f32x4  __attribute__((ext_vector_type(4)));

constexpr int N_NODES = 32768;
constexpr int NPG_    = 512;

#define MFMA16(a, b, c) __builtin_amdgcn_mfma_f32_16x16x32_f16((a), (b), (c), 0, 0, 0)

__device__ __forceinline__ void gload_lds16(const half_t* g, half_t* l) {
  __builtin_amdgcn_global_load_lds(
      (const __attribute__((address_space(1))) void*)g,
      (__attribute__((address_space(3))) void*)l, 16, 0, 0);
}

// ---------------- CSR build ----------------
__global__ void k_deg_init(int* __restrict__ deg) {
  deg[blockIdx.x * 256 + threadIdx.x] = 1;   // self-loop counts as 1
}

__global__ void k_hist(const int* __restrict__ dst, int* __restrict__ deg, int E) {
  int i = blockIdx.x * 256 + threadIdx.x;
  if (i < E) atomicAdd(&deg[dst[i]], 1);
}

__global__ __launch_bounds__(1024) void k_scan(const int* __restrict__ deg,
                                               int* __restrict__ rowptr) {
  __shared__ int part[1024];
  int t = threadIdx.x;
  int base = t * 32;
  int s = 0;
  #pragma unroll
  for (int i = 0; i < 32; i++) s += deg[base + i];
  part[t] = s;
  __syncthreads();
  for (int off = 1; off < 1024; off <<= 1) {
    int add = (t >= off) ? part[t - off] : 0;
    __syncthreads();
    part[t] += add;
    __syncthreads();
  }
  int run = (t == 0) ? 0 : part[t - 1];
  for (int i = 0; i < 32; i++) { rowptr[base + i] = run; run += deg[base + i]; }
  if (t == 1023) rowptr[N_NODES] = run;
}

__global__ void k_selfloop(const int* __restrict__ rowptr, int* __restrict__ fill,
                           int* __restrict__ col) {
  int i = blockIdx.x * 256 + threadIdx.x;
  fill[i] = 1;
  col[rowptr[i]] = i;   // self-loop is slot 0 of every dst
}

__global__ void k_scatter(const int* __restrict__ src, const int* __restrict__ dst,
                          const int* __restrict__ rowptr, int* __restrict__ fill,
                          int* __restrict__ col, int E) {
  int i = blockIdx.x * 256 + threadIdx.x;
  if (i < E) {
    int d = dst[i];
    int pos = rowptr[d] + atomicAdd(&fill[d], 1);
    col[pos] = src[i];
  }
}

// ---------------- conversions ----------------
__global__ void k_f2h(const float* __restrict__ in, half_t* __restrict__ out, int n) {
  int i = blockIdx.x * 256 + threadIdx.x;
  if (i < n) out[i] = (half_t)in[i];
}

// out[o*K + k] = W[k*Nc + o]  (transpose-convert: W is [K,Nc], out is [Nc,K])
__global__ void k_f2h_T(const float* __restrict__ W, half_t* __restrict__ out,
                        int K, int Nc) {
  int i = blockIdx.x * 256 + threadIdx.x;
  if (i < K * Nc) {
    int o = i / K, k = i % K;
    out[i] = (half_t)W[(size_t)k * Nc + o];
  }
}

// ---------------- GEMM: C[M,Nc] = A[M,K] @ Bt[Nc,K]^T (+bias) ----------------
// m97-style: 128x128 tile, BK=32, LDS staging via global_load_lds width=16.
__global__ __launch_bounds__(256) void k_gemm(
    const half_t* __restrict__ A, const half_t* __restrict__ Bt,
    const float* __restrict__ bias, int bias_per_row,
    half_t* __restrict__ outh, float* __restrict__ outf,
    int M, int Nc, int K)
{
  __shared__ __align__(16) half_t As[128 * 32];
  __shared__ __align__(16) half_t Bs[128 * 32];
  int w = threadIdx.x >> 6, lane = threadIdx.x & 63;
  int r = lane & 15, q = lane >> 4;
  int m0 = blockIdx.y * 128, n0 = blockIdx.x * 128;
  int mh = (w & 1) * 64, nh = (w >> 1) * 64;
  f32x4 acc[4][4];
  #pragma unroll
  for (int i = 0; i < 4; i++)
    #pragma unroll
    for (int j = 0; j < 4; j++) acc[i][j] = f32x4{0.f, 0.f, 0.f, 0.f};

  int srow = lane >> 2;          // 0..15 within a 16-row slab
  int sch  = (lane & 3) * 8;     // 16B chunk within a 64B row

  for (int k0 = 0; k0 < K; k0 += 32) {
    __syncthreads();
    #pragma unroll
    for (int i = 0; i < 2; i++) {
      int R0 = i * 64 + w * 16;
      int row = R0 + srow;
      gload_lds16(A  + (size_t)(m0 + row) * K + k0 + sch, &As[R0 * 32]);
      gload_lds16(Bt + (size_t)(n0 + row) * K + k0 + sch, &Bs[R0 * 32]);
    }
    __syncthreads();
    half8 af[4], bf[4];
    #pragma unroll
    for (int t = 0; t < 4; t++) af[t] = *(const half8*)&As[(mh + t * 16 + r) * 32 + q * 8];
    #pragma unroll
    for (int t = 0; t < 4; t++) bf[t] = *(const half8*)&Bs[(nh + t * 16 + r) * 32 + q * 8];
    #pragma unroll
    for (int ti = 0; ti < 4; ti++)
      #pragma unroll
      for (int tj = 0; tj < 4; tj++)
        acc[ti][tj] = MFMA16(af[ti], bf[tj], acc[ti][tj]);
  }

  #pragma unroll
  for (int tj = 0; tj < 4; tj++) {
    int colc = n0 + nh + tj * 16 + r;
    #pragma unroll
    for (int ti = 0; ti < 4; ti++) {
      #pragma unroll
      for (int i = 0; i < 4; i++) {
        int row = m0 + mh + ti * 16 + q * 4 + i;
        float bv = bias ? (bias_per_row ? bias[row] : bias[colc]) : 0.f;
        float v = acc[ti][tj][i] + bv;
        size_t idx = (size_t)row * Nc + colc;
        if (outf) outf[idx] = v;
        if (outh) outh[idx] = (half_t)v;
      }
    }
  }
}

// ---------------- per-node attention scores es/ed ----------------
template<int HC, int H>
__global__ __launch_bounds__(256) void k_scored(
    const half_t* __restrict__ h, const float* __restrict__ aS,
    const float* __restrict__ aD, float* __restrict__ es, float* __restrict__ ed)
{
  constexpr int VPT = HC / 64;
  constexpr int LPH = 64 / H;     // lanes per head
  int lane = threadIdx.x & 63;
  int n = blockIdx.x * 4 + (threadIdx.x >> 6);
  const half_t* hp = h + (size_t)n * HC + lane * VPT;
  float ps = 0.f, pd = 0.f;
  #pragma unroll
  for (int i = 0; i < VPT; i++) {
    float v = (float)hp[i];
    ps += v * aS[lane * VPT + i];
    pd += v * aD[lane * VPT + i];
  }
  #pragma unroll
  for (int off = 1; off < LPH; off <<= 1) {
    ps += __shfl_xor(ps, off);
    pd += __shfl_xor(pd, off);
  }
  if ((lane & (LPH - 1)) == 0) {
    es[(size_t)n * H + lane / LPH] = ps;
    ed[(size_t)n * H + lane / LPH] = pd;
  }
}

// ---------------- edge-softmax aggregation (one wave per dst) ----------------
// Single pass, max-free softmax (|e| <= ~12 here; fp32 exp safe to e~88;
// exp(e)/sum(exp) is mathematically identical to the max-subtracted form).
// 4-edge unroll with 4 independent accumulator sets for memory-level parallelism.
template<int HC, int H>
__global__ __launch_bounds__(256) void k_agg(
    const half_t* __restrict__ h, const float* __restrict__ es,
    const float* __restrict__ ed, const float* __restrict__ bias,
    const int* __restrict__ rowptr, const int* __restrict__ col, int elu,
    float* __restrict__ outf, half_t* __restrict__ outh)
{
  constexpr int VPT = HC / 64;
  constexpr int C = HC / H;
  int lane = threadIdx.x & 63;
  int n = blockIdx.x * 4 + (threadIdx.x >> 6);
  int hl = (lane * VPT) / C;
  float edn = ed[(size_t)n * H + hl];
  int j0 = rowptr[n], j1 = rowptr[n + 1];
  int cbase = lane * VPT;

  float sum[4] = {0.f, 0.f, 0.f, 0.f};
  float acc[4][VPT];
  #pragma unroll
  for (int k = 0; k < 4; k++)
    #pragma unroll
    for (int i = 0; i < VPT; i++) acc[k][i] = 0.f;

  for (int j = j0; j < j1; j += 4) {
    int   s[4];
    float e[4];
    #pragma unroll
    for (int k = 0; k < 4; k++) {
      int jj = j + k;
      int jc = (jj < j1) ? jj : (j1 - 1);
      s[k] = col[jc];
      float ev = es[(size_t)s[k] * H + hl] + edn;
      ev = fmaxf(ev, 0.2f * ev);              // LeakyReLU(0.2)
      e[k] = (jj < j1) ? ev : -1e30f;         // padded edge -> exp = 0
    }
    #pragma unroll
    for (int k = 0; k < 4; k++) {
      float p = __expf(e[k]);
      sum[k] += p;
      const half_t* hp = h + (size_t)s[k] * HC + cbase;
      if constexpr (VPT == 4) {
        half4v hv = *(const half4v*)hp;
        acc[k][0] += p * (float)hv[0]; acc[k][1] += p * (float)hv[1];
        acc[k][2] += p * (float)hv[2]; acc[k][3] += p * (float)hv[3];
      } else {
        half2v hv = *(const half2v*)hp;
        acc[k][0] += p * (float)hv[0]; acc[k][1] += p * (float)hv[1];
      }
    }
  }

  float ssum = (sum[0] + sum[1]) + (sum[2] + sum[3]);
  float inv = 1.f / ssum;
  #pragma unroll
  for (int i = 0; i < VPT; i++) {
    float a = (acc[0][i] + acc[1][i]) + (acc[2][i] + acc[3][i]);
    int c = cbase + i;
    float v = a * inv + bias[c];
    if (elu) v = (v > 0.f) ? v : __expf(v) - 1.f;   // jax.nn.elu
    if (outf) outf[(size_t)n * HC + c] = v;
    if (outh) outh[(size_t)n * HC + c] = (half_t)v;
  }
}

// ---------------- MHA core: block = (pair, 64 q-rows), LDS-resident ----------------
__global__ __launch_bounds__(256) void k_attn(
    const half_t* __restrict__ qk, const half_t* __restrict__ vt,
    half_t* __restrict__ o)
{
  __shared__ __align__(16) half_t KV[32768];     // 64 KB: K[512][64] then V[64][512]
  __shared__ __align__(16) half_t SP[64][520];   // scores -> probabilities
  __shared__ float rowmax[64];
  __shared__ float rowsum[64];

  int pair = blockIdx.x;            // 0..255 = graph*4 + head  (pins pair -> XCD)
  int b = pair >> 2, hh = pair & 3;
  int q0 = blockIdx.y * 64;         // q-chunk base within graph
  int w = threadIdx.x >> 6, lane = threadIdx.x & 63;
  int r = lane & 15, q = lane >> 4;

  // ---- stage K slab: row=key (512), 8 chunks of 16B, xor-swizzled on source ----
  {
    const half_t* kbase = qk + ((size_t)(b * NPG_) * 512 + 256 + hh * 64);
    int key_off = lane >> 3;         // 0..7
    int cl = lane & 7;
    #pragma unroll
    for (int i = 0; i < 16; i++) {
      int R0 = (i * 4 + w) * 8;
      int key = R0 + key_off;
      int cg = cl ^ (key & 7);
      gload_lds16(kbase + (size_t)key * 512 + cg * 8, &KV[R0 * 64]);
    }
  }
  __syncthreads();

  // ---- phase 1: S = Q K^T / 8, row max tracked in registers ----
  {
    const half_t* Qp = qk + ((size_t)(b * NPG_ + q0 + w * 16 + r) * 512 + hh * 64);
    half8 qa0 = *(const half8*)(Qp + q * 8);
    half8 qa1 = *(const half8*)(Qp + 32 + q * 8);
    int sw = r & 7;
    float mloc[4] = {-1e30f, -1e30f, -1e30f, -1e30f};
    for (int ct = 0; ct < 32; ct++) {
      int key = ct * 16 + r;
      half8 b0 = *(const half8*)&KV[key * 64 + ((q ^ sw) << 3)];
      half8 b1 = *(const half8*)&KV[key * 64 + (((4 + q) ^ sw) << 3)];
      f32x4 acc = f32x4{0.f, 0.f, 0.f, 0.f};
      acc = MFMA16(qa0, b0, acc);
      acc = MFMA16(qa1, b1, acc);
      #pragma unroll
      for (int i = 0; i < 4; i++) {
        float v = acc[i] * 0.125f;
        mloc[i] = fmaxf(mloc[i], v);
        SP[w * 16 + q * 4 + i][ct * 16 + r] = (half_t)v;
      }
    }
    #pragma unroll
    for (int off = 1; off < 16; off <<= 1)
      #pragma unroll
      for (int i = 0; i < 4; i++) mloc[i] = fmaxf(mloc[i], __shfl_xor(mloc[i], off));
    if (r == 0)
      #pragma unroll
      for (int i = 0; i < 4; i++) rowmax[w * 16 + q * 4 + i] = mloc[i];
  }
  __syncthreads();

  // ---- stage V slab over K region (async; overlaps softmax VALU) ----
  {
    const half_t* vbase = vt + ((size_t)(hh * 64) * 32768 + b * NPG_);
    #pragma unroll
    for (int i = 0; i < 16; i++) {
      int d = i * 4 + w;
      int cg = lane ^ (d & 7);
      gload_lds16(vbase + (size_t)d * 32768 + cg * 8, &KV[d * 512]);
    }
  }

  // ---- phase 2: softmax on own rows (exp + rowsum), P written back fp16 ----
  {
    int row = w * 16 + (lane >> 2);
    float mx = rowmax[row];
    float sm = 0.f;
    #pragma unroll
    for (int j = 0; j < 16; j++) {
      int ch = (lane & 3) + j * 4;
      half8* p = (half8*)&SP[row][ch * 8];
      half8 hv = *p;
      half8 ov;
      #pragma unroll
      for (int t = 0; t < 8; t++) {
        float pv = __expf((float)hv[t] - mx);
        sm += pv;
        ov[t] = (half_t)pv;
      }
      *p = ov;
    }
    sm += __shfl_xor(sm, 1);
    sm += __shfl_xor(sm, 2);
    if ((lane & 3) == 0) rowsum[row] = sm;
  }
  __syncthreads();   // drains V staging (vmcnt) + makes P/rowsum visible

  // ---- phase 3: O = P V from LDS ----
  {
    f32x4 oacc[4];
    #pragma unroll
    for (int t = 0; t < 4; t++) oacc[t] = f32x4{0.f, 0.f, 0.f, 0.f};
    int sw = r & 7;
    for (int ks = 0; ks < 16; ks++) {
      half8 a = *(const half8*)&SP[w * 16 + r][ks * 32 + q * 8];
      #pragma unroll
      for (int nt = 0; nt < 4; nt++) {
        int d = nt * 16 + r;
        half8 bb = *(const half8*)&KV[d * 512 + (((ks * 4 + q) ^ sw) << 3)];
        oacc[nt] = MFMA16(a, bb, oacc[nt]);
      }
    }
    #pragma unroll
    for (int nt = 0; nt < 4; nt++) {
      #pragma unroll
      for (int i = 0; i < 4; i++) {
        int row = w * 16 + q * 4 + i;
        float v = oacc[nt][i] / rowsum[row];
        int node = b * NPG_ + q0 + row;
        o[(size_t)node * 256 + hh * 64 + nt * 16 + r] = (half_t)v;
      }
    }
  }
}

// ---------------- residual + LayerNorm -> fp16 ----------------
__global__ __launch_bounds__(256) void k_ln(
    const float* __restrict__ att, const float* __restrict__ x2,
    const float* __restrict__ gamma, const float* __restrict__ beta,
    half_t* __restrict__ outh)
{
  int lane = threadIdx.x & 63;
  int n = blockIdx.x * 4 + (threadIdx.x >> 6);
  size_t base = (size_t)n * 256 + lane * 4;
  float4 a  = *(const float4*)(att + base);
  float4 xx = *(const float4*)(x2 + base);
  float v[4] = {a.x + xx.x, a.y + xx.y, a.z + xx.z, a.w + xx.w};
  float s  = v[0] + v[1] + v[2] + v[3];
  float ss = v[0]*v[0] + v[1]*v[1] + v[2]*v[2] + v[3]*v[3];
  #pragma unroll
  for (int off = 1; off < 64; off <<= 1) {
    s  += __shfl_xor(s, off);
    ss += __shfl_xor(ss, off);
  }
  float mean = s * (1.f / 256.f);
  float var  = ss * (1.f / 256.f) - mean * mean;
  float rstd = rsqrtf(var + 1e-5f);
  #pragma unroll
  for (int i = 0; i < 4; i++) {
    int c = lane * 4 + i;
    outh[(size_t)n * 256 + c] = (half_t)((v[i] - mean) * rstd * gamma[c] + beta[c]);
  }
}

// ---------------- host ----------------
extern "C" void kernel_launch(void* const* d_in, const int* in_sizes, int n_in,
                              void* d_out, int out_size, void* d_ws, size_t ws_size,
                              hipStream_t stream)
{
  const float* x    = (const float*)d_in[0];
  const int*   ei   = (const int*)d_in[1];
  const float* W1   = (const float*)d_in[3];
  const float* aS1  = (const float*)d_in[4];
  const float* aD1  = (const float*)d_in[5];
  const float* b1   = (const float*)d_in[6];
  const float* W2   = (const float*)d_in[7];
  const float* aS2  = (const float*)d_in[8];
  const float* aD2  = (const float*)d_in[9];
  const float* b2   = (const float*)d_in[10];
  const float* W3   = (const float*)d_in[11];
  const float* aS3  = (const float*)d_in[12];
  const float* aD3  = (const float*)d_in[13];
  const float* b3   = (const float*)d_in[14];
  const float* Wi   = (const float*)d_in[15];
  const float* bi   = (const float*)d_in[16];
  const float* Wo   = (const float*)d_in[17];
  const float* bo   = (const float*)d_in[18];
  const float* gam  = (const float*)d_in[19];
  const float* bet  = (const float*)d_in[20];
  float* out = (float*)d_out;
  const int N = N_NODES;
  int E = in_sizes[1] / 2;

  char* ws = (char*)d_ws;
  size_t off = 0;
  auto alloc = [&](size_t bytes) -> void* {
    void* p = ws + off;
    off = (off + bytes + 255) & ~(size_t)255;
    return p;
  };
  half_t* x_h    = (half_t*)alloc((size_t)N * 128 * 2);
  half_t* h_h    = (half_t*)alloc((size_t)N * 256 * 2);   // h1/h2/h3
  half_t* x1_h   = (half_t*)alloc((size_t)N * 256 * 2);
  float*  x2_f   = (float*) alloc((size_t)N * 256 * 4);
  half_t* x2_h   = (half_t*)alloc((size_t)N * 256 * 2);
  half_t* qk_h   = (half_t*)alloc((size_t)N * 512 * 2);
  half_t* vt_h   = (half_t*)alloc((size_t)256 * N * 2);   // V^T: [256][32768]
  half_t* o_h    = (half_t*)alloc((size_t)N * 256 * 2);
  float*  att_f  = (float*) alloc((size_t)N * 256 * 4);
  half_t* x2a_h  = (half_t*)alloc((size_t)N * 256 * 2);
  half_t* W1t    = (half_t*)alloc(256 * 128 * 2);
  half_t* W2t    = (half_t*)alloc(256 * 256 * 2);
  half_t* W3t    = (half_t*)alloc(128 * 256 * 2);
  half_t* Wi_h   = (half_t*)alloc(768 * 256 * 2);
  half_t* Wo_h   = (half_t*)alloc(256 * 256 * 2);
  float*  es     = (float*) alloc((size_t)N * 4 * 4);
  float*  ed     = (float*) alloc((size_t)N * 4 * 4);
  int*    deg    = (int*)   alloc((size_t)N * 4);
  int*    fill   = (int*)   alloc((size_t)N * 4);
  int*    rowptr = (int*)   alloc(((size_t)N + 1) * 4);
  int*    col    = (int*)   alloc((size_t)(N + E) * 4);

  const int* srcE = ei;
  const int* dstE = ei + E;

  // CSR by destination (self-loop first in every row)
  k_deg_init<<<N / 256, 256, 0, stream>>>(deg);
  k_hist<<<(E + 255) / 256, 256, 0, stream>>>(dstE, deg, E);
  k_scan<<<1, 1024, 0, stream>>>(deg, rowptr);
  k_selfloop<<<N / 256, 256, 0, stream>>>(rowptr, fill, col);
  k_scatter<<<(E + 255) / 256, 256, 0, stream>>>(srcE, dstE, rowptr, fill, col, E);

  // fp16 conversions
  k_f2h<<<(N * 128 + 255) / 256, 256, 0, stream>>>(x, x_h, N * 128);
  k_f2h_T<<<(256 * 128 + 255) / 256, 256, 0, stream>>>(W1, W1t, 128, 256);
  k_f2h_T<<<(256 * 256 + 255) / 256, 256, 0, stream>>>(W2, W2t, 256, 256);
  k_f2h_T<<<(128 * 256 + 255) / 256, 256, 0, stream>>>(W3, W3t, 256, 128);
  k_f2h<<<(768 * 256 + 255) / 256, 256, 0, stream>>>(Wi, Wi_h, 768 * 256);
  k_f2h<<<(256 * 256 + 255) / 256, 256, 0, stream>>>(Wo, Wo_h, 256 * 256);

  // ---- GAT1: h1 = x @ W1 ; edge softmax ; ELU -> x1 ----
  k_gemm<<<dim3(2, N / 128), 256, 0, stream>>>(x_h, W1t, nullptr, 0, h_h, nullptr, N, 256, 128);
  k_scored<256, 4><<<N / 4, 256, 0, stream>>>(h_h, aS1, aD1, es, ed);
  k_agg<256, 4><<<N / 4, 256, 0, stream>>>(h_h, es, ed, b1, rowptr, col, 1, nullptr, x1_h);

  // ---- GAT2 -> x2 (fp32 for residual/LN + fp16 for QKV) ----
  k_gemm<<<dim3(2, N / 128), 256, 0, stream>>>(x1_h, W2t, nullptr, 0, h_h, nullptr, N, 256, 256);
  k_scored<256, 4><<<N / 4, 256, 0, stream>>>(h_h, aS2, aD2, es, ed);
  k_agg<256, 4><<<N / 4, 256, 0, stream>>>(h_h, es, ed, b2, rowptr, col, 1, x2_f, x2_h);

  // ---- MHA: QK projection [N,512]; V projected transposed [256,N] ----
  k_gemm<<<dim3(4, N / 128), 256, 0, stream>>>(x2_h, Wi_h, bi, 0, qk_h, nullptr, N, 512, 256);
  k_gemm<<<dim3(N / 128, 2), 256, 0, stream>>>(Wi_h + 512 * 256, x2_h, bi + 512, 1,
                                               vt_h, nullptr, 256, N, 256);
  k_attn<<<dim3(256, 8), 256, 0, stream>>>(qk_h, vt_h, o_h);
  k_gemm<<<dim3(2, N / 128), 256, 0, stream>>>(o_h, Wo_h, bo, 0, nullptr, att_f, N, 256, 256);

  // ---- residual + LayerNorm -> x2a (fp16) ----
  k_ln<<<N / 4, 256, 0, stream>>>(att_f, x2_f, gam, bet, x2a_h);

  // ---- GAT3: heads=1, C=128, no ELU, mean==identity -> d_out fp32 ----
  k_gemm<<<dim3(1, N / 128), 256, 0, stream>>>(x2a_h, W3t, nullptr, 0, h_h, nullptr, N, 128, 256);
  k_scored<128, 1><<<N / 4, 256, 0, stream>>>(h_h, aS3, aD3, es, ed);
  k_agg<128, 1><<<N / 4, 256, 0, stream>>>(h_h, es, ed, b3, rowptr, col, 0, out, nullptr);
}

// Round 4
// 517.801 us; speedup vs baseline: 1.7461x; 1.0796x over previous
//
#include <hip/hip_runtime.h>

typedef _Float16 half_t;
typedef _Float16 half8  __attribute__((ext_vector_type(8)));
typedef _Float16 half4v __attribute__((ext_vector_type(4)));
typedef _Float16 half2v __attribute__((ext_vector_type(2)));
typedef float    f32x4  __attribute__((ext_vector_type(4)));

constexpr int N_NODES = 32768;
constexpr int NPG_    = 512;

#define MFMA16(a, b, c) __builtin_amdgcn_mfma_f32_16x16x32_f16((a), (b), (c), 0, 0, 0)

__device__ __forceinline__ void gload_lds16(const half_t* g, half_t* l) {
  __builtin_amdgcn_global_load_lds(
      (const __attribute__((address_space(1))) void*)g,
      (__attribute__((address_space(3))) void*)l, 16, 0, 0);
}

// ---------------- CSR build ----------------
__global__ void k_deg_init(int* __restrict__ deg) {
  deg[blockIdx.x * 256 + threadIdx.x] = 1;   // self-loop counts as 1
}

__global__ void k_hist(const int* __restrict__ dst, int* __restrict__ deg, int E) {
  int i = blockIdx.x * 256 + threadIdx.x;
  if (i < E) atomicAdd(&deg[dst[i]], 1);
}

__global__ __launch_bounds__(1024) void k_scan(const int* __restrict__ deg,
                                               int* __restrict__ rowptr) {
  __shared__ int part[1024];
  int t = threadIdx.x;
  int base = t * 32;
  int s = 0;
  #pragma unroll
  for (int i = 0; i < 32; i++) s += deg[base + i];
  part[t] = s;
  __syncthreads();
  for (int off = 1; off < 1024; off <<= 1) {
    int add = (t >= off) ? part[t - off] : 0;
    __syncthreads();
    part[t] += add;
    __syncthreads();
  }
  int run = (t == 0) ? 0 : part[t - 1];
  for (int i = 0; i < 32; i++) { rowptr[base + i] = run; run += deg[base + i]; }
  if (t == 1023) rowptr[N_NODES] = run;
}

__global__ void k_selfloop(const int* __restrict__ rowptr, int* __restrict__ fill,
                           int* __restrict__ col) {
  int i = blockIdx.x * 256 + threadIdx.x;
  fill[i] = 1;
  col[rowptr[i]] = i;   // self-loop is slot 0 of every dst
}

__global__ void k_scatter(const int* __restrict__ src, const int* __restrict__ dst,
                          const int* __restrict__ rowptr, int* __restrict__ fill,
                          int* __restrict__ col, int E) {
  int i = blockIdx.x * 256 + threadIdx.x;
  if (i < E) {
    int d = dst[i];
    int pos = rowptr[d] + atomicAdd(&fill[d], 1);
    col[pos] = src[i];
  }
}

// ---------------- conversions ----------------
__global__ void k_f2h(const float* __restrict__ in, half_t* __restrict__ out, int n) {
  int i = blockIdx.x * 256 + threadIdx.x;
  if (i < n) out[i] = (half_t)in[i];
}

// out[o*K + k] = W[k*Nc + o]  (transpose-convert: W is [K,Nc], out is [Nc,K])
__global__ void k_f2h_T(const float* __restrict__ W, half_t* __restrict__ out,
                        int K, int Nc) {
  int i = blockIdx.x * 256 + threadIdx.x;
  if (i < K * Nc) {
    int o = i / K, k = i % K;
    out[i] = (half_t)W[(size_t)k * Nc + o];
  }
}

// ---------------- GEMM: C[M,Nc] = A[M,K] @ Bt[Nc,K]^T (+bias) ----------------
// m97-style: 128x128 tile, BK=32, LDS staging via global_load_lds width=16.
__global__ __launch_bounds__(256) void k_gemm(
    const half_t* __restrict__ A, const half_t* __restrict__ Bt,
    const float* __restrict__ bias, int bias_per_row,
    half_t* __restrict__ outh, float* __restrict__ outf,
    int M, int Nc, int K)
{
  __shared__ __align__(16) half_t As[128 * 32];
  __shared__ __align__(16) half_t Bs[128 * 32];
  int w = threadIdx.x >> 6, lane = threadIdx.x & 63;
  int r = lane & 15, q = lane >> 4;
  int m0 = blockIdx.y * 128, n0 = blockIdx.x * 128;
  int mh = (w & 1) * 64, nh = (w >> 1) * 64;
  f32x4 acc[4][4];
  #pragma unroll
  for (int i = 0; i < 4; i++)
    #pragma unroll
    for (int j = 0; j < 4; j++) acc[i][j] = f32x4{0.f, 0.f, 0.f, 0.f};

  int srow = lane >> 2;          // 0..15 within a 16-row slab
  int sch  = (lane & 3) * 8;     // 16B chunk within a 64B row

  for (int k0 = 0; k0 < K; k0 += 32) {
    __syncthreads();
    #pragma unroll
    for (int i = 0; i < 2; i++) {
      int R0 = i * 64 + w * 16;
      int row = R0 + srow;
      gload_lds16(A  + (size_t)(m0 + row) * K + k0 + sch, &As[R0 * 32]);
      gload_lds16(Bt + (size_t)(n0 + row) * K + k0 + sch, &Bs[R0 * 32]);
    }
    __syncthreads();
    half8 af[4], bf[4];
    #pragma unroll
    for (int t = 0; t < 4; t++) af[t] = *(const half8*)&As[(mh + t * 16 + r) * 32 + q * 8];
    #pragma unroll
    for (int t = 0; t < 4; t++) bf[t] = *(const half8*)&Bs[(nh + t * 16 + r) * 32 + q * 8];
    #pragma unroll
    for (int ti = 0; ti < 4; ti++)
      #pragma unroll
      for (int tj = 0; tj < 4; tj++)
        acc[ti][tj] = MFMA16(af[ti], bf[tj], acc[ti][tj]);
  }

  #pragma unroll
  for (int tj = 0; tj < 4; tj++) {
    int colc = n0 + nh + tj * 16 + r;
    #pragma unroll
    for (int ti = 0; ti < 4; ti++) {
      #pragma unroll
      for (int i = 0; i < 4; i++) {
        int row = m0 + mh + ti * 16 + q * 4 + i;
        float bv = bias ? (bias_per_row ? bias[row] : bias[colc]) : 0.f;
        float v = acc[ti][tj][i] + bv;
        size_t idx = (size_t)row * Nc + colc;
        if (outf) outf[idx] = v;
        if (outh) outh[idx] = (half_t)v;
      }
    }
  }
}

// ---------------- per-node attention scores es/ed ----------------
template<int HC, int H>
__global__ __launch_bounds__(256) void k_scored(
    const half_t* __restrict__ h, const float* __restrict__ aS,
    const float* __restrict__ aD, float* __restrict__ es, float* __restrict__ ed)
{
  constexpr int VPT = HC / 64;
  constexpr int LPH = 64 / H;     // lanes per head
  int lane = threadIdx.x & 63;
  int n = blockIdx.x * 4 + (threadIdx.x >> 6);
  const half_t* hp = h + (size_t)n * HC + lane * VPT;
  float ps = 0.f, pd = 0.f;
  #pragma unroll
  for (int i = 0; i < VPT; i++) {
    float v = (float)hp[i];
    ps += v * aS[lane * VPT + i];
    pd += v * aD[lane * VPT + i];
  }
  #pragma unroll
  for (int off = 1; off < LPH; off <<= 1) {
    ps += __shfl_xor(ps, off);
    pd += __shfl_xor(pd, off);
  }
  if ((lane & (LPH - 1)) == 0) {
    es[(size_t)n * H + lane / LPH] = ps;
    ed[(size_t)n * H + lane / LPH] = pd;
  }
}

// ---------------- edge-softmax aggregation (one wave per dst) ----------------
// Single pass, max-free softmax; 4-edge unroll for memory-level parallelism.
template<int HC, int H>
__global__ __launch_bounds__(256) void k_agg(
    const half_t* __restrict__ h, const float* __restrict__ es,
    const float* __restrict__ ed, const float* __restrict__ bias,
    const int* __restrict__ rowptr, const int* __restrict__ col, int elu,
    float* __restrict__ outf, half_t* __restrict__ outh)
{
  constexpr int VPT = HC / 64;
  constexpr int C = HC / H;
  int lane = threadIdx.x & 63;
  int n = blockIdx.x * 4 + (threadIdx.x >> 6);
  int hl = (lane * VPT) / C;
  float edn = ed[(size_t)n * H + hl];
  int j0 = rowptr[n], j1 = rowptr[n + 1];
  int cbase = lane * VPT;

  float sum[4] = {0.f, 0.f, 0.f, 0.f};
  float acc[4][VPT];
  #pragma unroll
  for (int k = 0; k < 4; k++)
    #pragma unroll
    for (int i = 0; i < VPT; i++) acc[k][i] = 0.f;

  for (int j = j0; j < j1; j += 4) {
    int   s[4];
    float e[4];
    #pragma unroll
    for (int k = 0; k < 4; k++) {
      int jj = j + k;
      int jc = (jj < j1) ? jj : (j1 - 1);
      s[k] = col[jc];
      float ev = es[(size_t)s[k] * H + hl] + edn;
      ev = fmaxf(ev, 0.2f * ev);              // LeakyReLU(0.2)
      e[k] = (jj < j1) ? ev : -1e30f;         // padded edge -> exp = 0
    }
    #pragma unroll
    for (int k = 0; k < 4; k++) {
      float p = __expf(e[k]);
      sum[k] += p;
      const half_t* hp = h + (size_t)s[k] * HC + cbase;
      if constexpr (VPT == 4) {
        half4v hv = *(const half4v*)hp;
        acc[k][0] += p * (float)hv[0]; acc[k][1] += p * (float)hv[1];
        acc[k][2] += p * (float)hv[2]; acc[k][3] += p * (float)hv[3];
      } else {
        half2v hv = *(const half2v*)hp;
        acc[k][0] += p * (float)hv[0]; acc[k][1] += p * (float)hv[1];
      }
    }
  }

  float ssum = (sum[0] + sum[1]) + (sum[2] + sum[3]);
  float inv = 1.f / ssum;
  #pragma unroll
  for (int i = 0; i < VPT; i++) {
    float a = (acc[0][i] + acc[1][i]) + (acc[2][i] + acc[3][i]);
    int c = cbase + i;
    float v = a * inv + bias[c];
    if (elu) v = (v > 0.f) ? v : __expf(v) - 1.f;   // jax.nn.elu
    if (outf) outf[(size_t)n * HC + c] = v;
    if (outh) outh[(size_t)n * HC + c] = (half_t)v;
  }
}

// ---------------- MHA core, flash-style ----------------
// Block = (pair, 64 q-rows); streams 4 key-tiles of 128.
// Max-free softmax with constant shift: P = exp(S/8 - 8) -- uniform shift
// cancels in P/sum(P), keeps P in fp16 range (S/8 up to ~19 safe).
// S computed TRANSPOSED (A=K rows, B=Q rows) so each lane's 4 outputs are
// key-consecutive at fixed q -> one ds_write_b64 into wave-private P[q][key],
// which is directly A-operand layout for the PV MFMA. No rowmax pass, no
// block-wide score buffer: LDS = 16K(K) + 16K(V^T) + 17K(P) = 50 KB -> 3 blk/CU.
__global__ __launch_bounds__(256) void k_attn(
    const half_t* __restrict__ qk, const half_t* __restrict__ vt,
    half_t* __restrict__ o)
{
  __shared__ __align__(16) half_t Kt[128 * 64];       // K tile [key][64]
  __shared__ __align__(16) half_t Vt[64 * 128];       // V^T tile [d][key]
  __shared__ __align__(16) half_t Pb[4][16][136];     // per-wave P [q][key+pad]

  int pair = blockIdx.x;            // 0..255 = graph*4 + head (pins pair -> XCD)
  int b = pair >> 2, hh = pair & 3;
  int q0 = blockIdx.y * 64;
  int w = threadIdx.x >> 6, lane = threadIdx.x & 63;
  int cc = lane & 15, qq = lane >> 4;

  // Q fragments (reused across all key-tiles)
  const half_t* Qp = qk + ((size_t)(b * NPG_ + q0 + w * 16 + cc) * 512 + hh * 64);
  half8 qa0 = *(const half8*)(Qp + qq * 8);
  half8 qa1 = *(const half8*)(Qp + 32 + qq * 8);

  f32x4 oacc[4];
  #pragma unroll
  for (int t = 0; t < 4; t++) oacc[t] = f32x4{0.f, 0.f, 0.f, 0.f};
  float rs = 0.f;

  const half_t* kb = qk + ((size_t)(b * NPG_) * 512 + 256 + hh * 64);
  const half_t* vb = vt + ((size_t)(hh * 64) * 32768 + b * NPG_);

  int krow_l = lane >> 3, ks_l = lane & 7;
  int vrow_l = lane >> 4, vs_l = lane & 15;

  for (int kt = 0; kt < 4; kt++) {
    __syncthreads();   // prior iter's tile reads done before overwrite
    #pragma unroll
    for (int i = 0; i < 4; i++) {          // K tile: 4 x 1KB per wave
      int R = (i * 4 + w) * 8;
      int kr = R + krow_l;
      gload_lds16(kb + (size_t)(kt * 128 + kr) * 512 + ((ks_l ^ (kr & 7)) * 8),
                  &Kt[R * 64]);
    }
    #pragma unroll
    for (int i = 0; i < 4; i++) {          // V tile: 4 x 1KB per wave
      int D0 = (i * 4 + w) * 4;
      int d = D0 + vrow_l;
      gload_lds16(vb + (size_t)d * 32768 + kt * 128 + ((vs_l ^ (d & 15)) * 8),
                  &Vt[D0 * 128]);
    }
    __syncthreads();   // staging drained (compiler emits vmcnt(0) before barrier)

    // S^T = K Q^T : D[m=key][n=q]; exp; pack to wave-private P[q][key]
    #pragma unroll
    for (int mt = 0; mt < 8; mt++) {
      int key = mt * 16 + cc;
      half8 k0 = *(const half8*)&Kt[key * 64 + ((qq ^ (key & 7)) << 3)];
      half8 k1 = *(const half8*)&Kt[key * 64 + (((qq + 4) ^ (key & 7)) << 3)];
      f32x4 s = f32x4{0.f, 0.f, 0.f, 0.f};
      s = MFMA16(k0, qa0, s);
      s = MFMA16(k1, qa1, s);
      half4v ph;
      #pragma unroll
      for (int i = 0; i < 4; i++) {
        float p = __expf(s[i] * 0.125f - 8.0f);
        rs += p;                            // partial rowsum for q = cc
        ph[i] = (half_t)p;
      }
      *(half4v*)&Pb[w][cc][mt * 16 + qq * 4] = ph;
    }
    // Pb is wave-private: no barrier; compiler inserts lgkmcnt waits.

    // O += P V : A = P[q][k] rows, B = V^T[d][k] rows
    #pragma unroll
    for (int kc = 0; kc < 4; kc++) {
      half8 a = *(const half8*)&Pb[w][cc][kc * 32 + qq * 8];
      #pragma unroll
      for (int nt = 0; nt < 4; nt++) {
        int d = nt * 16 + cc;
        half8 bb = *(const half8*)&Vt[d * 128 + (((kc * 4 + qq) ^ (d & 15)) << 3)];
        oacc[nt] = MFMA16(a, bb, oacc[nt]);
      }
    }
  }

  // finalize rowsum (per q = cc), then normalize + store
  rs += __shfl_xor(rs, 16);
  rs += __shfl_xor(rs, 32);
  #pragma unroll
  for (int i = 0; i < 4; i++) {
    float rsv = __shfl(rs, qq * 4 + i);    // rowsum for q-row qq*4+i
    float inv = 1.f / rsv;
    int node = b * NPG_ + q0 + w * 16 + qq * 4 + i;
    #pragma unroll
    for (int nt = 0; nt < 4; nt++)
      o[(size_t)node * 256 + hh * 64 + nt * 16 + cc] = (half_t)(oacc[nt][i] * inv);
  }
}

// ---------------- residual + LayerNorm -> fp16 ----------------
__global__ __launch_bounds__(256) void k_ln(
    const float* __restrict__ att, const float* __restrict__ x2,
    const float* __restrict__ gamma, const float* __restrict__ beta,
    half_t* __restrict__ outh)
{
  int lane = threadIdx.x & 63;
  int n = blockIdx.x * 4 + (threadIdx.x >> 6);
  size_t base = (size_t)n * 256 + lane * 4;
  float4 a  = *(const float4*)(att + base);
  float4 xx = *(const float4*)(x2 + base);
  float v[4] = {a.x + xx.x, a.y + xx.y, a.z + xx.z, a.w + xx.w};
  float s  = v[0] + v[1] + v[2] + v[3];
  float ss = v[0]*v[0] + v[1]*v[1] + v[2]*v[2] + v[3]*v[3];
  #pragma unroll
  for (int off = 1; off < 64; off <<= 1) {
    s  += __shfl_xor(s, off);
    ss += __shfl_xor(ss, off);
  }
  float mean = s * (1.f / 256.f);
  float var  = ss * (1.f / 256.f) - mean * mean;
  float rstd = rsqrtf(var + 1e-5f);
  #pragma unroll
  for (int i = 0; i < 4; i++) {
    int c = lane * 4 + i;
    outh[(size_t)n * 256 + c] = (half_t)((v[i] - mean) * rstd * gamma[c] + beta[c]);
  }
}

// ---------------- host ----------------
extern "C" void kernel_launch(void* const* d_in, const int* in_sizes, int n_in,
                              void* d_out, int out_size, void* d_ws, size_t ws_size,
                              hipStream_t stream)
{
  const float* x    = (const float*)d_in[0];
  const int*   ei   = (const int*)d_in[1];
  const float* W1   = (const float*)d_in[3];
  const float* aS1  = (const float*)d_in[4];
  const float* aD1  = (const float*)d_in[5];
  const float* b1   = (const float*)d_in[6];
  const float* W2   = (const float*)d_in[7];
  const float* aS2  = (const float*)d_in[8];
  const float* aD2  = (const float*)d_in[9];
  const float* b2   = (const float*)d_in[10];
  const float* W3   = (const float*)d_in[11];
  const float* aS3  = (const float*)d_in[12];
  const float* aD3  = (const float*)d_in[13];
  const float* b3   = (const float*)d_in[14];
  const float* Wi   = (const float*)d_in[15];
  const float* bi   = (const float*)d_in[16];
  const float* Wo   = (const float*)d_in[17];
  const float* bo   = (const float*)d_in[18];
  const float* gam  = (const float*)d_in[19];
  const float* bet  = (const float*)d_in[20];
  float* out = (float*)d_out;
  const int N = N_NODES;
  int E = in_sizes[1] / 2;

  char* ws = (char*)d_ws;
  size_t off = 0;
  auto alloc = [&](size_t bytes) -> void* {
    void* p = ws + off;
    off = (off + bytes + 255) & ~(size_t)255;
    return p;
  };
  half_t* x_h    = (half_t*)alloc((size_t)N * 128 * 2);
  half_t* h_h    = (half_t*)alloc((size_t)N * 256 * 2);   // h1/h2/h3
  half_t* x1_h   = (half_t*)alloc((size_t)N * 256 * 2);
  float*  x2_f   = (float*) alloc((size_t)N * 256 * 4);
  half_t* x2_h   = (half_t*)alloc((size_t)N * 256 * 2);
  half_t* qk_h   = (half_t*)alloc((size_t)N * 512 * 2);
  half_t* vt_h   = (half_t*)alloc((size_t)256 * N * 2);   // V^T: [256][32768]
  half_t* o_h    = (half_t*)alloc((size_t)N * 256 * 2);
  float*  att_f  = (float*) alloc((size_t)N * 256 * 4);
  half_t* x2a_h  = (half_t*)alloc((size_t)N * 256 * 2);
  half_t* W1t    = (half_t*)alloc(256 * 128 * 2);
  half_t* W2t    = (half_t*)alloc(256 * 256 * 2);
  half_t* W3t    = (half_t*)alloc(128 * 256 * 2);
  half_t* Wi_h   = (half_t*)alloc(768 * 256 * 2);
  half_t* Wo_h   = (half_t*)alloc(256 * 256 * 2);
  float*  es     = (float*) alloc((size_t)N * 4 * 4);
  float*  ed     = (float*) alloc((size_t)N * 4 * 4);
  int*    deg    = (int*)   alloc((size_t)N * 4);
  int*    fill   = (int*)   alloc((size_t)N * 4);
  int*    rowptr = (int*)   alloc(((size_t)N + 1) * 4);
  int*    col    = (int*)   alloc((size_t)(N + E) * 4);

  const int* srcE = ei;
  const int* dstE = ei + E;

  // CSR by destination (self-loop first in every row)
  k_deg_init<<<N / 256, 256, 0, stream>>>(deg);
  k_hist<<<(E + 255) / 256, 256, 0, stream>>>(dstE, deg, E);
  k_scan<<<1, 1024, 0, stream>>>(deg, rowptr);
  k_selfloop<<<N / 256, 256, 0, stream>>>(rowptr, fill, col);
  k_scatter<<<(E + 255) / 256, 256, 0, stream>>>(srcE, dstE, rowptr, fill, col, E);

  // fp16 conversions
  k_f2h<<<(N * 128 + 255) / 256, 256, 0, stream>>>(x, x_h, N * 128);
  k_f2h_T<<<(256 * 128 + 255) / 256, 256, 0, stream>>>(W1, W1t, 128, 256);
  k_f2h_T<<<(256 * 256 + 255) / 256, 256, 0, stream>>>(W2, W2t, 256, 256);
  k_f2h_T<<<(128 * 256 + 255) / 256, 256, 0, stream>>>(W3, W3t, 256, 128);
  k_f2h<<<(768 * 256 + 255) / 256, 256, 0, stream>>>(Wi, Wi_h, 768 * 256);
  k_f2h<<<(256 * 256 + 255) / 256, 256, 0, stream>>>(Wo, Wo_h, 256 * 256);

  // ---- GAT1: h1 = x @ W1 ; edge softmax ; ELU -> x1 ----
  k_gemm<<<dim3(2, N / 128), 256, 0, stream>>>(x_h, W1t, nullptr, 0, h_h, nullptr, N, 256, 128);
  k_scored<256, 4><<<N / 4, 256, 0, stream>>>(h_h, aS1, aD1, es, ed);
  k_agg<256, 4><<<N / 4, 256, 0, stream>>>(h_h, es, ed, b1, rowptr, col, 1, nullptr, x1_h);

  // ---- GAT2 -> x2 (fp32 for residual/LN + fp16 for QKV) ----
  k_gemm<<<dim3(2, N / 128), 256, 0, stream>>>(x1_h, W2t, nullptr, 0, h_h, nullptr, N, 256, 256);
  k_scored<256, 4><<<N / 4, 256, 0, stream>>>(h_h, aS2, aD2, es, ed);
  k_agg<256, 4><<<N / 4, 256, 0, stream>>>(h_h, es, ed, b2, rowptr, col, 1, x2_f, x2_h);

  // ---- MHA: QK projection [N,512]; V projected transposed [256,N] ----
  k_gemm<<<dim3(4, N / 128), 256, 0, stream>>>(x2_h, Wi_h, bi, 0, qk_h, nullptr, N, 512, 256);
  k_gemm<<<dim3(N / 128, 2), 256, 0, stream>>>(Wi_h + 512 * 256, x2_h, bi + 512, 1,
                                               vt_h, nullptr, 256, N, 256);
  k_attn<<<dim3(256, 8), 256, 0, stream>>>(qk_h, vt_h, o_h);
  k_gemm<<<dim3(2, N / 128), 256, 0, stream>>>(o_h, Wo_h, bo, 0, nullptr, att_f, N, 256, 256);

  // ---- residual + LayerNorm -> x2a (fp16) ----
  k_ln<<<N / 4, 256, 0, stream>>>(att_f, x2_f, gam, bet, x2a_h);

  // ---- GAT3: heads=1, C=128, no ELU, mean==identity -> d_out fp32 ----
  k_gemm<<<dim3(1, N / 128), 256, 0, stream>>>(x2a_h, W3t, nullptr, 0, h_h, nullptr, N, 128, 256);
  k_scored<128, 1><<<N / 4, 256, 0, stream>>>(h_h, aS3, aD3, es, ed);
  k_agg<128, 1><<<N / 4, 256, 0, stream>>>(h_h, es, ed, b3, rowptr, col, 0, out, nullptr);
}

// Round 5
// 495.623 us; speedup vs baseline: 1.8242x; 1.0447x over previous
//
#include <hip/hip_runtime.h>

typedef _Float16 half_t;
typedef _Float16 half8  __attribute__((ext_vector_type(8)));
typedef _Float16 half4v __attribute__((ext_vector_type(4)));
typedef float    f32x4  __attribute__((ext_vector_type(4)));

constexpr int N_NODES = 32768;
constexpr int NPG_    = 512;

#define MFMA16(a, b, c) __builtin_amdgcn_mfma_f32_16x16x32_f16((a), (b), (c), 0, 0, 0)

__device__ __forceinline__ void gload_lds16(const half_t* g, half_t* l) {
  __builtin_amdgcn_global_load_lds(
      (const __attribute__((address_space(1))) void*)g,
      (__attribute__((address_space(3))) void*)l, 16, 0, 0);
}

// ---------------- CSR build ----------------
__global__ void k_deg_init(int* __restrict__ deg) {
  deg[blockIdx.x * 256 + threadIdx.x] = 1;   // self-loop counts as 1
}

__global__ void k_hist(const int* __restrict__ dst, int* __restrict__ deg, int E) {
  int i = blockIdx.x * 256 + threadIdx.x;
  if (i < E) atomicAdd(&deg[dst[i]], 1);
}

__global__ __launch_bounds__(1024) void k_scan(const int* __restrict__ deg,
                                               int* __restrict__ rowptr) {
  __shared__ int part[1024];
  int t = threadIdx.x;
  int base = t * 32;
  int s = 0;
  #pragma unroll
  for (int i = 0; i < 32; i++) s += deg[base + i];
  part[t] = s;
  __syncthreads();
  for (int off = 1; off < 1024; off <<= 1) {
    int add = (t >= off) ? part[t - off] : 0;
    __syncthreads();
    part[t] += add;
    __syncthreads();
  }
  int run = (t == 0) ? 0 : part[t - 1];
  for (int i = 0; i < 32; i++) { rowptr[base + i] = run; run += deg[base + i]; }
  if (t == 1023) rowptr[N_NODES] = run;
}

__global__ void k_selfloop(const int* __restrict__ rowptr, int* __restrict__ fill,
                           int* __restrict__ col) {
  int i = blockIdx.x * 256 + threadIdx.x;
  fill[i] = 1;
  col[rowptr[i]] = i;   // self-loop is slot 0 of every dst
}

__global__ void k_scatter(const int* __restrict__ src, const int* __restrict__ dst,
                          const int* __restrict__ rowptr, int* __restrict__ fill,
                          int* __restrict__ col, int E) {
  int i = blockIdx.x * 256 + threadIdx.x;
  if (i < E) {
    int d = dst[i];
    int pos = rowptr[d] + atomicAdd(&fill[d], 1);
    col[pos] = src[i];
  }
}

// ---------------- fused conversions (one launch replaces six) ----------------
// block ranges: [0,16384) x->x_h | [16384,16512) W1t | [16512,16768) W2t
// [16768,16896) W3t | [16896,17664) Wi_h | [17664,17920) Wo_h
__global__ void k_convert(
    const float* __restrict__ x,  half_t* __restrict__ x_h,
    const float* __restrict__ W1, half_t* __restrict__ W1t,
    const float* __restrict__ W2, half_t* __restrict__ W2t,
    const float* __restrict__ W3, half_t* __restrict__ W3t,
    const float* __restrict__ Wi, half_t* __restrict__ Wi_h,
    const float* __restrict__ Wo, half_t* __restrict__ Wo_h)
{
  int bid = blockIdx.x, t = threadIdx.x;
  if (bid < 16384) {
    int i = bid * 256 + t;
    x_h[i] = (half_t)x[i];
  } else if (bid < 16512) {            // W1t[o*128+k] = W1[k*256+o], K=128
    int i = (bid - 16384) * 256 + t;
    int o = i >> 7, k = i & 127;
    W1t[i] = (half_t)W1[k * 256 + o];
  } else if (bid < 16768) {            // W2t[o*256+k] = W2[k*256+o], K=256
    int i = (bid - 16512) * 256 + t;
    int o = i >> 8, k = i & 255;
    W2t[i] = (half_t)W2[k * 256 + o];
  } else if (bid < 16896) {            // W3t[o*256+k] = W3[k*128+o], K=256, Nc=128
    int i = (bid - 16768) * 256 + t;
    int o = i >> 8, k = i & 255;
    W3t[i] = (half_t)W3[k * 128 + o];
  } else if (bid < 17664) {
    int i = (bid - 16896) * 256 + t;
    Wi_h[i] = (half_t)Wi[i];
  } else {
    int i = (bid - 17664) * 256 + t;
    Wo_h[i] = (half_t)Wo[i];
  }
}

// ---------------- GEMM: C[M,Nc] = A[M,K] @ Bt[Nc,K]^T (+bias) ----------------
// m97-style: 128x128 tile, BK=32, LDS staging via global_load_lds width=16.
__global__ __launch_bounds__(256) void k_gemm(
    const half_t* __restrict__ A, const half_t* __restrict__ Bt,
    const float* __restrict__ bias, int bias_per_row,
    half_t* __restrict__ outh, float* __restrict__ outf,
    int M, int Nc, int K)
{
  __shared__ __align__(16) half_t As[128 * 32];
  __shared__ __align__(16) half_t Bs[128 * 32];
  int w = threadIdx.x >> 6, lane = threadIdx.x & 63;
  int r = lane & 15, q = lane >> 4;
  int m0 = blockIdx.y * 128, n0 = blockIdx.x * 128;
  int mh = (w & 1) * 64, nh = (w >> 1) * 64;
  f32x4 acc[4][4];
  #pragma unroll
  for (int i = 0; i < 4; i++)
    #pragma unroll
    for (int j = 0; j < 4; j++) acc[i][j] = f32x4{0.f, 0.f, 0.f, 0.f};

  int srow = lane >> 2;          // 0..15 within a 16-row slab
  int sch  = (lane & 3) * 8;     // 16B chunk within a 64B row

  for (int k0 = 0; k0 < K; k0 += 32) {
    __syncthreads();
    #pragma unroll
    for (int i = 0; i < 2; i++) {
      int R0 = i * 64 + w * 16;
      int row = R0 + srow;
      gload_lds16(A  + (size_t)(m0 + row) * K + k0 + sch, &As[R0 * 32]);
      gload_lds16(Bt + (size_t)(n0 + row) * K + k0 + sch, &Bs[R0 * 32]);
    }
    __syncthreads();
    half8 af[4], bf[4];
    #pragma unroll
    for (int t = 0; t < 4; t++) af[t] = *(const half8*)&As[(mh + t * 16 + r) * 32 + q * 8];
    #pragma unroll
    for (int t = 0; t < 4; t++) bf[t] = *(const half8*)&Bs[(nh + t * 16 + r) * 32 + q * 8];
    #pragma unroll
    for (int ti = 0; ti < 4; ti++)
      #pragma unroll
      for (int tj = 0; tj < 4; tj++)
        acc[ti][tj] = MFMA16(af[ti], bf[tj], acc[ti][tj]);
  }

  #pragma unroll
  for (int tj = 0; tj < 4; tj++) {
    int colc = n0 + nh + tj * 16 + r;
    #pragma unroll
    for (int ti = 0; ti < 4; ti++) {
      #pragma unroll
      for (int i = 0; i < 4; i++) {
        int row = m0 + mh + ti * 16 + q * 4 + i;
        float bv = bias ? (bias_per_row ? bias[row] : bias[colc]) : 0.f;
        float v = acc[ti][tj][i] + bv;
        size_t idx = (size_t)row * Nc + colc;
        if (outf) outf[idx] = v;
        if (outh) outh[idx] = (half_t)v;
      }
    }
  }
}

// ---------------- per-node attention scores es/ed ----------------
template<int HC, int H>
__global__ __launch_bounds__(256) void k_scored(
    const half_t* __restrict__ h, const float* __restrict__ aS,
    const float* __restrict__ aD, float* __restrict__ es, float* __restrict__ ed)
{
  constexpr int VPT = HC / 64;
  constexpr int LPH = 64 / H;     // lanes per head
  int lane = threadIdx.x & 63;
  int n = blockIdx.x * 4 + (threadIdx.x >> 6);
  const half_t* hp = h + (size_t)n * HC + lane * VPT;
  float ps = 0.f, pd = 0.f;
  #pragma unroll
  for (int i = 0; i < VPT; i++) {
    float v = (float)hp[i];
    ps += v * aS[lane * VPT + i];
    pd += v * aD[lane * VPT + i];
  }
  #pragma unroll
  for (int off = 1; off < LPH; off <<= 1) {
    ps += __shfl_xor(ps, off);
    pd += __shfl_xor(pd, off);
  }
  if ((lane & (LPH - 1)) == 0) {
    es[(size_t)n * H + lane / LPH] = ps;
    ed[(size_t)n * H + lane / LPH] = pd;
  }
}

// ---------------- edge-softmax aggregation (one wave per dst) ----------------
// Max-free single-pass softmax. Wave split into 2 edge-groups of 32 lanes:
// group g handles edges j0+g, j0+g+2, ... Each lane covers HC/32 channels
// (16B half8 loads for HC=256). Per-edge scalar chain (col/es/exp) now runs
// on half the lanes -> ~2.5x fewer VALU inst per edge. Groups merge with one
// shfl_xor(32) at the end (exact same math).
template<int HC, int H>
__global__ __launch_bounds__(256) void k_agg(
    const half_t* __restrict__ h, const float* __restrict__ es,
    const float* __restrict__ ed, const float* __restrict__ bias,
    const int* __restrict__ rowptr, const int* __restrict__ col, int elu,
    float* __restrict__ outf, half_t* __restrict__ outh)
{
  constexpr int VPT = HC / 32;        // channels per lane
  constexpr int C = HC / H;
  int lane = threadIdx.x & 63;
  int g = lane >> 5, li = lane & 31;
  int n = blockIdx.x * 4 + (threadIdx.x >> 6);
  int cbase = li * VPT;
  int hl = cbase / C;
  float edn = ed[(size_t)n * H + hl];
  int j0 = rowptr[n], j1 = rowptr[n + 1];
  const half_t* hb = h + cbase;

  float sum0 = 0.f, sum1 = 0.f;
  float acc0[VPT], acc1[VPT];
  #pragma unroll
  for (int i = 0; i < VPT; i++) { acc0[i] = 0.f; acc1[i] = 0.f; }

  for (int j = j0 + g; j < j1; j += 4) {   // 2 edges per iter per group
    int jb = j + 2;
    int s0 = col[j];
    int s1 = col[(jb < j1) ? jb : j];
    float e0 = es[(size_t)s0 * H + hl] + edn;
    e0 = fmaxf(e0, 0.2f * e0);              // LeakyReLU(0.2)
    float e1 = es[(size_t)s1 * H + hl] + edn;
    e1 = fmaxf(e1, 0.2f * e1);
    e1 = (jb < j1) ? e1 : -1e30f;           // padded edge -> exp = 0
    const half_t* hp0 = hb + (size_t)s0 * HC;
    const half_t* hp1 = hb + (size_t)s1 * HC;
    float p0 = __expf(e0), p1 = __expf(e1);
    sum0 += p0; sum1 += p1;
    if constexpr (VPT == 8) {
      half8 v0 = *(const half8*)hp0;
      half8 v1 = *(const half8*)hp1;
      #pragma unroll
      for (int i = 0; i < 8; i++) { acc0[i] += p0 * (float)v0[i]; acc1[i] += p1 * (float)v1[i]; }
    } else {
      half4v v0 = *(const half4v*)hp0;
      half4v v1 = *(const half4v*)hp1;
      #pragma unroll
      for (int i = 0; i < 4; i++) { acc0[i] += p0 * (float)v0[i]; acc1[i] += p1 * (float)v1[i]; }
    }
  }

  // merge the two edge-groups (partner lane has same channels)
  float sum = sum0 + sum1;
  sum += __shfl_xor(sum, 32);
  float av[VPT];
  #pragma unroll
  for (int i = 0; i < VPT; i++) {
    av[i] = acc0[i] + acc1[i];
    av[i] += __shfl_xor(av[i], 32);
  }

  float inv = 1.f / sum;
  float v[VPT];
  #pragma unroll
  for (int i = 0; i < VPT; i++) {
    float t = av[i] * inv + bias[cbase + i];
    if (elu) t = (t > 0.f) ? t : __expf(t) - 1.f;   // jax.nn.elu
    v[i] = t;
  }

  size_t obase = (size_t)n * HC + cbase;
  if constexpr (VPT == 8) {
    if (outf) {   // split the two float4 stores across the groups
      float4 lo = {v[0], v[1], v[2], v[3]};
      float4 hi = {v[4], v[5], v[6], v[7]};
      if (g == 0) *(float4*)(outf + obase) = lo;
      else        *(float4*)(outf + obase + 4) = hi;
    }
    if (outh && g == 0) {
      half8 hv;
      #pragma unroll
      for (int i = 0; i < 8; i++) hv[i] = (half_t)v[i];
      *(half8*)(outh + obase) = hv;
    }
  } else {
    if (outf && g == 0) {
      float4 lo = {v[0], v[1], v[2], v[3]};
      *(float4*)(outf + obase) = lo;
    }
    if (outh && g == 0) {
      half4v hv;
      #pragma unroll
      for (int i = 0; i < 4; i++) hv[i] = (half_t)v[i];
      *(half4v*)(outh + obase) = hv;
    }
  }
}

// ---------------- MHA core, flash-style ----------------
// Block = (pair, 64 q-rows); streams 4 key-tiles of 128.
// Max-free softmax with constant shift: P = exp(S/8 - 8).
__global__ __launch_bounds__(256) void k_attn(
    const half_t* __restrict__ qk, const half_t* __restrict__ vt,
    half_t* __restrict__ o)
{
  __shared__ __align__(16) half_t Kt[128 * 64];       // K tile [key][64]
  __shared__ __align__(16) half_t Vt[64 * 128];       // V^T tile [d][key]
  __shared__ __align__(16) half_t Pb[4][16][136];     // per-wave P [q][key+pad]

  int pair = blockIdx.x;            // 0..255 = graph*4 + head (pins pair -> XCD)
  int b = pair >> 2, hh = pair & 3;
  int q0 = blockIdx.y * 64;
  int w = threadIdx.x >> 6, lane = threadIdx.x & 63;
  int cc = lane & 15, qq = lane >> 4;

  const half_t* Qp = qk + ((size_t)(b * NPG_ + q0 + w * 16 + cc) * 512 + hh * 64);
  half8 qa0 = *(const half8*)(Qp + qq * 8);
  half8 qa1 = *(const half8*)(Qp + 32 + qq * 8);

  f32x4 oacc[4];
  #pragma unroll
  for (int t = 0; t < 4; t++) oacc[t] = f32x4{0.f, 0.f, 0.f, 0.f};
  float rs = 0.f;

  const half_t* kb = qk + ((size_t)(b * NPG_) * 512 + 256 + hh * 64);
  const half_t* vb = vt + ((size_t)(hh * 64) * 32768 + b * NPG_);

  int krow_l = lane >> 3, ks_l = lane & 7;
  int vrow_l = lane >> 4, vs_l = lane & 15;

  for (int kt = 0; kt < 4; kt++) {
    __syncthreads();
    #pragma unroll
    for (int i = 0; i < 4; i++) {          // K tile: 4 x 1KB per wave
      int R = (i * 4 + w) * 8;
      int kr = R + krow_l;
      gload_lds16(kb + (size_t)(kt * 128 + kr) * 512 + ((ks_l ^ (kr & 7)) * 8),
                  &Kt[R * 64]);
    }
    #pragma unroll
    for (int i = 0; i < 4; i++) {          // V tile: 4 x 1KB per wave
      int D0 = (i * 4 + w) * 4;
      int d = D0 + vrow_l;
      gload_lds16(vb + (size_t)d * 32768 + kt * 128 + ((vs_l ^ (d & 15)) * 8),
                  &Vt[D0 * 128]);
    }
    __syncthreads();

    // S^T = K Q^T ; exp ; pack to wave-private P[q][key] (A-operand layout)
    #pragma unroll
    for (int mt = 0; mt < 8; mt++) {
      int key = mt * 16 + cc;
      half8 k0 = *(const half8*)&Kt[key * 64 + ((qq ^ (key & 7)) << 3)];
      half8 k1 = *(const half8*)&Kt[key * 64 + (((qq + 4) ^ (key & 7)) << 3)];
      f32x4 s = f32x4{0.f, 0.f, 0.f, 0.f};
      s = MFMA16(k0, qa0, s);
      s = MFMA16(k1, qa1, s);
      half4v ph;
      #pragma unroll
      for (int i = 0; i < 4; i++) {
        float p = __expf(s[i] * 0.125f - 8.0f);
        rs += p;
        ph[i] = (half_t)p;
      }
      *(half4v*)&Pb[w][cc][mt * 16 + qq * 4] = ph;
    }

    // O += P V
    #pragma unroll
    for (int kc = 0; kc < 4; kc++) {
      half8 a = *(const half8*)&Pb[w][cc][kc * 32 + qq * 8];
      #pragma unroll
      for (int nt = 0; nt < 4; nt++) {
        int d = nt * 16 + cc;
        half8 bb = *(const half8*)&Vt[d * 128 + (((kc * 4 + qq) ^ (d & 15)) << 3)];
        oacc[nt] = MFMA16(a, bb, oacc[nt]);
      }
    }
  }

  rs += __shfl_xor(rs, 16);
  rs += __shfl_xor(rs, 32);
  #pragma unroll
  for (int i = 0; i < 4; i++) {
    float rsv = __shfl(rs, qq * 4 + i);
    float inv = 1.f / rsv;
    int node = b * NPG_ + q0 + w * 16 + qq * 4 + i;
    #pragma unroll
    for (int nt = 0; nt < 4; nt++)
      o[(size_t)node * 256 + hh * 64 + nt * 16 + cc] = (half_t)(oacc[nt][i] * inv);
  }
}

// ---------------- residual + LayerNorm -> fp16 ----------------
__global__ __launch_bounds__(256) void k_ln(
    const float* __restrict__ att, const float* __restrict__ x2,
    const float* __restrict__ gamma, const float* __restrict__ beta,
    half_t* __restrict__ outh)
{
  int lane = threadIdx.x & 63;
  int n = blockIdx.x * 4 + (threadIdx.x >> 6);
  size_t base = (size_t)n * 256 + lane * 4;
  float4 a  = *(const float4*)(att + base);
  float4 xx = *(const float4*)(x2 + base);
  float v[4] = {a.x + xx.x, a.y + xx.y, a.z + xx.z, a.w + xx.w};
  float s  = v[0] + v[1] + v[2] + v[3];
  float ss = v[0]*v[0] + v[1]*v[1] + v[2]*v[2] + v[3]*v[3];
  #pragma unroll
  for (int off = 1; off < 64; off <<= 1) {
    s  += __shfl_xor(s, off);
    ss += __shfl_xor(ss, off);
  }
  float mean = s * (1.f / 256.f);
  float var  = ss * (1.f / 256.f) - mean * mean;
  float rstd = rsqrtf(var + 1e-5f);
  #pragma unroll
  for (int i = 0; i < 4; i++) {
    int c = lane * 4 + i;
    outh[(size_t)n * 256 + c] = (half_t)((v[i] - mean) * rstd * gamma[c] + beta[c]);
  }
}

// ---------------- host ----------------
extern "C" void kernel_launch(void* const* d_in, const int* in_sizes, int n_in,
                              void* d_out, int out_size, void* d_ws, size_t ws_size,
                              hipStream_t stream)
{
  const float* x    = (const float*)d_in[0];
  const int*   ei   = (const int*)d_in[1];
  const float* W1   = (const float*)d_in[3];
  const float* aS1  = (const float*)d_in[4];
  const float* aD1  = (const float*)d_in[5];
  const float* b1   = (const float*)d_in[6];
  const float* W2   = (const float*)d_in[7];
  const float* aS2  = (const float*)d_in[8];
  const float* aD2  = (const float*)d_in[9];
  const float* b2   = (const float*)d_in[10];
  const float* W3   = (const float*)d_in[11];
  const float* aS3  = (const float*)d_in[12];
  const float* aD3  = (const float*)d_in[13];
  const float* b3   = (const float*)d_in[14];
  const float* Wi   = (const float*)d_in[15];
  const float* bi   = (const float*)d_in[16];
  const float* Wo   = (const float*)d_in[17];
  const float* bo   = (const float*)d_in[18];
  const float* gam  = (const float*)d_in[19];
  const float* bet  = (const float*)d_in[20];
  float* out = (float*)d_out;
  const int N = N_NODES;
  int E = in_sizes[1] / 2;

  char* ws = (char*)d_ws;
  size_t off = 0;
  auto alloc = [&](size_t bytes) -> void* {
    void* p = ws + off;
    off = (off + bytes + 255) & ~(size_t)255;
    return p;
  };
  half_t* x_h    = (half_t*)alloc((size_t)N * 128 * 2);
  half_t* h_h    = (half_t*)alloc((size_t)N * 256 * 2);   // h1/h2/h3
  half_t* x1_h   = (half_t*)alloc((size_t)N * 256 * 2);
  float*  x2_f   = (float*) alloc((size_t)N * 256 * 4);
  half_t* x2_h   = (half_t*)alloc((size_t)N * 256 * 2);
  half_t* qk_h   = (half_t*)alloc((size_t)N * 512 * 2);
  half_t* vt_h   = (half_t*)alloc((size_t)256 * N * 2);   // V^T: [256][32768]
  half_t* o_h    = (half_t*)alloc((size_t)N * 256 * 2);
  float*  att_f  = (float*) alloc((size_t)N * 256 * 4);
  half_t* x2a_h  = (half_t*)alloc((size_t)N * 256 * 2);
  half_t* W1t    = (half_t*)alloc(256 * 128 * 2);
  half_t* W2t    = (half_t*)alloc(256 * 256 * 2);
  half_t* W3t    = (half_t*)alloc(128 * 256 * 2);
  half_t* Wi_h   = (half_t*)alloc(768 * 256 * 2);
  half_t* Wo_h   = (half_t*)alloc(256 * 256 * 2);
  float*  es     = (float*) alloc((size_t)N * 4 * 4);
  float*  ed     = (float*) alloc((size_t)N * 4 * 4);
  int*    deg    = (int*)   alloc((size_t)N * 4);
  int*    fill   = (int*)   alloc((size_t)N * 4);
  int*    rowptr = (int*)   alloc(((size_t)N + 1) * 4);
  int*    col    = (int*)   alloc((size_t)(N + E) * 4);

  const int* srcE = ei;
  const int* dstE = ei + E;

  // CSR by destination (self-loop first in every row)
  k_deg_init<<<N / 256, 256, 0, stream>>>(deg);
  k_hist<<<(E + 255) / 256, 256, 0, stream>>>(dstE, deg, E);
  k_scan<<<1, 1024, 0, stream>>>(deg, rowptr);
  k_selfloop<<<N / 256, 256, 0, stream>>>(rowptr, fill, col);
  k_scatter<<<(E + 255) / 256, 256, 0, stream>>>(srcE, dstE, rowptr, fill, col, E);

  // fused fp16 conversions (x + 5 weights) in one launch
  k_convert<<<17920, 256, 0, stream>>>(x, x_h, W1, W1t, W2, W2t, W3, W3t,
                                       Wi, Wi_h, Wo, Wo_h);

  // ---- GAT1: h1 = x @ W1 ; edge softmax ; ELU -> x1 ----
  k_gemm<<<dim3(2, N / 128), 256, 0, stream>>>(x_h, W1t, nullptr, 0, h_h, nullptr, N, 256, 128);
  k_scored<256, 4><<<N / 4, 256, 0, stream>>>(h_h, aS1, aD1, es, ed);
  k_agg<256, 4><<<N / 4, 256, 0, stream>>>(h_h, es, ed, b1, rowptr, col, 1, nullptr, x1_h);

  // ---- GAT2 -> x2 (fp32 for residual/LN + fp16 for QKV) ----
  k_gemm<<<dim3(2, N / 128), 256, 0, stream>>>(x1_h, W2t, nullptr, 0, h_h, nullptr, N, 256, 256);
  k_scored<256, 4><<<N / 4, 256, 0, stream>>>(h_h, aS2, aD2, es, ed);
  k_agg<256, 4><<<N / 4, 256, 0, stream>>>(h_h, es, ed, b2, rowptr, col, 1, x2_f, x2_h);

  // ---- MHA: QK projection [N,512]; V projected transposed [256,N] ----
  k_gemm<<<dim3(4, N / 128), 256, 0, stream>>>(x2_h, Wi_h, bi, 0, qk_h, nullptr, N, 512, 256);
  k_gemm<<<dim3(N / 128, 2), 256, 0, stream>>>(Wi_h + 512 * 256, x2_h, bi + 512, 1,
                                               vt_h, nullptr, 256, N, 256);
  k_attn<<<dim3(256, 8), 256, 0, stream>>>(qk_h, vt_h, o_h);
  k_gemm<<<dim3(2, N / 128), 256, 0, stream>>>(o_h, Wo_h, bo, 0, nullptr, att_f, N, 256, 256);

  // ---- residual + LayerNorm -> x2a (fp16) ----
  k_ln<<<N / 4, 256, 0, stream>>>(att_f, x2_f, gam, bet, x2a_h);

  // ---- GAT3: heads=1, C=128, no ELU, mean==identity -> d_out fp32 ----
  k_gemm<<<dim3(1, N / 128), 256, 0, stream>>>(x2a_h, W3t, nullptr, 0, h_h, nullptr, N, 128, 256);
  k_scored<128, 1><<<N / 4, 256, 0, stream>>>(h_h, aS3, aD3, es, ed);
  k_agg<128, 1><<<N / 4, 256, 0, stream>>>(h_h, es, ed, b3, rowptr, col, 0, out, nullptr);
}

// Round 6
// 474.483 us; speedup vs baseline: 1.9055x; 1.0446x over previous
//
#include <hip/hip_runtime.h>

typedef _Float16 half_t;
typedef _Float16 half8  __attribute__((ext_vector_type(8)));
typedef _Float16 half4v __attribute__((ext_vector_type(4)));
typedef float    f32x4  __attribute__((ext_vector_type(4)));

constexpr int N_NODES = 32768;
constexpr int NPG_    = 512;

#define MFMA16(a, b, c) __builtin_amdgcn_mfma_f32_16x16x32_f16((a), (b), (c), 0, 0, 0)

__device__ __forceinline__ void gload_lds16(const half_t* g, half_t* l) {
  __builtin_amdgcn_global_load_lds(
      (const __attribute__((address_space(1))) void*)g,
      (__attribute__((address_space(3))) void*)l, 16, 0, 0);
}

// ---------------- CSR build ----------------
__global__ void k_hist(const int* __restrict__ dst, int* __restrict__ deg, int E) {
  int i = blockIdx.x * 256 + threadIdx.x;
  if (i < E) atomicAdd(&deg[dst[i]], 1);
}

__global__ __launch_bounds__(1024) void k_scan(const int* __restrict__ deg,
                                               int* __restrict__ rowptr) {
  __shared__ int part[1024];
  int t = threadIdx.x;
  int base = t * 32;
  int s = 0;
  #pragma unroll
  for (int i = 0; i < 32; i++) s += deg[base + i];
  part[t] = s;
  __syncthreads();
  for (int off = 1; off < 1024; off <<= 1) {
    int add = (t >= off) ? part[t - off] : 0;
    __syncthreads();
    part[t] += add;
    __syncthreads();
  }
  int run = (t == 0) ? 0 : part[t - 1];
  for (int i = 0; i < 32; i++) { rowptr[base + i] = run; run += deg[base + i]; }
  if (t == 1023) rowptr[N_NODES] = run;
}

__global__ void k_selfloop(const int* __restrict__ rowptr, int* __restrict__ fill,
                           int* __restrict__ col) {
  int i = blockIdx.x * 256 + threadIdx.x;
  fill[i] = 1;
  col[rowptr[i]] = i;   // self-loop is slot 0 of every dst
}

__global__ void k_scatter(const int* __restrict__ src, const int* __restrict__ dst,
                          const int* __restrict__ rowptr, int* __restrict__ fill,
                          int* __restrict__ col, int E) {
  int i = blockIdx.x * 256 + threadIdx.x;
  if (i < E) {
    int d = dst[i];
    int pos = rowptr[d] + atomicAdd(&fill[d], 1);
    col[pos] = src[i];
  }
}

// ---------------- fused conversions + deg init (one launch) ----------------
// [0,16384) x->x_h | [16384,16512) W1t | [16512,16768) W2t | [16768,16896) W3t
// [16896,17664) Wi_h | [17664,17920) Wo_h | [17920,18048) deg=1
__global__ void k_convert(
    const float* __restrict__ x,  half_t* __restrict__ x_h,
    const float* __restrict__ W1, half_t* __restrict__ W1t,
    const float* __restrict__ W2, half_t* __restrict__ W2t,
    const float* __restrict__ W3, half_t* __restrict__ W3t,
    const float* __restrict__ Wi, half_t* __restrict__ Wi_h,
    const float* __restrict__ Wo, half_t* __restrict__ Wo_h,
    int* __restrict__ deg)
{
  int bid = blockIdx.x, t = threadIdx.x;
  if (bid < 16384) {
    int i = bid * 256 + t;
    x_h[i] = (half_t)x[i];
  } else if (bid < 16512) {            // W1t[o*128+k] = W1[k*256+o]
    int i = (bid - 16384) * 256 + t;
    int o = i >> 7, k = i & 127;
    W1t[i] = (half_t)W1[k * 256 + o];
  } else if (bid < 16768) {            // W2t[o*256+k] = W2[k*256+o]
    int i = (bid - 16512) * 256 + t;
    int o = i >> 8, k = i & 255;
    W2t[i] = (half_t)W2[k * 256 + o];
  } else if (bid < 16896) {            // W3t[o*256+k] = W3[k*128+o]
    int i = (bid - 16768) * 256 + t;
    int o = i >> 8, k = i & 255;
    W3t[i] = (half_t)W3[k * 128 + o];
  } else if (bid < 17664) {
    int i = (bid - 16896) * 256 + t;
    Wi_h[i] = (half_t)Wi[i];
  } else if (bid < 17920) {
    int i = (bid - 17664) * 256 + t;
    Wo_h[i] = (half_t)Wo[i];
  } else {
    deg[(bid - 17920) * 256 + t] = 1;  // self-loop counts as 1
  }
}

// ---------------- GEMM + optional fused GAT-score epilogue ----------------
// C[M,Nc] = A[M,K] @ Bt[Nc,K]^T (+bias). If es!=null, also computes
// es/ed per-row per-head dot products from the accumulators:
//   H==4 (C=64): wave's 64 cols == one head -> shfl-reduce, direct write.
//   H==1 (C=128=Nc): wave holds half the row -> LDS cross-wave combine.
__global__ __launch_bounds__(256) void k_gemm(
    const half_t* __restrict__ A, const half_t* __restrict__ Bt,
    const float* __restrict__ bias, int bias_per_row,
    half_t* __restrict__ outh, float* __restrict__ outf,
    int M, int Nc, int K,
    const float* __restrict__ aS, const float* __restrict__ aD,
    float* __restrict__ es, float* __restrict__ ed, int H)
{
  __shared__ __align__(16) half_t As[128 * 32];
  __shared__ __align__(16) half_t Bs[128 * 32];
  __shared__ float sRed[2][4][64];     // H==1 cross-wave partials
  int w = threadIdx.x >> 6, lane = threadIdx.x & 63;
  int r = lane & 15, q = lane >> 4;
  int m0 = blockIdx.y * 128, n0 = blockIdx.x * 128;
  int mh = (w & 1) * 64, nh = (w >> 1) * 64;
  f32x4 acc[4][4];
  #pragma unroll
  for (int i = 0; i < 4; i++)
    #pragma unroll
    for (int j = 0; j < 4; j++) acc[i][j] = f32x4{0.f, 0.f, 0.f, 0.f};

  int srow = lane >> 2;
  int sch  = (lane & 3) * 8;

  for (int k0 = 0; k0 < K; k0 += 32) {
    __syncthreads();
    #pragma unroll
    for (int i = 0; i < 2; i++) {
      int R0 = i * 64 + w * 16;
      int row = R0 + srow;
      gload_lds16(A  + (size_t)(m0 + row) * K + k0 + sch, &As[R0 * 32]);
      gload_lds16(Bt + (size_t)(n0 + row) * K + k0 + sch, &Bs[R0 * 32]);
    }
    __syncthreads();
    half8 af[4], bf[4];
    #pragma unroll
    for (int t = 0; t < 4; t++) af[t] = *(const half8*)&As[(mh + t * 16 + r) * 32 + q * 8];
    #pragma unroll
    for (int t = 0; t < 4; t++) bf[t] = *(const half8*)&Bs[(nh + t * 16 + r) * 32 + q * 8];
    #pragma unroll
    for (int ti = 0; ti < 4; ti++)
      #pragma unroll
      for (int tj = 0; tj < 4; tj++)
        acc[ti][tj] = MFMA16(af[ti], bf[tj], acc[ti][tj]);
  }

  // C store
  #pragma unroll
  for (int tj = 0; tj < 4; tj++) {
    int colc = n0 + nh + tj * 16 + r;
    #pragma unroll
    for (int ti = 0; ti < 4; ti++) {
      #pragma unroll
      for (int i = 0; i < 4; i++) {
        int row = m0 + mh + ti * 16 + q * 4 + i;
        float bv = bias ? (bias_per_row ? bias[row] : bias[colc]) : 0.f;
        float v = acc[ti][tj][i] + bv;
        size_t idx = (size_t)row * Nc + colc;
        if (outf) outf[idx] = v;
        if (outh) outh[idx] = (half_t)v;
      }
    }
  }

  // fused score epilogue
  if (es) {
    if (H == 4) {
      int head = (n0 >> 6) + (nh >> 6);
      float aSv[4], aDv[4];
      #pragma unroll
      for (int tj = 0; tj < 4; tj++) {
        int cl = tj * 16 + r;
        aSv[tj] = aS[head * 64 + cl];
        aDv[tj] = aD[head * 64 + cl];
      }
      #pragma unroll
      for (int ti = 0; ti < 4; ti++) {
        #pragma unroll
        for (int i = 0; i < 4; i++) {
          float ps = 0.f, pd = 0.f;
          #pragma unroll
          for (int tj = 0; tj < 4; tj++) {
            float av = acc[ti][tj][i];
            ps += av * aSv[tj];
            pd += av * aDv[tj];
          }
          #pragma unroll
          for (int off = 1; off < 16; off <<= 1) {
            ps += __shfl_xor(ps, off);
            pd += __shfl_xor(pd, off);
          }
          if (r == 0) {
            int row = m0 + mh + ti * 16 + q * 4 + i;
            es[(size_t)row * 4 + head] = ps;
            ed[(size_t)row * 4 + head] = pd;
          }
        }
      }
    } else {   // H == 1, Nc == 128
      float aSv[4], aDv[4];
      #pragma unroll
      for (int tj = 0; tj < 4; tj++) {
        int c = nh + tj * 16 + r;
        aSv[tj] = aS[c];
        aDv[tj] = aD[c];
      }
      #pragma unroll
      for (int ti = 0; ti < 4; ti++) {
        #pragma unroll
        for (int i = 0; i < 4; i++) {
          float ps = 0.f, pd = 0.f;
          #pragma unroll
          for (int tj = 0; tj < 4; tj++) {
            float av = acc[ti][tj][i];
            ps += av * aSv[tj];
            pd += av * aDv[tj];
          }
          #pragma unroll
          for (int off = 1; off < 16; off <<= 1) {
            ps += __shfl_xor(ps, off);
            pd += __shfl_xor(pd, off);
          }
          if (r == 0) {
            int ri = ti * 16 + q * 4 + i;
            sRed[0][w][ri] = ps;
            sRed[1][w][ri] = pd;
          }
        }
      }
      __syncthreads();
      if (threadIdx.x < 128) {
        int row = threadIdx.x;
        int wlo = row >> 6, ri = row & 63;
        es[m0 + row] = sRed[0][wlo][ri] + sRed[0][wlo + 2][ri];
        ed[m0 + row] = sRed[1][wlo][ri] + sRed[1][wlo + 2][ri];
      }
    }
  }
}

// ---------------- edge-softmax aggregation (one wave per dst) ----------------
// Max-free single-pass softmax. 4 edge-groups x 16 lanes; each lane covers
// HC/16 channels. Scalar chain amortized over 4 edges per wave-instruction;
// 2 unroll slots -> 8 edges in flight. Groups merge via butterfly shfl.
template<int HC, int H>
__global__ __launch_bounds__(256) void k_agg(
    const half_t* __restrict__ h, const float* __restrict__ es,
    const float* __restrict__ ed, const float* __restrict__ bias,
    const int* __restrict__ rowptr, const int* __restrict__ col, int elu,
    float* __restrict__ outf, half_t* __restrict__ outh)
{
  constexpr int VPT = HC / 16;        // channels per lane (16 or 8)
  constexpr int C = HC / H;
  int lane = threadIdx.x & 63;
  int g = lane >> 4, li = lane & 15;
  int n = blockIdx.x * 4 + (threadIdx.x >> 6);
  int cbase = li * VPT;
  int hl = cbase / C;
  float edn = ed[(size_t)n * H + hl];
  int j0 = rowptr[n], j1 = rowptr[n + 1];
  const half_t* hb = h + cbase;

  float sum0 = 0.f, sum1 = 0.f;
  float acc0[VPT], acc1[VPT];
  #pragma unroll
  for (int i = 0; i < VPT; i++) { acc0[i] = 0.f; acc1[i] = 0.f; }

  for (int j = j0 + g; j < j1; j += 8) {   // 2 slots per group per iter
    int jb = j + 4;
    int s0 = col[j];
    int s1 = col[(jb < j1) ? jb : j];
    float e0 = es[(size_t)s0 * H + hl] + edn;
    e0 = fmaxf(e0, 0.2f * e0);              // LeakyReLU(0.2)
    float e1 = es[(size_t)s1 * H + hl] + edn;
    e1 = fmaxf(e1, 0.2f * e1);
    e1 = (jb < j1) ? e1 : -1e30f;           // padded slot -> exp = 0
    const half_t* hp0 = hb + (size_t)s0 * HC;
    const half_t* hp1 = hb + (size_t)s1 * HC;
    float p0 = __expf(e0), p1 = __expf(e1);
    sum0 += p0; sum1 += p1;
    if constexpr (VPT == 16) {
      half8 a0 = *(const half8*)hp0;
      half8 b0 = *(const half8*)(hp0 + 8);
      half8 a1 = *(const half8*)hp1;
      half8 b1 = *(const half8*)(hp1 + 8);
      #pragma unroll
      for (int i = 0; i < 8; i++) {
        acc0[i]     += p0 * (float)a0[i];
        acc0[i + 8] += p0 * (float)b0[i];
        acc1[i]     += p1 * (float)a1[i];
        acc1[i + 8] += p1 * (float)b1[i];
      }
    } else {
      half8 a0 = *(const half8*)hp0;
      half8 a1 = *(const half8*)hp1;
      #pragma unroll
      for (int i = 0; i < 8; i++) {
        acc0[i] += p0 * (float)a0[i];
        acc1[i] += p1 * (float)a1[i];
      }
    }
  }

  // butterfly merge across the 4 groups (same channels in partner lanes)
  float sum = sum0 + sum1;
  sum += __shfl_xor(sum, 16);
  sum += __shfl_xor(sum, 32);
  float av[VPT];
  #pragma unroll
  for (int i = 0; i < VPT; i++) {
    av[i] = acc0[i] + acc1[i];
    av[i] += __shfl_xor(av[i], 16);
    av[i] += __shfl_xor(av[i], 32);
  }

  float inv = 1.f / sum;
  float v[VPT];
  #pragma unroll
  for (int i = 0; i < VPT; i++) {
    float t = av[i] * inv + bias[cbase + i];
    if (elu) t = (t > 0.f) ? t : __expf(t) - 1.f;   // jax.nn.elu
    v[i] = t;
  }

  if (g == 0) {
    size_t obase = (size_t)n * HC + cbase;
    if (outh) {
      half8 hv0, hv1;
      #pragma unroll
      for (int i = 0; i < 8; i++) hv0[i] = (half_t)v[i];
      *(half8*)(outh + obase) = hv0;
      if constexpr (VPT == 16) {
        #pragma unroll
        for (int i = 0; i < 8; i++) hv1[i] = (half_t)v[i + 8];
        *(half8*)(outh + obase + 8) = hv1;
      }
    }
    if (outf) {
      #pragma unroll
      for (int p4 = 0; p4 < VPT / 4; p4++) {
        float4 fv = {v[p4 * 4], v[p4 * 4 + 1], v[p4 * 4 + 2], v[p4 * 4 + 3]};
        *(float4*)(outf + obase + p4 * 4) = fv;
      }
    }
  }
}

// ---------------- MHA core, flash-style (unchanged from R4) ----------------
__global__ __launch_bounds__(256) void k_attn(
    const half_t* __restrict__ qk, const half_t* __restrict__ vt,
    half_t* __restrict__ o)
{
  __shared__ __align__(16) half_t Kt[128 * 64];
  __shared__ __align__(16) half_t Vt[64 * 128];
  __shared__ __align__(16) half_t Pb[4][16][136];

  int pair = blockIdx.x;
  int b = pair >> 2, hh = pair & 3;
  int q0 = blockIdx.y * 64;
  int w = threadIdx.x >> 6, lane = threadIdx.x & 63;
  int cc = lane & 15, qq = lane >> 4;

  const half_t* Qp = qk + ((size_t)(b * NPG_ + q0 + w * 16 + cc) * 512 + hh * 64);
  half8 qa0 = *(const half8*)(Qp + qq * 8);
  half8 qa1 = *(const half8*)(Qp + 32 + qq * 8);

  f32x4 oacc[4];
  #pragma unroll
  for (int t = 0; t < 4; t++) oacc[t] = f32x4{0.f, 0.f, 0.f, 0.f};
  float rs = 0.f;

  const half_t* kb = qk + ((size_t)(b * NPG_) * 512 + 256 + hh * 64);
  const half_t* vb = vt + ((size_t)(hh * 64) * 32768 + b * NPG_);

  int krow_l = lane >> 3, ks_l = lane & 7;
  int vrow_l = lane >> 4, vs_l = lane & 15;

  for (int kt = 0; kt < 4; kt++) {
    __syncthreads();
    #pragma unroll
    for (int i = 0; i < 4; i++) {
      int R = (i * 4 + w) * 8;
      int kr = R + krow_l;
      gload_lds16(kb + (size_t)(kt * 128 + kr) * 512 + ((ks_l ^ (kr & 7)) * 8),
                  &Kt[R * 64]);
    }
    #pragma unroll
    for (int i = 0; i < 4; i++) {
      int D0 = (i * 4 + w) * 4;
      int d = D0 + vrow_l;
      gload_lds16(vb + (size_t)d * 32768 + kt * 128 + ((vs_l ^ (d & 15)) * 8),
                  &Vt[D0 * 128]);
    }
    __syncthreads();

    #pragma unroll
    for (int mt = 0; mt < 8; mt++) {
      int key = mt * 16 + cc;
      half8 k0 = *(const half8*)&Kt[key * 64 + ((qq ^ (key & 7)) << 3)];
      half8 k1 = *(const half8*)&Kt[key * 64 + (((qq + 4) ^ (key & 7)) << 3)];
      f32x4 s = f32x4{0.f, 0.f, 0.f, 0.f};
      s = MFMA16(k0, qa0, s);
      s = MFMA16(k1, qa1, s);
      half4v ph;
      #pragma unroll
      for (int i = 0; i < 4; i++) {
        float p = __expf(s[i] * 0.125f - 8.0f);
        rs += p;
        ph[i] = (half_t)p;
      }
      *(half4v*)&Pb[w][cc][mt * 16 + qq * 4] = ph;
    }

    #pragma unroll
    for (int kc = 0; kc < 4; kc++) {
      half8 a = *(const half8*)&Pb[w][cc][kc * 32 + qq * 8];
      #pragma unroll
      for (int nt = 0; nt < 4; nt++) {
        int d = nt * 16 + cc;
        half8 bb = *(const half8*)&Vt[d * 128 + (((kc * 4 + qq) ^ (d & 15)) << 3)];
        oacc[nt] = MFMA16(a, bb, oacc[nt]);
      }
    }
  }

  rs += __shfl_xor(rs, 16);
  rs += __shfl_xor(rs, 32);
  #pragma unroll
  for (int i = 0; i < 4; i++) {
    float rsv = __shfl(rs, qq * 4 + i);
    float inv = 1.f / rsv;
    int node = b * NPG_ + q0 + w * 16 + qq * 4 + i;
    #pragma unroll
    for (int nt = 0; nt < 4; nt++)
      o[(size_t)node * 256 + hh * 64 + nt * 16 + cc] = (half_t)(oacc[nt][i] * inv);
  }
}

// ---------------- residual + LayerNorm (fp16 in, fp16 out) ----------------
__global__ __launch_bounds__(256) void k_ln(
    const half_t* __restrict__ att, const half_t* __restrict__ x2,
    const float* __restrict__ gamma, const float* __restrict__ beta,
    half_t* __restrict__ outh)
{
  int lane = threadIdx.x & 63;
  int n = blockIdx.x * 4 + (threadIdx.x >> 6);
  size_t base = (size_t)n * 256 + lane * 4;
  half4v a  = *(const half4v*)(att + base);
  half4v xx = *(const half4v*)(x2 + base);
  float v[4];
  #pragma unroll
  for (int i = 0; i < 4; i++) v[i] = (float)a[i] + (float)xx[i];
  float s  = v[0] + v[1] + v[2] + v[3];
  float ss = v[0]*v[0] + v[1]*v[1] + v[2]*v[2] + v[3]*v[3];
  #pragma unroll
  for (int off = 1; off < 64; off <<= 1) {
    s  += __shfl_xor(s, off);
    ss += __shfl_xor(ss, off);
  }
  float mean = s * (1.f / 256.f);
  float var  = ss * (1.f / 256.f) - mean * mean;
  float rstd = rsqrtf(var + 1e-5f);
  #pragma unroll
  for (int i = 0; i < 4; i++) {
    int c = lane * 4 + i;
    outh[(size_t)n * 256 + c] = (half_t)((v[i] - mean) * rstd * gamma[c] + beta[c]);
  }
}

// ---------------- host ----------------
extern "C" void kernel_launch(void* const* d_in, const int* in_sizes, int n_in,
                              void* d_out, int out_size, void* d_ws, size_t ws_size,
                              hipStream_t stream)
{
  const float* x    = (const float*)d_in[0];
  const int*   ei   = (const int*)d_in[1];
  const float* W1   = (const float*)d_in[3];
  const float* aS1  = (const float*)d_in[4];
  const float* aD1  = (const float*)d_in[5];
  const float* b1   = (const float*)d_in[6];
  const float* W2   = (const float*)d_in[7];
  const float* aS2  = (const float*)d_in[8];
  const float* aD2  = (const float*)d_in[9];
  const float* b2   = (const float*)d_in[10];
  const float* W3   = (const float*)d_in[11];
  const float* aS3  = (const float*)d_in[12];
  const float* aD3  = (const float*)d_in[13];
  const float* b3   = (const float*)d_in[14];
  const float* Wi   = (const float*)d_in[15];
  const float* bi   = (const float*)d_in[16];
  const float* Wo   = (const float*)d_in[17];
  const float* bo   = (const float*)d_in[18];
  const float* gam  = (const float*)d_in[19];
  const float* bet  = (const float*)d_in[20];
  float* out = (float*)d_out;
  const int N = N_NODES;
  int E = in_sizes[1] / 2;

  char* ws = (char*)d_ws;
  size_t off = 0;
  auto alloc = [&](size_t bytes) -> void* {
    void* p = ws + off;
    off = (off + bytes + 255) & ~(size_t)255;
    return p;
  };
  half_t* x_h    = (half_t*)alloc((size_t)N * 128 * 2);
  half_t* h_h    = (half_t*)alloc((size_t)N * 256 * 2);   // h1/h2/h3
  half_t* x1_h   = (half_t*)alloc((size_t)N * 256 * 2);
  half_t* x2_h   = (half_t*)alloc((size_t)N * 256 * 2);
  half_t* qk_h   = (half_t*)alloc((size_t)N * 512 * 2);
  half_t* vt_h   = (half_t*)alloc((size_t)256 * N * 2);   // V^T: [256][32768]
  half_t* o_h    = (half_t*)alloc((size_t)N * 256 * 2);
  half_t* att_h  = (half_t*)alloc((size_t)N * 256 * 2);
  half_t* x2a_h  = (half_t*)alloc((size_t)N * 256 * 2);
  half_t* W1t    = (half_t*)alloc(256 * 128 * 2);
  half_t* W2t    = (half_t*)alloc(256 * 256 * 2);
  half_t* W3t    = (half_t*)alloc(128 * 256 * 2);
  half_t* Wi_h   = (half_t*)alloc(768 * 256 * 2);
  half_t* Wo_h   = (half_t*)alloc(256 * 256 * 2);
  float*  es     = (float*) alloc((size_t)N * 4 * 4);
  float*  ed     = (float*) alloc((size_t)N * 4 * 4);
  int*    deg    = (int*)   alloc((size_t)N * 4);
  int*    fill   = (int*)   alloc((size_t)N * 4);
  int*    rowptr = (int*)   alloc(((size_t)N + 1) * 4);
  int*    col    = (int*)   alloc((size_t)(N + E) * 4);

  const int* srcE = ei;
  const int* dstE = ei + E;

  // conversions + deg init (one launch), then CSR
  k_convert<<<18048, 256, 0, stream>>>(x, x_h, W1, W1t, W2, W2t, W3, W3t,
                                       Wi, Wi_h, Wo, Wo_h, deg);
  k_hist<<<(E + 255) / 256, 256, 0, stream>>>(dstE, deg, E);
  k_scan<<<1, 1024, 0, stream>>>(deg, rowptr);
  k_selfloop<<<N / 256, 256, 0, stream>>>(rowptr, fill, col);
  k_scatter<<<(E + 255) / 256, 256, 0, stream>>>(srcE, dstE, rowptr, fill, col, E);

  // ---- GAT1: h1 = x @ W1 (+fused es/ed) ; aggregate+ELU -> x1 ----
  k_gemm<<<dim3(2, N / 128), 256, 0, stream>>>(x_h, W1t, nullptr, 0, h_h, nullptr,
                                               N, 256, 128, aS1, aD1, es, ed, 4);
  k_agg<256, 4><<<N / 4, 256, 0, stream>>>(h_h, es, ed, b1, rowptr, col, 1, nullptr, x1_h);

  // ---- GAT2 -> x2 (fp16) ----
  k_gemm<<<dim3(2, N / 128), 256, 0, stream>>>(x1_h, W2t, nullptr, 0, h_h, nullptr,
                                               N, 256, 256, aS2, aD2, es, ed, 4);
  k_agg<256, 4><<<N / 4, 256, 0, stream>>>(h_h, es, ed, b2, rowptr, col, 1, nullptr, x2_h);

  // ---- MHA ----
  k_gemm<<<dim3(4, N / 128), 256, 0, stream>>>(x2_h, Wi_h, bi, 0, qk_h, nullptr,
                                               N, 512, 256, nullptr, nullptr, nullptr, nullptr, 0);
  k_gemm<<<dim3(N / 128, 2), 256, 0, stream>>>(Wi_h + 512 * 256, x2_h, bi + 512, 1,
                                               vt_h, nullptr, 256, N, 256,
                                               nullptr, nullptr, nullptr, nullptr, 0);
  k_attn<<<dim3(256, 8), 256, 0, stream>>>(qk_h, vt_h, o_h);
  k_gemm<<<dim3(2, N / 128), 256, 0, stream>>>(o_h, Wo_h, bo, 0, att_h, nullptr,
                                               N, 256, 256, nullptr, nullptr, nullptr, nullptr, 0);

  // ---- residual + LayerNorm -> x2a (fp16) ----
  k_ln<<<N / 4, 256, 0, stream>>>(att_h, x2_h, gam, bet, x2a_h);

  // ---- GAT3 (H=1, C=128, fused es/ed via LDS combine) -> d_out fp32 ----
  k_gemm<<<dim3(1, N / 128), 256, 0, stream>>>(x2a_h, W3t, nullptr, 0, h_h, nullptr,
                                               N, 128, 256, aS3, aD3, es, ed, 1);
  k_agg<128, 1><<<N / 4, 256, 0, stream>>>(h_h, es, ed, b3, rowptr, col, 0, out, nullptr);
}

// Round 7
// 459.963 us; speedup vs baseline: 1.9656x; 1.0316x over previous
//
#include <hip/hip_runtime.h>

typedef _Float16 half_t;
typedef _Float16 half8  __attribute__((ext_vector_type(8)));
typedef _Float16 half4v __attribute__((ext_vector_type(4)));
typedef float    f32x4  __attribute__((ext_vector_type(4)));

constexpr int N_NODES = 32768;
constexpr int NPG_    = 512;

#define MFMA16(a, b, c) __builtin_amdgcn_mfma_f32_16x16x32_f16((a), (b), (c), 0, 0, 0)

__device__ __forceinline__ void gload_lds16(const half_t* g, half_t* l) {
  __builtin_amdgcn_global_load_lds(
      (const __attribute__((address_space(1))) void*)g,
      (__attribute__((address_space(3))) void*)l, 16, 0, 0);
}

// ---------------- CSR build ----------------
__global__ void k_hist(const int* __restrict__ dst, int* __restrict__ deg, int E) {
  int i = blockIdx.x * 256 + threadIdx.x;
  if (i < E) atomicAdd(&deg[dst[i]], 1);
}

__global__ __launch_bounds__(1024) void k_scan(const int* __restrict__ deg,
                                               int* __restrict__ rowptr) {
  __shared__ int part[1024];
  int t = threadIdx.x;
  int base = t * 32;
  int s = 0;
  #pragma unroll
  for (int i = 0; i < 32; i++) s += deg[base + i];
  part[t] = s;
  __syncthreads();
  for (int off = 1; off < 1024; off <<= 1) {
    int add = (t >= off) ? part[t - off] : 0;
    __syncthreads();
    part[t] += add;
    __syncthreads();
  }
  int run = (t == 0) ? 0 : part[t - 1];
  for (int i = 0; i < 32; i++) { rowptr[base + i] = run; run += deg[base + i]; }
  if (t == 1023) rowptr[N_NODES] = run;
}

__global__ void k_selfloop(const int* __restrict__ rowptr, int* __restrict__ fill,
                           int* __restrict__ col) {
  int i = blockIdx.x * 256 + threadIdx.x;
  fill[i] = 1;
  col[rowptr[i]] = i;   // self-loop is slot 0 of every dst
}

__global__ void k_scatter(const int* __restrict__ src, const int* __restrict__ dst,
                          const int* __restrict__ rowptr, int* __restrict__ fill,
                          int* __restrict__ col, int E) {
  int i = blockIdx.x * 256 + threadIdx.x;
  if (i < E) {
    int d = dst[i];
    int pos = rowptr[d] + atomicAdd(&fill[d], 1);
    col[pos] = src[i];
  }
}

// ---------------- fused conversions + deg init (one launch) ----------------
__global__ void k_convert(
    const float* __restrict__ x,  half_t* __restrict__ x_h,
    const float* __restrict__ W1, half_t* __restrict__ W1t,
    const float* __restrict__ W2, half_t* __restrict__ W2t,
    const float* __restrict__ W3, half_t* __restrict__ W3t,
    const float* __restrict__ Wi, half_t* __restrict__ Wi_h,
    const float* __restrict__ Wo, half_t* __restrict__ Wo_h,
    int* __restrict__ deg)
{
  int bid = blockIdx.x, t = threadIdx.x;
  if (bid < 16384) {
    int i = bid * 256 + t;
    x_h[i] = (half_t)x[i];
  } else if (bid < 16512) {            // W1t[o*128+k] = W1[k*256+o]
    int i = (bid - 16384) * 256 + t;
    int o = i >> 7, k = i & 127;
    W1t[i] = (half_t)W1[k * 256 + o];
  } else if (bid < 16768) {            // W2t[o*256+k] = W2[k*256+o]
    int i = (bid - 16512) * 256 + t;
    int o = i >> 8, k = i & 255;
    W2t[i] = (half_t)W2[k * 256 + o];
  } else if (bid < 16896) {            // W3t[o*256+k] = W3[k*128+o]
    int i = (bid - 16768) * 256 + t;
    int o = i >> 8, k = i & 255;
    W3t[i] = (half_t)W3[k * 128 + o];
  } else if (bid < 17664) {
    int i = (bid - 16896) * 256 + t;
    Wi_h[i] = (half_t)Wi[i];
  } else if (bid < 17920) {
    int i = (bid - 17664) * 256 + t;
    Wo_h[i] = (half_t)Wo[i];
  } else {
    deg[(bid - 17920) * 256 + t] = 1;  // self-loop counts as 1
  }
}

// ---------------- GEMM + optional fused GAT-score epilogue ----------------
// C[M,Nc] = A[M,K] @ Bt[Nc,K]^T (+bias). BK=64 (half the barriers of BK=32);
// LDS rows are 128 B = exact bank period, so 16B chunks are XOR-swizzled on
// the GLOBAL source address (chunk c^(row&7)) keeping global_load_lds's
// lane-linear dest while making ds_read_b128 conflict-free.
__global__ __launch_bounds__(256) void k_gemm(
    const half_t* __restrict__ A, const half_t* __restrict__ Bt,
    const float* __restrict__ bias, int bias_per_row,
    half_t* __restrict__ outh, float* __restrict__ outf,
    int M, int Nc, int K,
    const float* __restrict__ aS, const float* __restrict__ aD,
    float* __restrict__ es, float* __restrict__ ed, int H)
{
  __shared__ __align__(16) half_t As[128 * 64];
  __shared__ __align__(16) half_t Bs[128 * 64];
  __shared__ float sRed[2][4][64];     // H==1 cross-wave partials
  int w = threadIdx.x >> 6, lane = threadIdx.x & 63;
  int r = lane & 15, q = lane >> 4;
  int m0 = blockIdx.y * 128, n0 = blockIdx.x * 128;
  int mh = (w & 1) * 64, nh = (w >> 1) * 64;
  f32x4 acc[4][4];
  #pragma unroll
  for (int i = 0; i < 4; i++)
    #pragma unroll
    for (int j = 0; j < 4; j++) acc[i][j] = f32x4{0.f, 0.f, 0.f, 0.f};

  int srow = lane >> 3;          // 0..7 rows per gload
  int sc   = lane & 7;           // 16B chunk slot 0..7

  for (int k0 = 0; k0 < K; k0 += 64) {
    __syncthreads();
    #pragma unroll
    for (int i = 0; i < 4; i++) {
      int R0 = w * 32 + i * 8;
      int row = R0 + srow;
      int cg = sc ^ (row & 7);
      gload_lds16(A  + (size_t)(m0 + row) * K + k0 + cg * 8, &As[R0 * 64]);
      gload_lds16(Bt + (size_t)(n0 + row) * K + k0 + cg * 8, &Bs[R0 * 64]);
    }
    __syncthreads();
    #pragma unroll
    for (int kk = 0; kk < 2; kk++) {
      half8 af[4], bf[4];
      #pragma unroll
      for (int t = 0; t < 4; t++) {
        int rr = mh + t * 16 + r;
        af[t] = *(const half8*)&As[rr * 64 + (((kk * 4 + q) ^ (rr & 7)) << 3)];
      }
      #pragma unroll
      for (int t = 0; t < 4; t++) {
        int rr = nh + t * 16 + r;
        bf[t] = *(const half8*)&Bs[rr * 64 + (((kk * 4 + q) ^ (rr & 7)) << 3)];
      }
      #pragma unroll
      for (int ti = 0; ti < 4; ti++)
        #pragma unroll
        for (int tj = 0; tj < 4; tj++)
          acc[ti][tj] = MFMA16(af[ti], bf[tj], acc[ti][tj]);
    }
  }

  // C store
  #pragma unroll
  for (int tj = 0; tj < 4; tj++) {
    int colc = n0 + nh + tj * 16 + r;
    #pragma unroll
    for (int ti = 0; ti < 4; ti++) {
      #pragma unroll
      for (int i = 0; i < 4; i++) {
        int row = m0 + mh + ti * 16 + q * 4 + i;
        float bv = bias ? (bias_per_row ? bias[row] : bias[colc]) : 0.f;
        float v = acc[ti][tj][i] + bv;
        size_t idx = (size_t)row * Nc + colc;
        if (outf) outf[idx] = v;
        if (outh) outh[idx] = (half_t)v;
      }
    }
  }

  // fused score epilogue
  if (es) {
    if (H == 4) {
      int head = (n0 >> 6) + (nh >> 6);
      float aSv[4], aDv[4];
      #pragma unroll
      for (int tj = 0; tj < 4; tj++) {
        int cl = tj * 16 + r;
        aSv[tj] = aS[head * 64 + cl];
        aDv[tj] = aD[head * 64 + cl];
      }
      #pragma unroll
      for (int ti = 0; ti < 4; ti++) {
        #pragma unroll
        for (int i = 0; i < 4; i++) {
          float ps = 0.f, pd = 0.f;
          #pragma unroll
          for (int tj = 0; tj < 4; tj++) {
            float av = acc[ti][tj][i];
            ps += av * aSv[tj];
            pd += av * aDv[tj];
          }
          #pragma unroll
          for (int off = 1; off < 16; off <<= 1) {
            ps += __shfl_xor(ps, off);
            pd += __shfl_xor(pd, off);
          }
          if (r == 0) {
            int row = m0 + mh + ti * 16 + q * 4 + i;
            es[(size_t)row * 4 + head] = ps;
            ed[(size_t)row * 4 + head] = pd;
          }
        }
      }
    } else {   // H == 1, Nc == 128
      float aSv[4], aDv[4];
      #pragma unroll
      for (int tj = 0; tj < 4; tj++) {
        int c = nh + tj * 16 + r;
        aSv[tj] = aS[c];
        aDv[tj] = aD[c];
      }
      #pragma unroll
      for (int ti = 0; ti < 4; ti++) {
        #pragma unroll
        for (int i = 0; i < 4; i++) {
          float ps = 0.f, pd = 0.f;
          #pragma unroll
          for (int tj = 0; tj < 4; tj++) {
            float av = acc[ti][tj][i];
            ps += av * aSv[tj];
            pd += av * aDv[tj];
          }
          #pragma unroll
          for (int off = 1; off < 16; off <<= 1) {
            ps += __shfl_xor(ps, off);
            pd += __shfl_xor(pd, off);
          }
          if (r == 0) {
            int ri = ti * 16 + q * 4 + i;
            sRed[0][w][ri] = ps;
            sRed[1][w][ri] = pd;
          }
        }
      }
      __syncthreads();
      if (threadIdx.x < 128) {
        int row = threadIdx.x;
        int wlo = row >> 6, ri = row & 63;
        es[m0 + row] = sRed[0][wlo][ri] + sRed[0][wlo + 2][ri];
        ed[m0 + row] = sRed[1][wlo][ri] + sRed[1][wlo + 2][ri];
      }
    }
  }
}

// ---------------- edge-softmax aggregation (one wave per dst) ----------------
// Max-free single-pass softmax, weights exp(e-6) (uniform shift cancels in
// the ratio). 4 edge-groups x 16 lanes. FP16ACC: accumulate in packed half8
// (v_pk_fma_f16) -- 4x fewer VALU inst and 4x fewer acc VGPRs than fp32.
template<int HC, int H, bool FP16ACC>
__global__ __launch_bounds__(256) void k_agg(
    const half_t* __restrict__ h, const float* __restrict__ es,
    const float* __restrict__ ed, const float* __restrict__ bias,
    const int* __restrict__ rowptr, const int* __restrict__ col, int elu,
    float* __restrict__ outf, half_t* __restrict__ outh)
{
  constexpr int VPT = HC / 16;        // channels per lane (16 or 8)
  constexpr int NV8 = VPT / 8;        // half8 regs per slot (2 or 1)
  constexpr int C = HC / H;
  int lane = threadIdx.x & 63;
  int g = lane >> 4, li = lane & 15;
  int n = blockIdx.x * 4 + (threadIdx.x >> 6);
  int cbase = li * VPT;
  int hl = cbase / C;
  float edn = ed[(size_t)n * H + hl];
  int j0 = rowptr[n], j1 = rowptr[n + 1];
  const half_t* hb = h + cbase;

  float sum0 = 0.f, sum1 = 0.f;

  if constexpr (FP16ACC) {
    half8 acc0[NV8], acc1[NV8];
    #pragma unroll
    for (int i = 0; i < NV8; i++) {
      acc0[i] = half8{0, 0, 0, 0, 0, 0, 0, 0};
      acc1[i] = half8{0, 0, 0, 0, 0, 0, 0, 0};
    }
    for (int j = j0 + g; j < j1; j += 8) {
      int jb = j + 4;
      int s0 = col[j];
      int s1 = col[(jb < j1) ? jb : j];
      float e0 = es[(size_t)s0 * H + hl] + edn;
      e0 = fmaxf(e0, 0.2f * e0);
      float e1 = es[(size_t)s1 * H + hl] + edn;
      e1 = fmaxf(e1, 0.2f * e1);
      e1 = (jb < j1) ? e1 : -1e30f;
      const half_t* hp0 = hb + (size_t)s0 * HC;
      const half_t* hp1 = hb + (size_t)s1 * HC;
      float p0 = __expf(e0 - 6.f), p1 = __expf(e1 - 6.f);
      sum0 += p0; sum1 += p1;
      half_t q0 = (half_t)p0, q1 = (half_t)p1;
      half8 pv0 = {q0, q0, q0, q0, q0, q0, q0, q0};
      half8 pv1 = {q1, q1, q1, q1, q1, q1, q1, q1};
      #pragma unroll
      for (int i = 0; i < NV8; i++) {
        half8 v0 = *(const half8*)(hp0 + i * 8);
        half8 v1 = *(const half8*)(hp1 + i * 8);
        acc0[i] += pv0 * v0;        // v_pk_fma_f16
        acc1[i] += pv1 * v1;
      }
    }
    float sum = sum0 + sum1;
    sum += __shfl_xor(sum, 16);
    sum += __shfl_xor(sum, 32);
    float av[VPT];
    #pragma unroll
    for (int i = 0; i < VPT; i++) {
      av[i] = (float)acc0[i >> 3][i & 7] + (float)acc1[i >> 3][i & 7];
      av[i] += __shfl_xor(av[i], 16);
      av[i] += __shfl_xor(av[i], 32);
    }
    float inv = 1.f / sum;
    float v[VPT];
    #pragma unroll
    for (int i = 0; i < VPT; i++) {
      float t = av[i] * inv + bias[cbase + i];
      if (elu) t = (t > 0.f) ? t : __expf(t) - 1.f;
      v[i] = t;
    }
    if (g == 0) {
      size_t obase = (size_t)n * HC + cbase;
      if (outh) {
        #pragma unroll
        for (int p8 = 0; p8 < NV8; p8++) {
          half8 hv;
          #pragma unroll
          for (int i = 0; i < 8; i++) hv[i] = (half_t)v[p8 * 8 + i];
          *(half8*)(outh + obase + p8 * 8) = hv;
        }
      }
      if (outf) {
        #pragma unroll
        for (int p4 = 0; p4 < VPT / 4; p4++) {
          float4 fv = {v[p4 * 4], v[p4 * 4 + 1], v[p4 * 4 + 2], v[p4 * 4 + 3]};
          *(float4*)(outf + obase + p4 * 4) = fv;
        }
      }
    }
  } else {
    float acc0[VPT], acc1[VPT];
    #pragma unroll
    for (int i = 0; i < VPT; i++) { acc0[i] = 0.f; acc1[i] = 0.f; }
    for (int j = j0 + g; j < j1; j += 8) {
      int jb = j + 4;
      int s0 = col[j];
      int s1 = col[(jb < j1) ? jb : j];
      float e0 = es[(size_t)s0 * H + hl] + edn;
      e0 = fmaxf(e0, 0.2f * e0);
      float e1 = es[(size_t)s1 * H + hl] + edn;
      e1 = fmaxf(e1, 0.2f * e1);
      e1 = (jb < j1) ? e1 : -1e30f;
      const half_t* hp0 = hb + (size_t)s0 * HC;
      const half_t* hp1 = hb + (size_t)s1 * HC;
      float p0 = __expf(e0), p1 = __expf(e1);
      sum0 += p0; sum1 += p1;
      #pragma unroll
      for (int c8 = 0; c8 < NV8; c8++) {
        half8 a0 = *(const half8*)(hp0 + c8 * 8);
        half8 a1 = *(const half8*)(hp1 + c8 * 8);
        #pragma unroll
        for (int i = 0; i < 8; i++) {
          acc0[c8 * 8 + i] += p0 * (float)a0[i];
          acc1[c8 * 8 + i] += p1 * (float)a1[i];
        }
      }
    }
    float sum = sum0 + sum1;
    sum += __shfl_xor(sum, 16);
    sum += __shfl_xor(sum, 32);
    float av[VPT];
    #pragma unroll
    for (int i = 0; i < VPT; i++) {
      av[i] = acc0[i] + acc1[i];
      av[i] += __shfl_xor(av[i], 16);
      av[i] += __shfl_xor(av[i], 32);
    }
    float inv = 1.f / sum;
    float v[VPT];
    #pragma unroll
    for (int i = 0; i < VPT; i++) {
      float t = av[i] * inv + bias[cbase + i];
      if (elu) t = (t > 0.f) ? t : __expf(t) - 1.f;
      v[i] = t;
    }
    if (g == 0) {
      size_t obase = (size_t)n * HC + cbase;
      if (outh) {
        #pragma unroll
        for (int p8 = 0; p8 < NV8; p8++) {
          half8 hv;
          #pragma unroll
          for (int i = 0; i < 8; i++) hv[i] = (half_t)v[p8 * 8 + i];
          *(half8*)(outh + obase + p8 * 8) = hv;
        }
      }
      if (outf) {
        #pragma unroll
        for (int p4 = 0; p4 < VPT / 4; p4++) {
          float4 fv = {v[p4 * 4], v[p4 * 4 + 1], v[p4 * 4 + 2], v[p4 * 4 + 3]};
          *(float4*)(outf + obase + p4 * 4) = fv;
        }
      }
    }
  }
}

// ---------------- MHA core, flash-style ----------------
__global__ __launch_bounds__(256) void k_attn(
    const half_t* __restrict__ qk, const half_t* __restrict__ vt,
    half_t* __restrict__ o)
{
  __shared__ __align__(16) half_t Kt[128 * 64];
  __shared__ __align__(16) half_t Vt[64 * 128];
  __shared__ __align__(16) half_t Pb[4][16][136];

  int pair = blockIdx.x;
  int b = pair >> 2, hh = pair & 3;
  int q0 = blockIdx.y * 64;
  int w = threadIdx.x >> 6, lane = threadIdx.x & 63;
  int cc = lane & 15, qq = lane >> 4;

  const half_t* Qp = qk + ((size_t)(b * NPG_ + q0 + w * 16 + cc) * 512 + hh * 64);
  half8 qa0 = *(const half8*)(Qp + qq * 8);
  half8 qa1 = *(const half8*)(Qp + 32 + qq * 8);

  f32x4 oacc[4];
  #pragma unroll
  for (int t = 0; t < 4; t++) oacc[t] = f32x4{0.f, 0.f, 0.f, 0.f};
  float rs = 0.f;

  const half_t* kb = qk + ((size_t)(b * NPG_) * 512 + 256 + hh * 64);
  const half_t* vb = vt + ((size_t)(hh * 64) * 32768 + b * NPG_);

  int krow_l = lane >> 3, ks_l = lane & 7;
  int vrow_l = lane >> 4, vs_l = lane & 15;

  for (int kt = 0; kt < 4; kt++) {
    __syncthreads();
    #pragma unroll
    for (int i = 0; i < 4; i++) {
      int R = (i * 4 + w) * 8;
      int kr = R + krow_l;
      gload_lds16(kb + (size_t)(kt * 128 + kr) * 512 + ((ks_l ^ (kr & 7)) * 8),
                  &Kt[R * 64]);
    }
    #pragma unroll
    for (int i = 0; i < 4; i++) {
      int D0 = (i * 4 + w) * 4;
      int d = D0 + vrow_l;
      gload_lds16(vb + (size_t)d * 32768 + kt * 128 + ((vs_l ^ (d & 15)) * 8),
                  &Vt[D0 * 128]);
    }
    __syncthreads();

    #pragma unroll
    for (int mt = 0; mt < 8; mt++) {
      int key = mt * 16 + cc;
      half8 k0 = *(const half8*)&Kt[key * 64 + ((qq ^ (key & 7)) << 3)];
      half8 k1 = *(const half8*)&Kt[key * 64 + (((qq + 4) ^ (key & 7)) << 3)];
      f32x4 s = f32x4{0.f, 0.f, 0.f, 0.f};
      s = MFMA16(k0, qa0, s);
      s = MFMA16(k1, qa1, s);
      half4v ph;
      #pragma unroll
      for (int i = 0; i < 4; i++) {
        float p = __expf(s[i] * 0.125f - 8.0f);
        rs += p;
        ph[i] = (half_t)p;
      }
      *(half4v*)&Pb[w][cc][mt * 16 + qq * 4] = ph;
    }

    #pragma unroll
    for (int kc = 0; kc < 4; kc++) {
      half8 a = *(const half8*)&Pb[w][cc][kc * 32 + qq * 8];
      #pragma unroll
      for (int nt = 0; nt < 4; nt++) {
        int d = nt * 16 + cc;
        half8 bb = *(const half8*)&Vt[d * 128 + (((kc * 4 + qq) ^ (d & 15)) << 3)];
        oacc[nt] = MFMA16(a, bb, oacc[nt]);
      }
    }
  }

  rs += __shfl_xor(rs, 16);
  rs += __shfl_xor(rs, 32);
  #pragma unroll
  for (int i = 0; i < 4; i++) {
    float rsv = __shfl(rs, qq * 4 + i);
    float inv = 1.f / rsv;
    int node = b * NPG_ + q0 + w * 16 + qq * 4 + i;
    #pragma unroll
    for (int nt = 0; nt < 4; nt++)
      o[(size_t)node * 256 + hh * 64 + nt * 16 + cc] = (half_t)(oacc[nt][i] * inv);
  }
}

// ---------------- residual + LayerNorm (fp16 in, fp16 out) ----------------
__global__ __launch_bounds__(256) void k_ln(
    const half_t* __restrict__ att, const half_t* __restrict__ x2,
    const float* __restrict__ gamma, const float* __restrict__ beta,
    half_t* __restrict__ outh)
{
  int lane = threadIdx.x & 63;
  int n = blockIdx.x * 4 + (threadIdx.x >> 6);
  size_t base = (size_t)n * 256 + lane * 4;
  half4v a  = *(const half4v*)(att + base);
  half4v xx = *(const half4v*)(x2 + base);
  float v[4];
  #pragma unroll
  for (int i = 0; i < 4; i++) v[i] = (float)a[i] + (float)xx[i];
  float s  = v[0] + v[1] + v[2] + v[3];
  float ss = v[0]*v[0] + v[1]*v[1] + v[2]*v[2] + v[3]*v[3];
  #pragma unroll
  for (int off = 1; off < 64; off <<= 1) {
    s  += __shfl_xor(s, off);
    ss += __shfl_xor(ss, off);
  }
  float mean = s * (1.f / 256.f);
  float var  = ss * (1.f / 256.f) - mean * mean;
  float rstd = rsqrtf(var + 1e-5f);
  #pragma unroll
  for (int i = 0; i < 4; i++) {
    int c = lane * 4 + i;
    outh[(size_t)n * 256 + c] = (half_t)((v[i] - mean) * rstd * gamma[c] + beta[c]);
  }
}

// ---------------- host ----------------
extern "C" void kernel_launch(void* const* d_in, const int* in_sizes, int n_in,
                              void* d_out, int out_size, void* d_ws, size_t ws_size,
                              hipStream_t stream)
{
  const float* x    = (const float*)d_in[0];
  const int*   ei   = (const int*)d_in[1];
  const float* W1   = (const float*)d_in[3];
  const float* aS1  = (const float*)d_in[4];
  const float* aD1  = (const float*)d_in[5];
  const float* b1   = (const float*)d_in[6];
  const float* W2   = (const float*)d_in[7];
  const float* aS2  = (const float*)d_in[8];
  const float* aD2  = (const float*)d_in[9];
  const float* b2   = (const float*)d_in[10];
  const float* W3   = (const float*)d_in[11];
  const float* aS3  = (const float*)d_in[12];
  const float* aD3  = (const float*)d_in[13];
  const float* b3   = (const float*)d_in[14];
  const float* Wi   = (const float*)d_in[15];
  const float* bi   = (const float*)d_in[16];
  const float* Wo   = (const float*)d_in[17];
  const float* bo   = (const float*)d_in[18];
  const float* gam  = (const float*)d_in[19];
  const float* bet  = (const float*)d_in[20];
  float* out = (float*)d_out;
  const int N = N_NODES;
  int E = in_sizes[1] / 2;

  char* ws = (char*)d_ws;
  size_t off = 0;
  auto alloc = [&](size_t bytes) -> void* {
    void* p = ws + off;
    off = (off + bytes + 255) & ~(size_t)255;
    return p;
  };
  half_t* x_h    = (half_t*)alloc((size_t)N * 128 * 2);
  half_t* h_h    = (half_t*)alloc((size_t)N * 256 * 2);   // h1/h2/h3
  half_t* x1_h   = (half_t*)alloc((size_t)N * 256 * 2);
  half_t* x2_h   = (half_t*)alloc((size_t)N * 256 * 2);
  half_t* qk_h   = (half_t*)alloc((size_t)N * 512 * 2);
  half_t* vt_h   = (half_t*)alloc((size_t)256 * N * 2);   // V^T: [256][32768]
  half_t* o_h    = (half_t*)alloc((size_t)N * 256 * 2);
  half_t* att_h  = (half_t*)alloc((size_t)N * 256 * 2);
  half_t* x2a_h  = (half_t*)alloc((size_t)N * 256 * 2);
  half_t* W1t    = (half_t*)alloc(256 * 128 * 2);
  half_t* W2t    = (half_t*)alloc(256 * 256 * 2);
  half_t* W3t    = (half_t*)alloc(128 * 256 * 2);
  half_t* Wi_h   = (half_t*)alloc(768 * 256 * 2);
  half_t* Wo_h   = (half_t*)alloc(256 * 256 * 2);
  float*  es     = (float*) alloc((size_t)N * 4 * 4);
  float*  ed     = (float*) alloc((size_t)N * 4 * 4);
  int*    deg    = (int*)   alloc((size_t)N * 4);
  int*    fill   = (int*)   alloc((size_t)N * 4);
  int*    rowptr = (int*)   alloc(((size_t)N + 1) * 4);
  int*    col    = (int*)   alloc((size_t)(N + E) * 4);

  const int* srcE = ei;
  const int* dstE = ei + E;

  // conversions + deg init (one launch), then CSR
  k_convert<<<18048, 256, 0, stream>>>(x, x_h, W1, W1t, W2, W2t, W3, W3t,
                                       Wi, Wi_h, Wo, Wo_h, deg);
  k_hist<<<(E + 255) / 256, 256, 0, stream>>>(dstE, deg, E);
  k_scan<<<1, 1024, 0, stream>>>(deg, rowptr);
  k_selfloop<<<N / 256, 256, 0, stream>>>(rowptr, fill, col);
  k_scatter<<<(E + 255) / 256, 256, 0, stream>>>(srcE, dstE, rowptr, fill, col, E);

  // ---- GAT1: h1 = x @ W1 (+fused es/ed) ; aggregate+ELU -> x1 ----
  k_gemm<<<dim3(2, N / 128), 256, 0, stream>>>(x_h, W1t, nullptr, 0, h_h, nullptr,
                                               N, 256, 128, aS1, aD1, es, ed, 4);
  k_agg<256, 4, true><<<N / 4, 256, 0, stream>>>(h_h, es, ed, b1, rowptr, col, 1, nullptr, x1_h);

  // ---- GAT2 -> x2 (fp16) ----
  k_gemm<<<dim3(2, N / 128), 256, 0, stream>>>(x1_h, W2t, nullptr, 0, h_h, nullptr,
                                               N, 256, 256, aS2, aD2, es, ed, 4);
  k_agg<256, 4, true><<<N / 4, 256, 0, stream>>>(h_h, es, ed, b2, rowptr, col, 1, nullptr, x2_h);

  // ---- MHA ----
  k_gemm<<<dim3(4, N / 128), 256, 0, stream>>>(x2_h, Wi_h, bi, 0, qk_h, nullptr,
                                               N, 512, 256, nullptr, nullptr, nullptr, nullptr, 0);
  k_gemm<<<dim3(N / 128, 2), 256, 0, stream>>>(Wi_h + 512 * 256, x2_h, bi + 512, 1,
                                               vt_h, nullptr, 256, N, 256,
                                               nullptr, nullptr, nullptr, nullptr, 0);
  k_attn<<<dim3(256, 8), 256, 0, stream>>>(qk_h, vt_h, o_h);
  k_gemm<<<dim3(2, N / 128), 256, 0, stream>>>(o_h, Wo_h, bo, 0, att_h, nullptr,
                                               N, 256, 256, nullptr, nullptr, nullptr, nullptr, 0);

  // ---- residual + LayerNorm -> x2a (fp16) ----
  k_ln<<<N / 4, 256, 0, stream>>>(att_h, x2_h, gam, bet, x2a_h);

  // ---- GAT3 (H=1, C=128, fp32 accumulation) -> d_out fp32 ----
  k_gemm<<<dim3(1, N / 128), 256, 0, stream>>>(x2a_h, W3t, nullptr, 0, h_h, nullptr,
                                               N, 128, 256, aS3, aD3, es, ed, 1);
  k_agg<128, 1, false><<<N / 4, 256, 0, stream>>>(h_h, es, ed, b3, rowptr, col, 0, out, nullptr);
}

// Round 8
// 448.342 us; speedup vs baseline: 2.0166x; 1.0259x over previous
//
#include <hip/hip_runtime.h>

typedef _Float16 half_t;
typedef _Float16 half8  __attribute__((ext_vector_type(8)));
typedef _Float16 half4v __attribute__((ext_vector_type(4)));
typedef float    f32x4  __attribute__((ext_vector_type(4)));

constexpr int N_NODES = 32768;
constexpr int NPG_    = 512;

#define MFMA16(a, b, c) __builtin_amdgcn_mfma_f32_16x16x32_f16((a), (b), (c), 0, 0, 0)

__device__ __forceinline__ void gload_lds16(const half_t* g, half_t* l) {
  __builtin_amdgcn_global_load_lds(
      (const __attribute__((address_space(1))) void*)g,
      (__attribute__((address_space(3))) void*)l, 16, 0, 0);
}

// ---------------- CSR build ----------------
__global__ void k_hist(const int* __restrict__ dst, int* __restrict__ deg, int E) {
  int i = blockIdx.x * 256 + threadIdx.x;
  if (i < E) atomicAdd(&deg[dst[i]], 1);
}

__global__ __launch_bounds__(1024) void k_scan(const int* __restrict__ deg,
                                               int* __restrict__ rowptr) {
  __shared__ int part[1024];
  int t = threadIdx.x;
  int base = t * 32;
  int s = 0;
  #pragma unroll
  for (int i = 0; i < 32; i++) s += deg[base + i];
  part[t] = s;
  __syncthreads();
  for (int off = 1; off < 1024; off <<= 1) {
    int add = (t >= off) ? part[t - off] : 0;
    __syncthreads();
    part[t] += add;
    __syncthreads();
  }
  int run = (t == 0) ? 0 : part[t - 1];
  for (int i = 0; i < 32; i++) { rowptr[base + i] = run; run += deg[base + i]; }
  if (t == 1023) rowptr[N_NODES] = run;
}

__global__ void k_selfloop(const int* __restrict__ rowptr, int* __restrict__ fill,
                           int* __restrict__ col) {
  int i = blockIdx.x * 256 + threadIdx.x;
  fill[i] = 1;
  col[rowptr[i]] = i;   // self-loop is slot 0 of every dst
}

__global__ void k_scatter(const int* __restrict__ src, const int* __restrict__ dst,
                          const int* __restrict__ rowptr, int* __restrict__ fill,
                          int* __restrict__ col, int E) {
  int i = blockIdx.x * 256 + threadIdx.x;
  if (i < E) {
    int d = dst[i];
    int pos = rowptr[d] + atomicAdd(&fill[d], 1);
    col[pos] = src[i];
  }
}

// ---------------- fused conversions + deg init (one launch) ----------------
__global__ void k_convert(
    const float* __restrict__ x,  half_t* __restrict__ x_h,
    const float* __restrict__ W1, half_t* __restrict__ W1t,
    const float* __restrict__ W2, half_t* __restrict__ W2t,
    const float* __restrict__ W3, half_t* __restrict__ W3t,
    const float* __restrict__ Wi, half_t* __restrict__ Wi_h,
    const float* __restrict__ Wo, half_t* __restrict__ Wo_h,
    int* __restrict__ deg)
{
  int bid = blockIdx.x, t = threadIdx.x;
  if (bid < 16384) {
    int i = bid * 256 + t;
    x_h[i] = (half_t)x[i];
  } else if (bid < 16512) {            // W1t[o*128+k] = W1[k*256+o]
    int i = (bid - 16384) * 256 + t;
    int o = i >> 7, k = i & 127;
    W1t[i] = (half_t)W1[k * 256 + o];
  } else if (bid < 16768) {            // W2t[o*256+k] = W2[k*256+o]
    int i = (bid - 16512) * 256 + t;
    int o = i >> 8, k = i & 255;
    W2t[i] = (half_t)W2[k * 256 + o];
  } else if (bid < 16896) {            // W3t[o*256+k] = W3[k*128+o]
    int i = (bid - 16768) * 256 + t;
    int o = i >> 8, k = i & 255;
    W3t[i] = (half_t)W3[k * 128 + o];
  } else if (bid < 17664) {
    int i = (bid - 16896) * 256 + t;
    Wi_h[i] = (half_t)Wi[i];
  } else if (bid < 17920) {
    int i = (bid - 17664) * 256 + t;
    Wo_h[i] = (half_t)Wo[i];
  } else {
    deg[(bid - 17920) * 256 + t] = 1;  // self-loop counts as 1
  }
}

// ---------------- GEMM + optional fused GAT-score epilogue ----------------
// C[M,Nc] = A[M,K] @ Bt[Nc,K]^T (+bias). BK=64, source-side XOR swizzle.
__global__ __launch_bounds__(256) void k_gemm(
    const half_t* __restrict__ A, const half_t* __restrict__ Bt,
    const float* __restrict__ bias, int bias_per_row,
    half_t* __restrict__ outh, float* __restrict__ outf,
    int M, int Nc, int K,
    const float* __restrict__ aS, const float* __restrict__ aD,
    float* __restrict__ es, float* __restrict__ ed, int H)
{
  __shared__ __align__(16) half_t As[128 * 64];
  __shared__ __align__(16) half_t Bs[128 * 64];
  __shared__ float sRed[2][4][64];     // H==1 cross-wave partials
  int w = threadIdx.x >> 6, lane = threadIdx.x & 63;
  int r = lane & 15, q = lane >> 4;
  int m0 = blockIdx.y * 128, n0 = blockIdx.x * 128;
  int mh = (w & 1) * 64, nh = (w >> 1) * 64;
  f32x4 acc[4][4];
  #pragma unroll
  for (int i = 0; i < 4; i++)
    #pragma unroll
    for (int j = 0; j < 4; j++) acc[i][j] = f32x4{0.f, 0.f, 0.f, 0.f};

  int srow = lane >> 3;          // 0..7 rows per gload
  int sc   = lane & 7;           // 16B chunk slot 0..7

  for (int k0 = 0; k0 < K; k0 += 64) {
    __syncthreads();
    #pragma unroll
    for (int i = 0; i < 4; i++) {
      int R0 = w * 32 + i * 8;
      int row = R0 + srow;
      int cg = sc ^ (row & 7);
      gload_lds16(A  + (size_t)(m0 + row) * K + k0 + cg * 8, &As[R0 * 64]);
      gload_lds16(Bt + (size_t)(n0 + row) * K + k0 + cg * 8, &Bs[R0 * 64]);
    }
    __syncthreads();
    #pragma unroll
    for (int kk = 0; kk < 2; kk++) {
      half8 af[4], bf[4];
      #pragma unroll
      for (int t = 0; t < 4; t++) {
        int rr = mh + t * 16 + r;
        af[t] = *(const half8*)&As[rr * 64 + (((kk * 4 + q) ^ (rr & 7)) << 3)];
      }
      #pragma unroll
      for (int t = 0; t < 4; t++) {
        int rr = nh + t * 16 + r;
        bf[t] = *(const half8*)&Bs[rr * 64 + (((kk * 4 + q) ^ (rr & 7)) << 3)];
      }
      #pragma unroll
      for (int ti = 0; ti < 4; ti++)
        #pragma unroll
        for (int tj = 0; tj < 4; tj++)
          acc[ti][tj] = MFMA16(af[ti], bf[tj], acc[ti][tj]);
    }
  }

  // C store
  #pragma unroll
  for (int tj = 0; tj < 4; tj++) {
    int colc = n0 + nh + tj * 16 + r;
    #pragma unroll
    for (int ti = 0; ti < 4; ti++) {
      #pragma unroll
      for (int i = 0; i < 4; i++) {
        int row = m0 + mh + ti * 16 + q * 4 + i;
        float bv = bias ? (bias_per_row ? bias[row] : bias[colc]) : 0.f;
        float v = acc[ti][tj][i] + bv;
        size_t idx = (size_t)row * Nc + colc;
        if (outf) outf[idx] = v;
        if (outh) outh[idx] = (half_t)v;
      }
    }
  }

  // fused score epilogue
  if (es) {
    if (H == 4) {
      int head = (n0 >> 6) + (nh >> 6);
      float aSv[4], aDv[4];
      #pragma unroll
      for (int tj = 0; tj < 4; tj++) {
        int cl = tj * 16 + r;
        aSv[tj] = aS[head * 64 + cl];
        aDv[tj] = aD[head * 64 + cl];
      }
      #pragma unroll
      for (int ti = 0; ti < 4; ti++) {
        #pragma unroll
        for (int i = 0; i < 4; i++) {
          float ps = 0.f, pd = 0.f;
          #pragma unroll
          for (int tj = 0; tj < 4; tj++) {
            float av = acc[ti][tj][i];
            ps += av * aSv[tj];
            pd += av * aDv[tj];
          }
          #pragma unroll
          for (int off = 1; off < 16; off <<= 1) {
            ps += __shfl_xor(ps, off);
            pd += __shfl_xor(pd, off);
          }
          if (r == 0) {
            int row = m0 + mh + ti * 16 + q * 4 + i;
            es[(size_t)row * 4 + head] = ps;
            ed[(size_t)row * 4 + head] = pd;
          }
        }
      }
    } else {   // H == 1, Nc == 128
      float aSv[4], aDv[4];
      #pragma unroll
      for (int tj = 0; tj < 4; tj++) {
        int c = nh + tj * 16 + r;
        aSv[tj] = aS[c];
        aDv[tj] = aD[c];
      }
      #pragma unroll
      for (int ti = 0; ti < 4; ti++) {
        #pragma unroll
        for (int i = 0; i < 4; i++) {
          float ps = 0.f, pd = 0.f;
          #pragma unroll
          for (int tj = 0; tj < 4; tj++) {
            float av = acc[ti][tj][i];
            ps += av * aSv[tj];
            pd += av * aDv[tj];
          }
          #pragma unroll
          for (int off = 1; off < 16; off <<= 1) {
            ps += __shfl_xor(ps, off);
            pd += __shfl_xor(pd, off);
          }
          if (r == 0) {
            int ri = ti * 16 + q * 4 + i;
            sRed[0][w][ri] = ps;
            sRed[1][w][ri] = pd;
          }
        }
      }
      __syncthreads();
      if (threadIdx.x < 128) {
        int row = threadIdx.x;
        int wlo = row >> 6, ri = row & 63;
        es[m0 + row] = sRed[0][wlo][ri] + sRed[0][wlo + 2][ri];
        ed[m0 + row] = sRed[1][wlo][ri] + sRed[1][wlo + 2][ri];
      }
    }
  }
}

// ---------------- fused Wo-GEMM + residual + LayerNorm ----------------
// out = LN((A @ Bt^T + bias) + res) * gamma + beta, Nc = K = 256.
// 64-row blocks (512 total); wave w owns cols [w*64, w*64+64) of all 64 rows.
__global__ __launch_bounds__(256) void k_gemm_ln(
    const half_t* __restrict__ A, const half_t* __restrict__ Bt,
    const float* __restrict__ bias, const half_t* __restrict__ res,
    const float* __restrict__ gamma, const float* __restrict__ beta,
    half_t* __restrict__ outh)
{
  __shared__ __align__(16) half_t As[64 * 64];
  __shared__ __align__(16) half_t Bs[256 * 64];
  __shared__ float sSum[4][64], sSq[4][64];
  __shared__ float sMR[64][2];
  int w = threadIdx.x >> 6, lane = threadIdx.x & 63;
  int r = lane & 15, q = lane >> 4;
  int m0 = blockIdx.x * 64;
  int nh = w * 64;
  f32x4 acc[4][4];
  #pragma unroll
  for (int i = 0; i < 4; i++)
    #pragma unroll
    for (int j = 0; j < 4; j++) acc[i][j] = f32x4{0.f, 0.f, 0.f, 0.f};

  int srow = lane >> 3, sc = lane & 7;

  for (int k0 = 0; k0 < 256; k0 += 64) {
    __syncthreads();
    #pragma unroll
    for (int i = 0; i < 2; i++) {          // As: 64 rows
      int R0 = w * 16 + i * 8;
      int row = R0 + srow;
      int cg = sc ^ (row & 7);
      gload_lds16(A + (size_t)(m0 + row) * 256 + k0 + cg * 8, &As[R0 * 64]);
    }
    #pragma unroll
    for (int i = 0; i < 8; i++) {          // Bs: 256 rows (full Wo)
      int R0 = w * 64 + i * 8;
      int row = R0 + srow;
      int cg = sc ^ (row & 7);
      gload_lds16(Bt + (size_t)row * 256 + k0 + cg * 8, &Bs[R0 * 64]);
    }
    __syncthreads();
    #pragma unroll
    for (int kk = 0; kk < 2; kk++) {
      half8 af[4], bf[4];
      #pragma unroll
      for (int t = 0; t < 4; t++) {
        int rr = t * 16 + r;
        af[t] = *(const half8*)&As[rr * 64 + (((kk * 4 + q) ^ (rr & 7)) << 3)];
      }
      #pragma unroll
      for (int t = 0; t < 4; t++) {
        int rr = nh + t * 16 + r;
        bf[t] = *(const half8*)&Bs[rr * 64 + (((kk * 4 + q) ^ (rr & 7)) << 3)];
      }
      #pragma unroll
      for (int ti = 0; ti < 4; ti++)
        #pragma unroll
        for (int tj = 0; tj < 4; tj++)
          acc[ti][tj] = MFMA16(af[ti], bf[tj], acc[ti][tj]);
    }
  }

  // add bias + residual into acc; per-row partial sums over this wave's 64 cols
  float gv[4], bv[4];
  #pragma unroll
  for (int tj = 0; tj < 4; tj++) {
    int col = nh + tj * 16 + r;
    gv[tj] = gamma[col];
    bv[tj] = beta[col];
  }
  #pragma unroll
  for (int ti = 0; ti < 4; ti++) {
    #pragma unroll
    for (int i = 0; i < 4; i++) {
      int row = ti * 16 + q * 4 + i;
      float s = 0.f, ss = 0.f;
      #pragma unroll
      for (int tj = 0; tj < 4; tj++) {
        int col = nh + tj * 16 + r;
        float v = acc[ti][tj][i] + bias[col]
                + (float)res[(size_t)(m0 + row) * 256 + col];
        acc[ti][tj][i] = v;
        s += v;
        ss += v * v;
      }
      #pragma unroll
      for (int off = 1; off < 16; off <<= 1) {
        s  += __shfl_xor(s, off);
        ss += __shfl_xor(ss, off);
      }
      if (r == 0) { sSum[w][row] = s; sSq[w][row] = ss; }
    }
  }
  __syncthreads();
  if (threadIdx.x < 64) {
    int row = threadIdx.x;
    float s  = sSum[0][row] + sSum[1][row] + sSum[2][row] + sSum[3][row];
    float ss = sSq[0][row] + sSq[1][row] + sSq[2][row] + sSq[3][row];
    float mean = s * (1.f / 256.f);
    float var  = ss * (1.f / 256.f) - mean * mean;
    sMR[row][0] = mean;
    sMR[row][1] = rsqrtf(var + 1e-5f);
  }
  __syncthreads();
  #pragma unroll
  for (int ti = 0; ti < 4; ti++) {
    #pragma unroll
    for (int i = 0; i < 4; i++) {
      int row = ti * 16 + q * 4 + i;
      float mean = sMR[row][0], rstd = sMR[row][1];
      #pragma unroll
      for (int tj = 0; tj < 4; tj++) {
        int col = nh + tj * 16 + r;
        outh[(size_t)(m0 + row) * 256 + col] =
            (half_t)((acc[ti][tj][i] - mean) * rstd * gv[tj] + bv[tj]);
      }
    }
  }
}

// ---------------- edge-softmax aggregation (one wave per dst) ----------------
template<int HC, int H, bool FP16ACC>
__global__ __launch_bounds__(256) void k_agg(
    const half_t* __restrict__ h, const float* __restrict__ es,
    const float* __restrict__ ed, const float* __restrict__ bias,
    const int* __restrict__ rowptr, const int* __restrict__ col, int elu,
    float* __restrict__ outf, half_t* __restrict__ outh)
{
  constexpr int VPT = HC / 16;        // channels per lane (16 or 8)
  constexpr int NV8 = VPT / 8;        // half8 regs per slot (2 or 1)
  constexpr int C = HC / H;
  int lane = threadIdx.x & 63;
  int g = lane >> 4, li = lane & 15;
  int n = blockIdx.x * 4 + (threadIdx.x >> 6);
  int cbase = li * VPT;
  int hl = cbase / C;
  float edn = ed[(size_t)n * H + hl];
  int j0 = rowptr[n], j1 = rowptr[n + 1];
  const half_t* hb = h + cbase;

  float sum0 = 0.f, sum1 = 0.f;

  if constexpr (FP16ACC) {
    half8 acc0[NV8], acc1[NV8];
    #pragma unroll
    for (int i = 0; i < NV8; i++) {
      acc0[i] = half8{0, 0, 0, 0, 0, 0, 0, 0};
      acc1[i] = half8{0, 0, 0, 0, 0, 0, 0, 0};
    }
    for (int j = j0 + g; j < j1; j += 8) {
      int jb = j + 4;
      int s0 = col[j];
      int s1 = col[(jb < j1) ? jb : j];
      float e0 = es[(size_t)s0 * H + hl] + edn;
      e0 = fmaxf(e0, 0.2f * e0);
      float e1 = es[(size_t)s1 * H + hl] + edn;
      e1 = fmaxf(e1, 0.2f * e1);
      e1 = (jb < j1) ? e1 : -1e30f;
      const half_t* hp0 = hb + (size_t)s0 * HC;
      const half_t* hp1 = hb + (size_t)s1 * HC;
      // exp(e-6) == 2^(e*log2e - 6*log2e); uniform shift cancels in the ratio
      float p0 = exp2f(e0 * 1.44269504f - 8.65617025f);
      float p1 = exp2f(e1 * 1.44269504f - 8.65617025f);
      sum0 += p0; sum1 += p1;
      half_t q0 = (half_t)p0, q1 = (half_t)p1;
      half8 pv0 = {q0, q0, q0, q0, q0, q0, q0, q0};
      half8 pv1 = {q1, q1, q1, q1, q1, q1, q1, q1};
      #pragma unroll
      for (int i = 0; i < NV8; i++) {
        half8 v0 = *(const half8*)(hp0 + i * 8);
        half8 v1 = *(const half8*)(hp1 + i * 8);
        acc0[i] += pv0 * v0;        // v_pk_fma_f16
        acc1[i] += pv1 * v1;
      }
    }
    float sum = sum0 + sum1;
    sum += __shfl_xor(sum, 16);
    sum += __shfl_xor(sum, 32);
    float av[VPT];
    #pragma unroll
    for (int i = 0; i < VPT; i++) {
      av[i] = (float)acc0[i >> 3][i & 7] + (float)acc1[i >> 3][i & 7];
      av[i] += __shfl_xor(av[i], 16);
      av[i] += __shfl_xor(av[i], 32);
    }
    float inv = 1.f / sum;
    float v[VPT];
    #pragma unroll
    for (int i = 0; i < VPT; i++) {
      float t = av[i] * inv + bias[cbase + i];
      if (elu) t = (t > 0.f) ? t : __expf(t) - 1.f;
      v[i] = t;
    }
    if (g == 0) {
      size_t obase = (size_t)n * HC + cbase;
      if (outh) {
        #pragma unroll
        for (int p8 = 0; p8 < NV8; p8++) {
          half8 hv;
          #pragma unroll
          for (int i = 0; i < 8; i++) hv[i] = (half_t)v[p8 * 8 + i];
          *(half8*)(outh + obase + p8 * 8) = hv;
        }
      }
      if (outf) {
        #pragma unroll
        for (int p4 = 0; p4 < VPT / 4; p4++) {
          float4 fv = {v[p4 * 4], v[p4 * 4 + 1], v[p4 * 4 + 2], v[p4 * 4 + 3]};
          *(float4*)(outf + obase + p4 * 4) = fv;
        }
      }
    }
  } else {
    float acc0[VPT], acc1[VPT];
    #pragma unroll
    for (int i = 0; i < VPT; i++) { acc0[i] = 0.f; acc1[i] = 0.f; }
    for (int j = j0 + g; j < j1; j += 8) {
      int jb = j + 4;
      int s0 = col[j];
      int s1 = col[(jb < j1) ? jb : j];
      float e0 = es[(size_t)s0 * H + hl] + edn;
      e0 = fmaxf(e0, 0.2f * e0);
      float e1 = es[(size_t)s1 * H + hl] + edn;
      e1 = fmaxf(e1, 0.2f * e1);
      e1 = (jb < j1) ? e1 : -1e30f;
      const half_t* hp0 = hb + (size_t)s0 * HC;
      const half_t* hp1 = hb + (size_t)s1 * HC;
      float p0 = __expf(e0), p1 = __expf(e1);
      sum0 += p0; sum1 += p1;
      #pragma unroll
      for (int c8 = 0; c8 < NV8; c8++) {
        half8 a0 = *(const half8*)(hp0 + c8 * 8);
        half8 a1 = *(const half8*)(hp1 + c8 * 8);
        #pragma unroll
        for (int i = 0; i < 8; i++) {
          acc0[c8 * 8 + i] += p0 * (float)a0[i];
          acc1[c8 * 8 + i] += p1 * (float)a1[i];
        }
      }
    }
    float sum = sum0 + sum1;
    sum += __shfl_xor(sum, 16);
    sum += __shfl_xor(sum, 32);
    float av[VPT];
    #pragma unroll
    for (int i = 0; i < VPT; i++) {
      av[i] = acc0[i] + acc1[i];
      av[i] += __shfl_xor(av[i], 16);
      av[i] += __shfl_xor(av[i], 32);
    }
    float inv = 1.f / sum;
    float v[VPT];
    #pragma unroll
    for (int i = 0; i < VPT; i++) {
      float t = av[i] * inv + bias[cbase + i];
      if (elu) t = (t > 0.f) ? t : __expf(t) - 1.f;
      v[i] = t;
    }
    if (g == 0) {
      size_t obase = (size_t)n * HC + cbase;
      if (outh) {
        #pragma unroll
        for (int p8 = 0; p8 < NV8; p8++) {
          half8 hv;
          #pragma unroll
          for (int i = 0; i < 8; i++) hv[i] = (half_t)v[p8 * 8 + i];
          *(half8*)(outh + obase + p8 * 8) = hv;
        }
      }
      if (outf) {
        #pragma unroll
        for (int p4 = 0; p4 < VPT / 4; p4++) {
          float4 fv = {v[p4 * 4], v[p4 * 4 + 1], v[p4 * 4 + 2], v[p4 * 4 + 3]};
          *(float4*)(outf + obase + p4 * 4) = fv;
        }
      }
    }
  }
}

// ---------------- MHA core, flash-style, 4x barrier amortization ----------------
// Block = (pair, q-half of 256 rows): 512 blocks. Wave owns 64 q-rows as 4
// sub-chunks of 16, all processed against each staged K/V tile -> work per
// barrier-pair 32 -> 128 MFMAs. Softmax weight = 2^(s*0.125*log2e - 8*log2e)
// (== exp(s/8 - 8); uniform shift cancels in P/sum).
__global__ __launch_bounds__(256) void k_attn(
    const half_t* __restrict__ qk, const half_t* __restrict__ vt,
    half_t* __restrict__ o)
{
  __shared__ __align__(16) half_t Kt[128 * 64];
  __shared__ __align__(16) half_t Vt[64 * 128];
  __shared__ __align__(16) half_t Pb[4][16][136];

  int pair = blockIdx.x;
  int b = pair >> 2, hh = pair & 3;
  int q0 = blockIdx.y * 256;
  int w = threadIdx.x >> 6, lane = threadIdx.x & 63;
  int cc = lane & 15, qq = lane >> 4;
  int qb = q0 + w * 64;

  half8 qa0[4], qa1[4];
  #pragma unroll
  for (int qs = 0; qs < 4; qs++) {
    const half_t* Qp = qk + ((size_t)(b * NPG_ + qb + qs * 16 + cc) * 512 + hh * 64);
    qa0[qs] = *(const half8*)(Qp + qq * 8);
    qa1[qs] = *(const half8*)(Qp + 32 + qq * 8);
  }

  f32x4 oacc[4][4];   // [qs][nt]
  #pragma unroll
  for (int a = 0; a < 4; a++)
    #pragma unroll
    for (int t = 0; t < 4; t++) oacc[a][t] = f32x4{0.f, 0.f, 0.f, 0.f};
  float rs[4] = {0.f, 0.f, 0.f, 0.f};

  const half_t* kb = qk + ((size_t)(b * NPG_) * 512 + 256 + hh * 64);
  const half_t* vb = vt + ((size_t)(hh * 64) * 32768 + b * NPG_);

  int krow_l = lane >> 3, ks_l = lane & 7;
  int vrow_l = lane >> 4, vs_l = lane & 15;

  for (int kt = 0; kt < 4; kt++) {
    __syncthreads();
    #pragma unroll
    for (int i = 0; i < 4; i++) {
      int R = (i * 4 + w) * 8;
      int kr = R + krow_l;
      gload_lds16(kb + (size_t)(kt * 128 + kr) * 512 + ((ks_l ^ (kr & 7)) * 8),
                  &Kt[R * 64]);
    }
    #pragma unroll
    for (int i = 0; i < 4; i++) {
      int D0 = (i * 4 + w) * 4;
      int d = D0 + vrow_l;
      gload_lds16(vb + (size_t)d * 32768 + kt * 128 + ((vs_l ^ (d & 15)) * 8),
                  &Vt[D0 * 128]);
    }
    __syncthreads();

    #pragma unroll
    for (int qs = 0; qs < 4; qs++) {
      #pragma unroll
      for (int mt = 0; mt < 8; mt++) {
        int key = mt * 16 + cc;
        half8 k0 = *(const half8*)&Kt[key * 64 + ((qq ^ (key & 7)) << 3)];
        half8 k1 = *(const half8*)&Kt[key * 64 + (((qq + 4) ^ (key & 7)) << 3)];
        f32x4 s = f32x4{0.f, 0.f, 0.f, 0.f};
        s = MFMA16(k0, qa0[qs], s);
        s = MFMA16(k1, qa1[qs], s);
        half4v ph;
        #pragma unroll
        for (int i = 0; i < 4; i++) {
          float p = exp2f(s[i] * 0.180336886f - 11.54156033f);
          rs[qs] += p;
          ph[i] = (half_t)p;
        }
        *(half4v*)&Pb[w][cc][mt * 16 + qq * 4] = ph;
      }
      #pragma unroll
      for (int kc = 0; kc < 4; kc++) {
        half8 a = *(const half8*)&Pb[w][cc][kc * 32 + qq * 8];
        #pragma unroll
        for (int nt = 0; nt < 4; nt++) {
          int d = nt * 16 + cc;
          half8 bb = *(const half8*)&Vt[d * 128 + (((kc * 4 + qq) ^ (d & 15)) << 3)];
          oacc[qs][nt] = MFMA16(a, bb, oacc[qs][nt]);
        }
      }
    }
  }

  #pragma unroll
  for (int qs = 0; qs < 4; qs++) {
    float r = rs[qs];
    r += __shfl_xor(r, 16);
    r += __shfl_xor(r, 32);
    #pragma unroll
    for (int i = 0; i < 4; i++) {
      float rsv = __shfl(r, qq * 4 + i);
      float inv = 1.f / rsv;
      int node = b * NPG_ + qb + qs * 16 + qq * 4 + i;
      #pragma unroll
      for (int nt = 0; nt < 4; nt++)
        o[(size_t)node * 256 + hh * 64 + nt * 16 + cc] = (half_t)(oacc[qs][nt][i] * inv);
    }
  }
}

// ---------------- host ----------------
extern "C" void kernel_launch(void* const* d_in, const int* in_sizes, int n_in,
                              void* d_out, int out_size, void* d_ws, size_t ws_size,
                              hipStream_t stream)
{
  const float* x    = (const float*)d_in[0];
  const int*   ei   = (const int*)d_in[1];
  const float* W1   = (const float*)d_in[3];
  const float* aS1  = (const float*)d_in[4];
  const float* aD1  = (const float*)d_in[5];
  const float* b1   = (const float*)d_in[6];
  const float* W2   = (const float*)d_in[7];
  const float* aS2  = (const float*)d_in[8];
  const float* aD2  = (const float*)d_in[9];
  const float* b2   = (const float*)d_in[10];
  const float* W3   = (const float*)d_in[11];
  const float* aS3  = (const float*)d_in[12];
  const float* aD3  = (const float*)d_in[13];
  const float* b3   = (const float*)d_in[14];
  const float* Wi   = (const float*)d_in[15];
  const float* bi   = (const float*)d_in[16];
  const float* Wo   = (const float*)d_in[17];
  const float* bo   = (const float*)d_in[18];
  const float* gam  = (const float*)d_in[19];
  const float* bet  = (const float*)d_in[20];
  float* out = (float*)d_out;
  const int N = N_NODES;
  int E = in_sizes[1] / 2;

  char* ws = (char*)d_ws;
  size_t off = 0;
  auto alloc = [&](size_t bytes) -> void* {
    void* p = ws + off;
    off = (off + bytes + 255) & ~(size_t)255;
    return p;
  };
  half_t* x_h    = (half_t*)alloc((size_t)N * 128 * 2);
  half_t* h_h    = (half_t*)alloc((size_t)N * 256 * 2);   // h1/h2/h3
  half_t* x1_h   = (half_t*)alloc((size_t)N * 256 * 2);
  half_t* x2_h   = (half_t*)alloc((size_t)N * 256 * 2);
  half_t* qk_h   = (half_t*)alloc((size_t)N * 512 * 2);
  half_t* vt_h   = (half_t*)alloc((size_t)256 * N * 2);   // V^T: [256][32768]
  half_t* o_h    = (half_t*)alloc((size_t)N * 256 * 2);
  half_t* x2a_h  = (half_t*)alloc((size_t)N * 256 * 2);
  half_t* W1t    = (half_t*)alloc(256 * 128 * 2);
  half_t* W2t    = (half_t*)alloc(256 * 256 * 2);
  half_t* W3t    = (half_t*)alloc(128 * 256 * 2);
  half_t* Wi_h   = (half_t*)alloc(768 * 256 * 2);
  half_t* Wo_h   = (half_t*)alloc(256 * 256 * 2);
  float*  es     = (float*) alloc((size_t)N * 4 * 4);
  float*  ed     = (float*) alloc((size_t)N * 4 * 4);
  int*    deg    = (int*)   alloc((size_t)N * 4);
  int*    fill   = (int*)   alloc((size_t)N * 4);
  int*    rowptr = (int*)   alloc(((size_t)N + 1) * 4);
  int*    col    = (int*)   alloc((size_t)(N + E) * 4);

  const int* srcE = ei;
  const int* dstE = ei + E;

  // conversions + deg init (one launch), then CSR
  k_convert<<<18048, 256, 0, stream>>>(x, x_h, W1, W1t, W2, W2t, W3, W3t,
                                       Wi, Wi_h, Wo, Wo_h, deg);
  k_hist<<<(E + 255) / 256, 256, 0, stream>>>(dstE, deg, E);
  k_scan<<<1, 1024, 0, stream>>>(deg, rowptr);
  k_selfloop<<<N / 256, 256, 0, stream>>>(rowptr, fill, col);
  k_scatter<<<(E + 255) / 256, 256, 0, stream>>>(srcE, dstE, rowptr, fill, col, E);

  // ---- GAT1: h1 = x @ W1 (+fused es/ed) ; aggregate+ELU -> x1 ----
  k_gemm<<<dim3(2, N / 128), 256, 0, stream>>>(x_h, W1t, nullptr, 0, h_h, nullptr,
                                               N, 256, 128, aS1, aD1, es, ed, 4);
  k_agg<256, 4, true><<<N / 4, 256, 0, stream>>>(h_h, es, ed, b1, rowptr, col, 1, nullptr, x1_h);

  // ---- GAT2 -> x2 (fp16) ----
  k_gemm<<<dim3(2, N / 128), 256, 0, stream>>>(x1_h, W2t, nullptr, 0, h_h, nullptr,
                                               N, 256, 256, aS2, aD2, es, ed, 4);
  k_agg<256, 4, true><<<N / 4, 256, 0, stream>>>(h_h, es, ed, b2, rowptr, col, 1, nullptr, x2_h);

  // ---- MHA ----
  k_gemm<<<dim3(4, N / 128), 256, 0, stream>>>(x2_h, Wi_h, bi, 0, qk_h, nullptr,
                                               N, 512, 256, nullptr, nullptr, nullptr, nullptr, 0);
  k_gemm<<<dim3(N / 128, 2), 256, 0, stream>>>(Wi_h + 512 * 256, x2_h, bi + 512, 1,
                                               vt_h, nullptr, 256, N, 256,
                                               nullptr, nullptr, nullptr, nullptr, 0);
  k_attn<<<dim3(256, 2), 256, 0, stream>>>(qk_h, vt_h, o_h);

  // ---- Wo-GEMM + residual + LayerNorm fused -> x2a (fp16) ----
  k_gemm_ln<<<N / 64, 256, 0, stream>>>(o_h, Wo_h, bo, x2_h, gam, bet, x2a_h);

  // ---- GAT3 (H=1, C=128, fp32 accumulation) -> d_out fp32 ----
  k_gemm<<<dim3(1, N / 128), 256, 0, stream>>>(x2a_h, W3t, nullptr, 0, h_h, nullptr,
                                               N, 128, 256, aS3, aD3, es, ed, 1);
  k_agg<128, 1, false><<<N / 4, 256, 0, stream>>>(h_h, es, ed, b3, rowptr, col, 0, out, nullptr);
}

// Round 9
// 446.112 us; speedup vs baseline: 2.0267x; 1.0050x over previous
//
#include <hip/hip_runtime.h>

typedef _Float16 half_t;
typedef _Float16 half8  __attribute__((ext_vector_type(8)));
typedef _Float16 half4v __attribute__((ext_vector_type(4)));
typedef float    f32x4  __attribute__((ext_vector_type(4)));

constexpr int N_NODES = 32768;
constexpr int NPG_    = 512;

#define MFMA16(a, b, c) __builtin_amdgcn_mfma_f32_16x16x32_f16((a), (b), (c), 0, 0, 0)

__device__ __forceinline__ void gload_lds16(const half_t* g, half_t* l) {
  __builtin_amdgcn_global_load_lds(
      (const __attribute__((address_space(1))) void*)g,
      (__attribute__((address_space(3))) void*)l, 16, 0, 0);
}

// ---------------- CSR build ----------------
__global__ void k_hist(const int* __restrict__ dst, int* __restrict__ deg, int E) {
  int i = blockIdx.x * 256 + threadIdx.x;
  if (i < E) atomicAdd(&deg[dst[i]], 1);
}

__global__ __launch_bounds__(1024) void k_scan(const int* __restrict__ deg,
                                               int* __restrict__ rowptr) {
  __shared__ int part[1024];
  int t = threadIdx.x;
  int base = t * 32;
  int s = 0;
  #pragma unroll
  for (int i = 0; i < 32; i++) s += deg[base + i];
  part[t] = s;
  __syncthreads();
  for (int off = 1; off < 1024; off <<= 1) {
    int add = (t >= off) ? part[t - off] : 0;
    __syncthreads();
    part[t] += add;
    __syncthreads();
  }
  int run = (t == 0) ? 0 : part[t - 1];
  for (int i = 0; i < 32; i++) { rowptr[base + i] = run; run += deg[base + i]; }
  if (t == 1023) rowptr[N_NODES] = run;
}

__global__ void k_selfloop(const int* __restrict__ rowptr, int* __restrict__ fill,
                           int* __restrict__ col) {
  int i = blockIdx.x * 256 + threadIdx.x;
  fill[i] = 1;
  col[rowptr[i]] = i;   // self-loop is slot 0 of every dst
}

__global__ void k_scatter(const int* __restrict__ src, const int* __restrict__ dst,
                          const int* __restrict__ rowptr, int* __restrict__ fill,
                          int* __restrict__ col, int E) {
  int i = blockIdx.x * 256 + threadIdx.x;
  if (i < E) {
    int d = dst[i];
    int pos = rowptr[d] + atomicAdd(&fill[d], 1);
    col[pos] = src[i];
  }
}

// ---------------- fused conversions + deg init (one launch) ----------------
__global__ void k_convert(
    const float* __restrict__ x,  half_t* __restrict__ x_h,
    const float* __restrict__ W1, half_t* __restrict__ W1t,
    const float* __restrict__ W2, half_t* __restrict__ W2t,
    const float* __restrict__ W3, half_t* __restrict__ W3t,
    const float* __restrict__ Wi, half_t* __restrict__ Wi_h,
    const float* __restrict__ Wo, half_t* __restrict__ Wo_h,
    int* __restrict__ deg)
{
  int bid = blockIdx.x, t = threadIdx.x;
  if (bid < 16384) {
    int i = bid * 256 + t;
    x_h[i] = (half_t)x[i];
  } else if (bid < 16512) {            // W1t[o*128+k] = W1[k*256+o]
    int i = (bid - 16384) * 256 + t;
    int o = i >> 7, k = i & 127;
    W1t[i] = (half_t)W1[k * 256 + o];
  } else if (bid < 16768) {            // W2t[o*256+k] = W2[k*256+o]
    int i = (bid - 16512) * 256 + t;
    int o = i >> 8, k = i & 255;
    W2t[i] = (half_t)W2[k * 256 + o];
  } else if (bid < 16896) {            // W3t[o*256+k] = W3[k*128+o]
    int i = (bid - 16768) * 256 + t;
    int o = i >> 8, k = i & 255;
    W3t[i] = (half_t)W3[k * 128 + o];
  } else if (bid < 17664) {
    int i = (bid - 16896) * 256 + t;
    Wi_h[i] = (half_t)Wi[i];
  } else if (bid < 17920) {
    int i = (bid - 17664) * 256 + t;
    Wo_h[i] = (half_t)Wo[i];
  } else {
    deg[(bid - 17920) * 256 + t] = 1;  // self-loop counts as 1
  }
}

// ---------------- GEMM + optional fused GAT-score epilogue ----------------
// C[M,Nc] = A[M,K] @ Bt[Nc,K]^T (+bias). BK=64, source-side XOR swizzle.
__global__ __launch_bounds__(256) void k_gemm(
    const half_t* __restrict__ A, const half_t* __restrict__ Bt,
    const float* __restrict__ bias, int bias_per_row,
    half_t* __restrict__ outh, float* __restrict__ outf,
    int M, int Nc, int K,
    const float* __restrict__ aS, const float* __restrict__ aD,
    float* __restrict__ es, float* __restrict__ ed, int H)
{
  __shared__ __align__(16) half_t As[128 * 64];
  __shared__ __align__(16) half_t Bs[128 * 64];
  __shared__ float sRed[2][4][64];     // H==1 cross-wave partials
  int w = threadIdx.x >> 6, lane = threadIdx.x & 63;
  int r = lane & 15, q = lane >> 4;
  int m0 = blockIdx.y * 128, n0 = blockIdx.x * 128;
  int mh = (w & 1) * 64, nh = (w >> 1) * 64;
  f32x4 acc[4][4];
  #pragma unroll
  for (int i = 0; i < 4; i++)
    #pragma unroll
    for (int j = 0; j < 4; j++) acc[i][j] = f32x4{0.f, 0.f, 0.f, 0.f};

  int srow = lane >> 3;          // 0..7 rows per gload
  int sc   = lane & 7;           // 16B chunk slot 0..7

  for (int k0 = 0; k0 < K; k0 += 64) {
    __syncthreads();
    #pragma unroll
    for (int i = 0; i < 4; i++) {
      int R0 = w * 32 + i * 8;
      int row = R0 + srow;
      int cg = sc ^ (row & 7);
      gload_lds16(A  + (size_t)(m0 + row) * K + k0 + cg * 8, &As[R0 * 64]);
      gload_lds16(Bt + (size_t)(n0 + row) * K + k0 + cg * 8, &Bs[R0 * 64]);
    }
    __syncthreads();
    #pragma unroll
    for (int kk = 0; kk < 2; kk++) {
      half8 af[4], bf[4];
      #pragma unroll
      for (int t = 0; t < 4; t++) {
        int rr = mh + t * 16 + r;
        af[t] = *(const half8*)&As[rr * 64 + (((kk * 4 + q) ^ (rr & 7)) << 3)];
      }
      #pragma unroll
      for (int t = 0; t < 4; t++) {
        int rr = nh + t * 16 + r;
        bf[t] = *(const half8*)&Bs[rr * 64 + (((kk * 4 + q) ^ (rr & 7)) << 3)];
      }
      #pragma unroll
      for (int ti = 0; ti < 4; ti++)
        #pragma unroll
        for (int tj = 0; tj < 4; tj++)
          acc[ti][tj] = MFMA16(af[ti], bf[tj], acc[ti][tj]);
    }
  }

  // C store
  #pragma unroll
  for (int tj = 0; tj < 4; tj++) {
    int colc = n0 + nh + tj * 16 + r;
    #pragma unroll
    for (int ti = 0; ti < 4; ti++) {
      #pragma unroll
      for (int i = 0; i < 4; i++) {
        int row = m0 + mh + ti * 16 + q * 4 + i;
        float bv = bias ? (bias_per_row ? bias[row] : bias[colc]) : 0.f;
        float v = acc[ti][tj][i] + bv;
        size_t idx = (size_t)row * Nc + colc;
        if (outf) outf[idx] = v;
        if (outh) outh[idx] = (half_t)v;
      }
    }
  }

  // fused score epilogue
  if (es) {
    if (H == 4) {
      int head = (n0 >> 6) + (nh >> 6);
      float aSv[4], aDv[4];
      #pragma unroll
      for (int tj = 0; tj < 4; tj++) {
        int cl = tj * 16 + r;
        aSv[tj] = aS[head * 64 + cl];
        aDv[tj] = aD[head * 64 + cl];
      }
      #pragma unroll
      for (int ti = 0; ti < 4; ti++) {
        #pragma unroll
        for (int i = 0; i < 4; i++) {
          float ps = 0.f, pd = 0.f;
          #pragma unroll
          for (int tj = 0; tj < 4; tj++) {
            float av = acc[ti][tj][i];
            ps += av * aSv[tj];
            pd += av * aDv[tj];
          }
          #pragma unroll
          for (int off = 1; off < 16; off <<= 1) {
            ps += __shfl_xor(ps, off);
            pd += __shfl_xor(pd, off);
          }
          if (r == 0) {
            int row = m0 + mh + ti * 16 + q * 4 + i;
            es[(size_t)row * 4 + head] = ps;
            ed[(size_t)row * 4 + head] = pd;
          }
        }
      }
    } else {   // H == 1, Nc == 128
      float aSv[4], aDv[4];
      #pragma unroll
      for (int tj = 0; tj < 4; tj++) {
        int c = nh + tj * 16 + r;
        aSv[tj] = aS[c];
        aDv[tj] = aD[c];
      }
      #pragma unroll
      for (int ti = 0; ti < 4; ti++) {
        #pragma unroll
        for (int i = 0; i < 4; i++) {
          float ps = 0.f, pd = 0.f;
          #pragma unroll
          for (int tj = 0; tj < 4; tj++) {
            float av = acc[ti][tj][i];
            ps += av * aSv[tj];
            pd += av * aDv[tj];
          }
          #pragma unroll
          for (int off = 1; off < 16; off <<= 1) {
            ps += __shfl_xor(ps, off);
            pd += __shfl_xor(pd, off);
          }
          if (r == 0) {
            int ri = ti * 16 + q * 4 + i;
            sRed[0][w][ri] = ps;
            sRed[1][w][ri] = pd;
          }
        }
      }
      __syncthreads();
      if (threadIdx.x < 128) {
        int row = threadIdx.x;
        int wlo = row >> 6, ri = row & 63;
        es[m0 + row] = sRed[0][wlo][ri] + sRed[0][wlo + 2][ri];
        ed[m0 + row] = sRed[1][wlo][ri] + sRed[1][wlo + 2][ri];
      }
    }
  }
}

// ---------------- fused Wo-GEMM + residual + LayerNorm ----------------
__global__ __launch_bounds__(256) void k_gemm_ln(
    const half_t* __restrict__ A, const half_t* __restrict__ Bt,
    const float* __restrict__ bias, const half_t* __restrict__ res,
    const float* __restrict__ gamma, const float* __restrict__ beta,
    half_t* __restrict__ outh)
{
  __shared__ __align__(16) half_t As[64 * 64];
  __shared__ __align__(16) half_t Bs[256 * 64];
  __shared__ float sSum[4][64], sSq[4][64];
  __shared__ float sMR[64][2];
  int w = threadIdx.x >> 6, lane = threadIdx.x & 63;
  int r = lane & 15, q = lane >> 4;
  int m0 = blockIdx.x * 64;
  int nh = w * 64;
  f32x4 acc[4][4];
  #pragma unroll
  for (int i = 0; i < 4; i++)
    #pragma unroll
    for (int j = 0; j < 4; j++) acc[i][j] = f32x4{0.f, 0.f, 0.f, 0.f};

  int srow = lane >> 3, sc = lane & 7;

  for (int k0 = 0; k0 < 256; k0 += 64) {
    __syncthreads();
    #pragma unroll
    for (int i = 0; i < 2; i++) {          // As: 64 rows
      int R0 = w * 16 + i * 8;
      int row = R0 + srow;
      int cg = sc ^ (row & 7);
      gload_lds16(A + (size_t)(m0 + row) * 256 + k0 + cg * 8, &As[R0 * 64]);
    }
    #pragma unroll
    for (int i = 0; i < 8; i++) {          // Bs: 256 rows (full Wo)
      int R0 = w * 64 + i * 8;
      int row = R0 + srow;
      int cg = sc ^ (row & 7);
      gload_lds16(Bt + (size_t)row * 256 + k0 + cg * 8, &Bs[R0 * 64]);
    }
    __syncthreads();
    #pragma unroll
    for (int kk = 0; kk < 2; kk++) {
      half8 af[4], bf[4];
      #pragma unroll
      for (int t = 0; t < 4; t++) {
        int rr = t * 16 + r;
        af[t] = *(const half8*)&As[rr * 64 + (((kk * 4 + q) ^ (rr & 7)) << 3)];
      }
      #pragma unroll
      for (int t = 0; t < 4; t++) {
        int rr = nh + t * 16 + r;
        bf[t] = *(const half8*)&Bs[rr * 64 + (((kk * 4 + q) ^ (rr & 7)) << 3)];
      }
      #pragma unroll
      for (int ti = 0; ti < 4; ti++)
        #pragma unroll
        for (int tj = 0; tj < 4; tj++)
          acc[ti][tj] = MFMA16(af[ti], bf[tj], acc[ti][tj]);
    }
  }

  float gv[4], bv[4];
  #pragma unroll
  for (int tj = 0; tj < 4; tj++) {
    int col = nh + tj * 16 + r;
    gv[tj] = gamma[col];
    bv[tj] = beta[col];
  }
  #pragma unroll
  for (int ti = 0; ti < 4; ti++) {
    #pragma unroll
    for (int i = 0; i < 4; i++) {
      int row = ti * 16 + q * 4 + i;
      float s = 0.f, ss = 0.f;
      #pragma unroll
      for (int tj = 0; tj < 4; tj++) {
        int col = nh + tj * 16 + r;
        float v = acc[ti][tj][i] + bias[col]
                + (float)res[(size_t)(m0 + row) * 256 + col];
        acc[ti][tj][i] = v;
        s += v;
        ss += v * v;
      }
      #pragma unroll
      for (int off = 1; off < 16; off <<= 1) {
        s  += __shfl_xor(s, off);
        ss += __shfl_xor(ss, off);
      }
      if (r == 0) { sSum[w][row] = s; sSq[w][row] = ss; }
    }
  }
  __syncthreads();
  if (threadIdx.x < 64) {
    int row = threadIdx.x;
    float s  = sSum[0][row] + sSum[1][row] + sSum[2][row] + sSum[3][row];
    float ss = sSq[0][row] + sSq[1][row] + sSq[2][row] + sSq[3][row];
    float mean = s * (1.f / 256.f);
    float var  = ss * (1.f / 256.f) - mean * mean;
    sMR[row][0] = mean;
    sMR[row][1] = rsqrtf(var + 1e-5f);
  }
  __syncthreads();
  #pragma unroll
  for (int ti = 0; ti < 4; ti++) {
    #pragma unroll
    for (int i = 0; i < 4; i++) {
      int row = ti * 16 + q * 4 + i;
      float mean = sMR[row][0], rstd = sMR[row][1];
      #pragma unroll
      for (int tj = 0; tj < 4; tj++) {
        int col = nh + tj * 16 + r;
        outh[(size_t)(m0 + row) * 256 + col] =
            (half_t)((acc[ti][tj][i] - mean) * rstd * gv[tj] + bv[tj]);
      }
    }
  }
}

// ---------------- edge-softmax aggregation (one wave per dst) ----------------
template<int HC, int H, bool FP16ACC>
__global__ __launch_bounds__(256) void k_agg(
    const half_t* __restrict__ h, const float* __restrict__ es,
    const float* __restrict__ ed, const float* __restrict__ bias,
    const int* __restrict__ rowptr, const int* __restrict__ col, int elu,
    float* __restrict__ outf, half_t* __restrict__ outh)
{
  constexpr int VPT = HC / 16;        // channels per lane (16 or 8)
  constexpr int NV8 = VPT / 8;        // half8 regs per slot (2 or 1)
  constexpr int C = HC / H;
  int lane = threadIdx.x & 63;
  int g = lane >> 4, li = lane & 15;
  int n = blockIdx.x * 4 + (threadIdx.x >> 6);
  int cbase = li * VPT;
  int hl = cbase / C;
  float edn = ed[(size_t)n * H + hl];
  int j0 = rowptr[n], j1 = rowptr[n + 1];
  const half_t* hb = h + cbase;

  float sum0 = 0.f, sum1 = 0.f;

  if constexpr (FP16ACC) {
    half8 acc0[NV8], acc1[NV8];
    #pragma unroll
    for (int i = 0; i < NV8; i++) {
      acc0[i] = half8{0, 0, 0, 0, 0, 0, 0, 0};
      acc1[i] = half8{0, 0, 0, 0, 0, 0, 0, 0};
    }
    for (int j = j0 + g; j < j1; j += 8) {
      int jb = j + 4;
      int s0 = col[j];
      int s1 = col[(jb < j1) ? jb : j];
      float e0 = es[(size_t)s0 * H + hl] + edn;
      e0 = fmaxf(e0, 0.2f * e0);
      float e1 = es[(size_t)s1 * H + hl] + edn;
      e1 = fmaxf(e1, 0.2f * e1);
      e1 = (jb < j1) ? e1 : -1e30f;
      const half_t* hp0 = hb + (size_t)s0 * HC;
      const half_t* hp1 = hb + (size_t)s1 * HC;
      float p0 = exp2f(e0 * 1.44269504f - 8.65617025f);
      float p1 = exp2f(e1 * 1.44269504f - 8.65617025f);
      sum0 += p0; sum1 += p1;
      half_t q0 = (half_t)p0, q1 = (half_t)p1;
      half8 pv0 = {q0, q0, q0, q0, q0, q0, q0, q0};
      half8 pv1 = {q1, q1, q1, q1, q1, q1, q1, q1};
      #pragma unroll
      for (int i = 0; i < NV8; i++) {
        half8 v0 = *(const half8*)(hp0 + i * 8);
        half8 v1 = *(const half8*)(hp1 + i * 8);
        acc0[i] += pv0 * v0;        // v_pk_fma_f16
        acc1[i] += pv1 * v1;
      }
    }
    float sum = sum0 + sum1;
    sum += __shfl_xor(sum, 16);
    sum += __shfl_xor(sum, 32);
    float av[VPT];
    #pragma unroll
    for (int i = 0; i < VPT; i++) {
      av[i] = (float)acc0[i >> 3][i & 7] + (float)acc1[i >> 3][i & 7];
      av[i] += __shfl_xor(av[i], 16);
      av[i] += __shfl_xor(av[i], 32);
    }
    float inv = 1.f / sum;
    float v[VPT];
    #pragma unroll
    for (int i = 0; i < VPT; i++) {
      float t = av[i] * inv + bias[cbase + i];
      if (elu) t = (t > 0.f) ? t : __expf(t) - 1.f;
      v[i] = t;
    }
    if (g == 0) {
      size_t obase = (size_t)n * HC + cbase;
      if (outh) {
        #pragma unroll
        for (int p8 = 0; p8 < NV8; p8++) {
          half8 hv;
          #pragma unroll
          for (int i = 0; i < 8; i++) hv[i] = (half_t)v[p8 * 8 + i];
          *(half8*)(outh + obase + p8 * 8) = hv;
        }
      }
      if (outf) {
        #pragma unroll
        for (int p4 = 0; p4 < VPT / 4; p4++) {
          float4 fv = {v[p4 * 4], v[p4 * 4 + 1], v[p4 * 4 + 2], v[p4 * 4 + 3]};
          *(float4*)(outf + obase + p4 * 4) = fv;
        }
      }
    }
  } else {
    float acc0[VPT], acc1[VPT];
    #pragma unroll
    for (int i = 0; i < VPT; i++) { acc0[i] = 0.f; acc1[i] = 0.f; }
    for (int j = j0 + g; j < j1; j += 8) {
      int jb = j + 4;
      int s0 = col[j];
      int s1 = col[(jb < j1) ? jb : j];
      float e0 = es[(size_t)s0 * H + hl] + edn;
      e0 = fmaxf(e0, 0.2f * e0);
      float e1 = es[(size_t)s1 * H + hl] + edn;
      e1 = fmaxf(e1, 0.2f * e1);
      e1 = (jb < j1) ? e1 : -1e30f;
      const half_t* hp0 = hb + (size_t)s0 * HC;
      const half_t* hp1 = hb + (size_t)s1 * HC;
      float p0 = __expf(e0), p1 = __expf(e1);
      sum0 += p0; sum1 += p1;
      #pragma unroll
      for (int c8 = 0; c8 < NV8; c8++) {
        half8 a0 = *(const half8*)(hp0 + c8 * 8);
        half8 a1 = *(const half8*)(hp1 + c8 * 8);
        #pragma unroll
        for (int i = 0; i < 8; i++) {
          acc0[c8 * 8 + i] += p0 * (float)a0[i];
          acc1[c8 * 8 + i] += p1 * (float)a1[i];
        }
      }
    }
    float sum = sum0 + sum1;
    sum += __shfl_xor(sum, 16);
    sum += __shfl_xor(sum, 32);
    float av[VPT];
    #pragma unroll
    for (int i = 0; i < VPT; i++) {
      av[i] = acc0[i] + acc1[i];
      av[i] += __shfl_xor(av[i], 16);
      av[i] += __shfl_xor(av[i], 32);
    }
    float inv = 1.f / sum;
    float v[VPT];
    #pragma unroll
    for (int i = 0; i < VPT; i++) {
      float t = av[i] * inv + bias[cbase + i];
      if (elu) t = (t > 0.f) ? t : __expf(t) - 1.f;
      v[i] = t;
    }
    if (g == 0) {
      size_t obase = (size_t)n * HC + cbase;
      if (outh) {
        #pragma unroll
        for (int p8 = 0; p8 < NV8; p8++) {
          half8 hv;
          #pragma unroll
          for (int i = 0; i < 8; i++) hv[i] = (half_t)v[p8 * 8 + i];
          *(half8*)(outh + obase + p8 * 8) = hv;
        }
      }
      if (outf) {
        #pragma unroll
        for (int p4 = 0; p4 < VPT / 4; p4++) {
          float4 fv = {v[p4 * 4], v[p4 * 4 + 1], v[p4 * 4 + 2], v[p4 * 4 + 3]};
          *(float4*)(outf + obase + p4 * 4) = fv;
        }
      }
    }
  }
}

// ---------------- MHA core, flash-style, occupancy-first ----------------
// Block = (pair, 64 q-rows), 2048 blocks; 64-key tiles (8 iterations).
// LDS = Kt 8K + Vt 8K + Pb 9.2K ~ 25 KB -> 6 resident blocks/CU: barrier
// drains overlap across blocks (R8 evidence: TLP, not barrier count, binds).
// Softmax weight = exp(S/8 - 8) via exp2 (uniform shift cancels in P/sum).
__global__ __launch_bounds__(256) void k_attn(
    const half_t* __restrict__ qk, const half_t* __restrict__ vt,
    half_t* __restrict__ o)
{
  __shared__ __align__(16) half_t Kt[64 * 64];        // K tile [key][64]
  __shared__ __align__(16) half_t Vt[64 * 64];        // V^T tile [d][64 keys]
  __shared__ __align__(16) half_t Pb[4][16][72];      // per-wave P [q][key+pad]

  int pair = blockIdx.x;            // pair -> fixed XCD (linear id % 8 == pair % 8)
  int b = pair >> 2, hh = pair & 3;
  int q0 = blockIdx.y * 64;
  int w = threadIdx.x >> 6, lane = threadIdx.x & 63;
  int cc = lane & 15, qq = lane >> 4;

  const half_t* Qp = qk + ((size_t)(b * NPG_ + q0 + w * 16 + cc) * 512 + hh * 64);
  half8 qa0 = *(const half8*)(Qp + qq * 8);
  half8 qa1 = *(const half8*)(Qp + 32 + qq * 8);

  f32x4 oacc[4];
  #pragma unroll
  for (int t = 0; t < 4; t++) oacc[t] = f32x4{0.f, 0.f, 0.f, 0.f};
  float rs = 0.f;

  const half_t* kb = qk + ((size_t)(b * NPG_) * 512 + 256 + hh * 64);
  const half_t* vb = vt + ((size_t)(hh * 64) * 32768 + b * NPG_);

  int krow = lane >> 3, ksl = lane & 7;

  for (int kt = 0; kt < 8; kt++) {
    __syncthreads();
    #pragma unroll
    for (int i = 0; i < 2; i++) {
      int R = w * 16 + i * 8;           // 8-row slab (1 KB) per gload
      int kr = R + krow;
      gload_lds16(kb + (size_t)(kt * 64 + kr) * 512 + ((ksl ^ (kr & 7)) * 8),
                  &Kt[R * 64]);
      gload_lds16(vb + (size_t)kr * 32768 + kt * 64 + ((ksl ^ (kr & 7)) * 8),
                  &Vt[R * 64]);
    }
    __syncthreads();

    // S^T = K Q^T ; exp ; pack to wave-private P[q][key] (A-operand layout)
    #pragma unroll
    for (int mt = 0; mt < 4; mt++) {
      int key = mt * 16 + cc;
      half8 k0 = *(const half8*)&Kt[key * 64 + ((qq ^ (key & 7)) << 3)];
      half8 k1 = *(const half8*)&Kt[key * 64 + (((qq + 4) ^ (key & 7)) << 3)];
      f32x4 s = f32x4{0.f, 0.f, 0.f, 0.f};
      s = MFMA16(k0, qa0, s);
      s = MFMA16(k1, qa1, s);
      half4v ph;
      #pragma unroll
      for (int i = 0; i < 4; i++) {
        float p = exp2f(s[i] * 0.180336886f - 11.54156033f);
        rs += p;
        ph[i] = (half_t)p;
      }
      *(half4v*)&Pb[w][cc][mt * 16 + qq * 4] = ph;
    }

    // O += P V
    #pragma unroll
    for (int kc = 0; kc < 2; kc++) {
      half8 a = *(const half8*)&Pb[w][cc][kc * 32 + qq * 8];
      #pragma unroll
      for (int nt = 0; nt < 4; nt++) {
        int d = nt * 16 + cc;
        half8 bb = *(const half8*)&Vt[d * 64 + (((kc * 4 + qq) ^ (d & 7)) << 3)];
        oacc[nt] = MFMA16(a, bb, oacc[nt]);
      }
    }
  }

  rs += __shfl_xor(rs, 16);
  rs += __shfl_xor(rs, 32);
  #pragma unroll
  for (int i = 0; i < 4; i++) {
    float rsv = __shfl(rs, qq * 4 + i);
    float inv = 1.f / rsv;
    int node = b * NPG_ + q0 + w * 16 + qq * 4 + i;
    #pragma unroll
    for (int nt = 0; nt < 4; nt++)
      o[(size_t)node * 256 + hh * 64 + nt * 16 + cc] = (half_t)(oacc[nt][i] * inv);
  }
}

// ---------------- host ----------------
extern "C" void kernel_launch(void* const* d_in, const int* in_sizes, int n_in,
                              void* d_out, int out_size, void* d_ws, size_t ws_size,
                              hipStream_t stream)
{
  const float* x    = (const float*)d_in[0];
  const int*   ei   = (const int*)d_in[1];
  const float* W1   = (const float*)d_in[3];
  const float* aS1  = (const float*)d_in[4];
  const float* aD1  = (const float*)d_in[5];
  const float* b1   = (const float*)d_in[6];
  const float* W2   = (const float*)d_in[7];
  const float* aS2  = (const float*)d_in[8];
  const float* aD2  = (const float*)d_in[9];
  const float* b2   = (const float*)d_in[10];
  const float* W3   = (const float*)d_in[11];
  const float* aS3  = (const float*)d_in[12];
  const float* aD3  = (const float*)d_in[13];
  const float* b3   = (const float*)d_in[14];
  const float* Wi   = (const float*)d_in[15];
  const float* bi   = (const float*)d_in[16];
  const float* Wo   = (const float*)d_in[17];
  const float* bo   = (const float*)d_in[18];
  const float* gam  = (const float*)d_in[19];
  const float* bet  = (const float*)d_in[20];
  float* out = (float*)d_out;
  const int N = N_NODES;
  int E = in_sizes[1] / 2;

  char* ws = (char*)d_ws;
  size_t off = 0;
  auto alloc = [&](size_t bytes) -> void* {
    void* p = ws + off;
    off = (off + bytes + 255) & ~(size_t)255;
    return p;
  };
  half_t* x_h    = (half_t*)alloc((size_t)N * 128 * 2);
  half_t* h_h    = (half_t*)alloc((size_t)N * 256 * 2);   // h1/h2/h3
  half_t* x1_h   = (half_t*)alloc((size_t)N * 256 * 2);
  half_t* x2_h   = (half_t*)alloc((size_t)N * 256 * 2);
  half_t* qk_h   = (half_t*)alloc((size_t)N * 512 * 2);
  half_t* vt_h   = (half_t*)alloc((size_t)256 * N * 2);   // V^T: [256][32768]
  half_t* o_h    = (half_t*)alloc((size_t)N * 256 * 2);
  half_t* x2a_h  = (half_t*)alloc((size_t)N * 256 * 2);
  half_t* W1t    = (half_t*)alloc(256 * 128 * 2);
  half_t* W2t    = (half_t*)alloc(256 * 256 * 2);
  half_t* W3t    = (half_t*)alloc(128 * 256 * 2);
  half_t* Wi_h   = (half_t*)alloc(768 * 256 * 2);
  half_t* Wo_h   = (half_t*)alloc(256 * 256 * 2);
  float*  es     = (float*) alloc((size_t)N * 4 * 4);
  float*  ed     = (float*) alloc((size_t)N * 4 * 4);
  int*    deg    = (int*)   alloc((size_t)N * 4);
  int*    fill   = (int*)   alloc((size_t)N * 4);
  int*    rowptr = (int*)   alloc(((size_t)N + 1) * 4);
  int*    col    = (int*)   alloc((size_t)(N + E) * 4);

  const int* srcE = ei;
  const int* dstE = ei + E;

  // conversions + deg init (one launch), then CSR
  k_convert<<<18048, 256, 0, stream>>>(x, x_h, W1, W1t, W2, W2t, W3, W3t,
                                       Wi, Wi_h, Wo, Wo_h, deg);
  k_hist<<<(E + 255) / 256, 256, 0, stream>>>(dstE, deg, E);
  k_scan<<<1, 1024, 0, stream>>>(deg, rowptr);
  k_selfloop<<<N / 256, 256, 0, stream>>>(rowptr, fill, col);
  k_scatter<<<(E + 255) / 256, 256, 0, stream>>>(srcE, dstE, rowptr, fill, col, E);

  // ---- GAT1: h1 = x @ W1 (+fused es/ed) ; aggregate+ELU -> x1 ----
  k_gemm<<<dim3(2, N / 128), 256, 0, stream>>>(x_h, W1t, nullptr, 0, h_h, nullptr,
                                               N, 256, 128, aS1, aD1, es, ed, 4);
  k_agg<256, 4, true><<<N / 4, 256, 0, stream>>>(h_h, es, ed, b1, rowptr, col, 1, nullptr, x1_h);

  // ---- GAT2 -> x2 (fp16) ----
  k_gemm<<<dim3(2, N / 128), 256, 0, stream>>>(x1_h, W2t, nullptr, 0, h_h, nullptr,
                                               N, 256, 256, aS2, aD2, es, ed, 4);
  k_agg<256, 4, true><<<N / 4, 256, 0, stream>>>(h_h, es, ed, b2, rowptr, col, 1, nullptr, x2_h);

  // ---- MHA ----
  k_gemm<<<dim3(4, N / 128), 256, 0, stream>>>(x2_h, Wi_h, bi, 0, qk_h, nullptr,
                                               N, 512, 256, nullptr, nullptr, nullptr, nullptr, 0);
  k_gemm<<<dim3(N / 128, 2), 256, 0, stream>>>(Wi_h + 512 * 256, x2_h, bi + 512, 1,
                                               vt_h, nullptr, 256, N, 256,
                                               nullptr, nullptr, nullptr, nullptr, 0);
  k_attn<<<dim3(256, 8), 256, 0, stream>>>(qk_h, vt_h, o_h);

  // ---- Wo-GEMM + residual + LayerNorm fused -> x2a (fp16) ----
  k_gemm_ln<<<N / 64, 256, 0, stream>>>(o_h, Wo_h, bo, x2_h, gam, bet, x2a_h);

  // ---- GAT3 (H=1, C=128, fp32 accumulation) -> d_out fp32 ----
  k_gemm<<<dim3(1, N / 128), 256, 0, stream>>>(x2a_h, W3t, nullptr, 0, h_h, nullptr,
                                               N, 128, 256, aS3, aD3, es, ed, 1);
  k_agg<128, 1, false><<<N / 4, 256, 0, stream>>>(h_h, es, ed, b3, rowptr, col, 0, out, nullptr);
}